// Round 8
// baseline (630.827 us; speedup 1.0000x reference)
//
#include <hip/hip_runtime.h>
#include <math.h>

// Problem constants (fixed by the reference).
#define N_ROWS 16384
#define D_INN  360
#define KP1    384      // D_INN padded to multiple of 64
#define HID    512
#define M_SLOTS 2048

typedef __attribute__((ext_vector_type(8))) short short8v;
typedef __attribute__((ext_vector_type(4))) float f32x4;
typedef __attribute__((ext_vector_type(16))) float f32x16;
typedef __attribute__((address_space(1))) unsigned int as1_uint;
typedef __attribute__((address_space(3))) unsigned int as3_uint;

// ---- bf16 helpers (manual, RNE) ----
__device__ __forceinline__ unsigned short bf16_rne(float f){
  unsigned u = __float_as_uint(f);
  unsigned r = u + 0x7FFFu + ((u >> 16) & 1u);
  return (unsigned short)(r >> 16);
}
__device__ __forceinline__ float bf16_to_f32(unsigned short h){
  return __uint_as_float(((unsigned)h) << 16);
}

__device__ __forceinline__ void glds16(const void* g, void* l){
  __builtin_amdgcn_global_load_lds((const as1_uint*)g, (as3_uint*)l, 16, 0, 0);
}

// reconstruct 4 consecutive f32 from hi/lo bf16 pair arrays
__device__ __forceinline__ float4 ld4bf(const unsigned short* hi, const unsigned short* lo, size_t off){
  uint2 h = *(const uint2*)(hi + off);
  uint2 l = *(const uint2*)(lo + off);
  float4 r;
  r.x = bf16_to_f32((unsigned short)(h.x & 0xffffu)) + bf16_to_f32((unsigned short)(l.x & 0xffffu));
  r.y = bf16_to_f32((unsigned short)(h.x >> 16))     + bf16_to_f32((unsigned short)(l.x >> 16));
  r.z = bf16_to_f32((unsigned short)(h.y & 0xffffu)) + bf16_to_f32((unsigned short)(l.y & 0xffffu));
  r.w = bf16_to_f32((unsigned short)(h.y >> 16))     + bf16_to_f32((unsigned short)(l.y >> 16));
  return r;
}

// C/D layout for mfma_f32_32x32x16: col = lane&31, row = (reg&3)+8*(reg>>2)+4*(lane>>5)
#define ROW32(reg, lh) (((reg) & 3) + 8*((reg) >> 2) + 4*(lh))

// ============================ conversion kernels ============================

__global__ __launch_bounds__(256) void cvt_split(const float* __restrict__ src,
                                                 unsigned short* __restrict__ hi,
                                                 unsigned short* __restrict__ lo,
                                                 int nelem)
{
  int idx = (blockIdx.x*256 + threadIdx.x) * 8;
  if (idx >= nelem) return;
  float4 a = *(const float4*)&src[idx];
  float4 b = *(const float4*)&src[idx+4];
  float v[8] = {a.x,a.y,a.z,a.w,b.x,b.y,b.z,b.w};
  short8v hv, lv;
#pragma unroll
  for (int e=0;e<8;++e){
    unsigned short h = bf16_rne(v[e]);
    float hf = bf16_to_f32(h);
    hv[e] = (short)h;
    lv[e] = (short)bf16_rne(v[e] - hf);
  }
  *(short8v*)&hi[idx] = hv;
  *(short8v*)&lo[idx] = lv;
}

__global__ __launch_bounds__(256) void cvt_pad_split(const float* __restrict__ src,
                                                     unsigned short* __restrict__ hi,
                                                     unsigned short* __restrict__ lo,
                                                     int R, int Ksrc, int Kp)
{
  long long e0 = ((long long)blockIdx.x*256 + threadIdx.x) * 4;
  if (e0 >= (long long)R*Kp) return;
  int row = (int)(e0 / Kp), c = (int)(e0 % Kp);
  unsigned short h4[4], l4[4];
  if (c < Ksrc){
    float4 v = *(const float4*)&src[(size_t)row*Ksrc + c];
    float vv[4] = {v.x, v.y, v.z, v.w};
#pragma unroll
    for (int e=0;e<4;++e){
      unsigned short h = bf16_rne(vv[e]);
      h4[e] = h;
      l4[e] = bf16_rne(vv[e] - bf16_to_f32(h));
    }
  } else {
#pragma unroll
    for (int e=0;e<4;++e){ h4[e]=0; l4[e]=0; }
  }
  *(uint2*)&hi[(size_t)row*Kp + c] = *(uint2*)h4;
  *(uint2*)&lo[(size_t)row*Kp + c] = *(uint2*)l4;
}

// Kt[h][slot] = bf16(K[slot][h])
__global__ __launch_bounds__(256) void kt_kernel(const float* __restrict__ K,
                                                 unsigned short* __restrict__ Kt)
{
  __shared__ float tile[64][65];
  const int sb = blockIdx.x * 64;
  const int hb = blockIdx.y * 64;
  const int t = threadIdx.x;
  {
    int r = t >> 2, cq = t & 3;
#pragma unroll
    for (int q=0;q<4;++q){
      float4 v = *(const float4*)&K[(size_t)(sb+r)*HID + hb + cq*16 + q*4];
      tile[r][cq*16+q*4+0]=v.x; tile[r][cq*16+q*4+1]=v.y;
      tile[r][cq*16+q*4+2]=v.z; tile[r][cq*16+q*4+3]=v.w;
    }
  }
  __syncthreads();
  {
    int hl = t >> 2, sq = t & 3;
    unsigned short w16[16];
#pragma unroll
    for (int q=0;q<16;++q) w16[q] = bf16_rne(tile[sq*16+q][hl]);
    *(uint4*)&Kt[(size_t)(hb+hl)*M_SLOTS + sb + sq*16]     = *(uint4*)&w16[0];
    *(uint4*)&Kt[(size_t)(hb+hl)*M_SLOTS + sb + sq*16 + 8] = *(uint4*)&w16[8];
  }
}

__global__ __launch_bounds__(256) void pred_init(float* __restrict__ pred, const float* __restrict__ bd){
  pred[blockIdx.x*256 + threadIdx.x] = bd[0];
}

// ============================ MLP GEMM (3-term split bf16, 32x32x16 MFMA) ============================
__global__ __launch_bounds__(256) void mlp_gemm(
    const unsigned short* __restrict__ Ah_g, const unsigned short* __restrict__ Al_g,
    const unsigned short* __restrict__ Wh_g, const unsigned short* __restrict__ Wl_g,
    const float* __restrict__ bias,
    unsigned short* __restrict__ Ohi, unsigned short* __restrict__ Olo,
    int Kp, const float* __restrict__ Wd, float* __restrict__ predp)
{
  __shared__ char smem[49152];
  unsigned short* Ah = (unsigned short*)smem;            // [64][64] bf16, chunk-swizzled
  unsigned short* Al = (unsigned short*)(smem + 8192);
  unsigned short* Bh = (unsigned short*)(smem + 16384);  // [128][64]
  unsigned short* Bl = (unsigned short*)(smem + 32768);
  const int t = threadIdx.x;
  const int lane = t & 63, w = t >> 6;
  const int l31 = lane & 31, lh = lane >> 5;
  const int rowBase = blockIdx.x * 64;
  const int colBase = blockIdx.y * 128;
  const int wr = (w >> 1) * 32;
  const int wc = (w & 1) * 64;

  f32x16 acc[2];
#pragma unroll
  for (int e=0;e<16;++e){ acc[0][e]=0.f; acc[1][e]=0.f; }

  const int nkt = Kp >> 6;
  for (int kt = 0; kt < nkt; ++kt){
    const int k0 = kt * 64;
#pragma unroll
    for (int p = 0; p < 2; ++p){
      int idx = p*256 + t;
      int r = idx >> 3, c = idx & 7;
      int cc = c ^ (r & 7);
      size_t go = (size_t)(rowBase + r) * Kp + (k0 + cc*8);
      glds16(Ah_g + go, (char*)Ah + idx*16);
      glds16(Al_g + go, (char*)Al + idx*16);
    }
#pragma unroll
    for (int p = 0; p < 4; ++p){
      int idx = p*256 + t;
      int r = idx >> 3, c = idx & 7;
      int cc = c ^ (r & 7);
      size_t go = (size_t)(colBase + r) * Kp + (k0 + cc*8);
      glds16(Wh_g + go, (char*)Bh + idx*16);
      glds16(Wl_g + go, (char*)Bl + idx*16);
    }
    __syncthreads();

#pragma unroll
    for (int ks = 0; ks < 4; ++ks){
      short8v a_h, a_l, b_h[2], b_l[2];
      {
        int r = wr + l31;
        int off = r*128 + ((ks*2 + lh) ^ (r & 7))*16;
        a_h = *(const short8v*)((const char*)Ah + off);
        a_l = *(const short8v*)((const char*)Al + off);
      }
#pragma unroll
      for (int ct = 0; ct < 2; ++ct){
        int r = wc + ct*32 + l31;
        int off = r*128 + ((ks*2 + lh) ^ (r & 7))*16;
        b_h[ct] = *(const short8v*)((const char*)Bh + off);
        b_l[ct] = *(const short8v*)((const char*)Bl + off);
      }
#pragma unroll
      for (int ct = 0; ct < 2; ++ct){
        acc[ct] = __builtin_amdgcn_mfma_f32_32x32x16_bf16(a_h, b_h[ct], acc[ct], 0,0,0);
        acc[ct] = __builtin_amdgcn_mfma_f32_32x32x16_bf16(a_h, b_l[ct], acc[ct], 0,0,0);
        acc[ct] = __builtin_amdgcn_mfma_f32_32x32x16_bf16(a_l, b_h[ct], acc[ct], 0,0,0);
      }
    }
    __syncthreads();
  }

  // epilogue: bias + relu, split hi/lo, stage through LDS for coalesced writes
  float bcol[2];
#pragma unroll
  for (int ct=0; ct<2; ++ct) bcol[ct] = bias[colBase + wc + ct*32 + l31];
  unsigned short* Sout = (unsigned short*)smem;  // [64][136]
#pragma unroll
  for (int ct=0; ct<2; ++ct)
#pragma unroll
    for (int reg=0; reg<16; ++reg){
      float v = acc[ct][reg] + bcol[ct];
      v = v > 0.f ? v : 0.f;
      acc[ct][reg] = v;
      Sout[(wr + ROW32(reg,lh))*136 + wc + ct*32 + l31] = bf16_rne(v);
    }

  // fused pred partial (last layer only)
  if (predp){
    float wdv[2];
#pragma unroll
    for (int ct=0; ct<2; ++ct) wdv[ct] = Wd[colBase + wc + ct*32 + l31];
#pragma unroll
    for (int reg=0; reg<16; ++reg){
      float pd = acc[0][reg]*wdv[0] + acc[1][reg]*wdv[1];
#pragma unroll
      for (int d=1; d<32; d<<=1) pd += __shfl_xor(pd, d);
      if (l31 == 0)
        atomicAdd(&predp[rowBase + wr + ROW32(reg,lh)], pd);
    }
  }

  __syncthreads();
#pragma unroll
  for (int p = 0; p < 4; ++p){
    int row = (t >> 4) + p*16;
    int c8 = (t & 15) * 8;
    uint4 v = *(uint4*)&Sout[row*136 + c8];
    *(uint4*)&Ohi[(size_t)(rowBase+row)*HID + colBase + c8] = v;
  }
  __syncthreads();
#pragma unroll
  for (int ct=0; ct<2; ++ct)
#pragma unroll
    for (int reg=0; reg<16; ++reg){
      float v = acc[ct][reg];
      unsigned short h = bf16_rne(v);
      Sout[(wr + ROW32(reg,lh))*136 + wc + ct*32 + l31] = bf16_rne(v - bf16_to_f32(h));
    }
  __syncthreads();
#pragma unroll
  for (int p = 0; p < 4; ++p){
    int row = (t >> 4) + p*16;
    int c8 = (t & 15) * 8;
    uint4 v = *(uint4*)&Sout[row*136 + c8];
    *(uint4*)&Olo[(size_t)(rowBase+row)*HID + colBase + c8] = v;
  }
}

// ============================ S GEMM + stats (32x32x16 MFMA) ============================
// BM=64 x BN=128, BK=64; all four operands LDS-staged. grid (16, 256).
__global__ __launch_bounds__(256) void sgemm_stats(
    const unsigned short* __restrict__ Qhi, const unsigned short* __restrict__ Qlo,
    const unsigned short* __restrict__ Khi, const unsigned short* __restrict__ Klo,
    unsigned short* __restrict__ Sb,
    float* __restrict__ pmax, int* __restrict__ pcol,
    float* __restrict__ psum, float* __restrict__ pnmax, float* __restrict__ pnsum,
    float* __restrict__ pcolmax)
{
  __shared__ char smem[49152];
  unsigned short* Ah = (unsigned short*)smem;
  unsigned short* Al = (unsigned short*)(smem + 8192);
  unsigned short* Bh = (unsigned short*)(smem + 16384);
  unsigned short* Bl = (unsigned short*)(smem + 32768);
  const int t = threadIdx.x;
  const int lane = t & 63, w = t >> 6;
  const int l31 = lane & 31, lh = lane >> 5;
  const int cb = blockIdx.x;      // 0..15  col block
  const int rb = blockIdx.y;      // 0..255 row block
  const int rowBase = rb * 64;
  const int colBase = cb * 128;
  const int wr = (w >> 1) * 32;
  const int wc = (w & 1) * 64;

  f32x16 acc[2];
#pragma unroll
  for (int e=0;e<16;++e){ acc[0][e]=0.f; acc[1][e]=0.f; }

  for (int kt = 0; kt < 8; ++kt){
    const int k0 = kt * 64;
#pragma unroll
    for (int p = 0; p < 2; ++p){
      int idx = p*256 + t;
      int r = idx >> 3, c = idx & 7;
      int cc = c ^ (r & 7);
      size_t go = (size_t)(rowBase + r) * HID + (k0 + cc*8);
      glds16(Qhi + go, (char*)Ah + idx*16);
      glds16(Qlo + go, (char*)Al + idx*16);
    }
#pragma unroll
    for (int p = 0; p < 4; ++p){
      int idx = p*256 + t;
      int r = idx >> 3, c = idx & 7;
      int cc = c ^ (r & 7);
      size_t go = (size_t)(colBase + r) * HID + (k0 + cc*8);
      glds16(Khi + go, (char*)Bh + idx*16);
      glds16(Klo + go, (char*)Bl + idx*16);
    }
    __syncthreads();

#pragma unroll
    for (int ks = 0; ks < 4; ++ks){
      short8v a_h, a_l, b_h[2], b_l[2];
      {
        int r = wr + l31;
        int off = r*128 + ((ks*2 + lh) ^ (r & 7))*16;
        a_h = *(const short8v*)((const char*)Ah + off);
        a_l = *(const short8v*)((const char*)Al + off);
      }
#pragma unroll
      for (int ct = 0; ct < 2; ++ct){
        int r = wc + ct*32 + l31;
        int off = r*128 + ((ks*2 + lh) ^ (r & 7))*16;
        b_h[ct] = *(const short8v*)((const char*)Bh + off);
        b_l[ct] = *(const short8v*)((const char*)Bl + off);
      }
#pragma unroll
      for (int ct = 0; ct < 2; ++ct){
        acc[ct] = __builtin_amdgcn_mfma_f32_32x32x16_bf16(a_h, b_h[ct], acc[ct], 0,0,0);
        acc[ct] = __builtin_amdgcn_mfma_f32_32x32x16_bf16(a_h, b_l[ct], acc[ct], 0,0,0);
        acc[ct] = __builtin_amdgcn_mfma_f32_32x32x16_bf16(a_l, b_h[ct], acc[ct], 0,0,0);
      }
    }
    __syncthreads();
  }

  // ---- row stats (per wave over its 64-col half; rows = wr + ROW32(reg,lh)) ----
#pragma unroll
  for (int reg = 0; reg < 16; ++reg){
    float v0 = acc[0][reg], v1 = acc[1][reg];
    float bvv = v0; int bcc = colBase + wc + l31;
    if (v1 > bvv){ bvv = v1; bcc = colBase + wc + 32 + l31; }
    float mnv = fminf(v0, v1);
#pragma unroll
    for (int d = 1; d < 32; d <<= 1){
      float ov = __shfl_xor(bvv, d);
      int   oc = __shfl_xor(bcc, d);
      float om = __shfl_xor(mnv, d);
      if (ov > bvv || (ov == bvv && oc < bcc)){ bvv = ov; bcc = oc; }
      mnv = fminf(mnv, om);
    }
    float sp = __expf(v0 - bvv) + __expf(v1 - bvv);
    float sn = __expf(mnv - v0) + __expf(mnv - v1);
#pragma unroll
    for (int d = 1; d < 32; d <<= 1){ sp += __shfl_xor(sp, d); sn += __shfl_xor(sn, d); }
    if (l31 == 0){
      int row = rowBase + wr + ROW32(reg, lh);
      size_t pi = (size_t)row*32 + cb*2 + (w & 1);
      pmax[pi] = bvv; pcol[pi] = bcc; psum[pi] = sp;
      pnmax[pi] = -mnv; pnsum[pi] = sn;
    }
  }

  // ---- per-column tile max (over this wave's 32 rows) ----
#pragma unroll
  for (int ct = 0; ct < 2; ++ct){
    float cm = -1e30f;
#pragma unroll
    for (int reg=0; reg<16; ++reg) cm = fmaxf(cm, acc[ct][reg]);
    cm = fmaxf(cm, __shfl_xor(cm, 32));
    if (lh == 0)
      pcolmax[(size_t)(rb*2 + (w>>1))*M_SLOTS + colBase + wc + ct*32 + l31] = cm;
  }

  // ---- S bf16 write (staged through LDS for coalescing) ----
  __syncthreads();
  unsigned short* Sout = (unsigned short*)smem;  // [64][136]
#pragma unroll
  for (int ct=0; ct<2; ++ct)
#pragma unroll
    for (int reg=0; reg<16; ++reg)
      Sout[(wr + ROW32(reg,lh))*136 + wc + ct*32 + l31] = bf16_rne(acc[ct][reg]);
  __syncthreads();
#pragma unroll
  for (int p = 0; p < 4; ++p){
    int row = (t >> 4) + p*16;
    int c8 = (t & 15) * 8;
    uint4 v = *(uint4*)&Sout[row*136 + c8];
    *(uint4*)&Sb[(size_t)(rowBase+row)*M_SLOTS + colBase + c8] = v;
  }
}

// fused merge_rows (blocks 0..63) + merge_cols (blocks 64..71)
__global__ __launch_bounds__(256) void merge_all(
    const float* __restrict__ pmax, const int* __restrict__ pcol,
    const float* __restrict__ psum, const float* __restrict__ pnmax,
    const float* __restrict__ pnsum, const float* __restrict__ pcolmax,
    float* __restrict__ rowm, float* __restrict__ rsp,
    float* __restrict__ rmn, float* __restrict__ rsn, int* __restrict__ gidx,
    int* __restrict__ cnt, float* __restrict__ colmax)
{
  if (blockIdx.x < 64){
    int row = blockIdx.x*256 + threadIdx.x;
    const size_t base = (size_t)row*32;
    float m = -1e30f; int g = 0;
    for (int i=0;i<32;++i){
      float v = pmax[base+i];
      if (v > m){ m = v; g = pcol[base+i]; }
    }
    float s = 0.f;
    for (int i=0;i<32;++i) s += psum[base+i] * __expf(pmax[base+i]-m);
    float mn = -1e30f;
    for (int i=0;i<32;++i) mn = fmaxf(mn, pnmax[base+i]);
    float sn = 0.f;
    for (int i=0;i<32;++i) sn += pnsum[base+i] * __expf(pnmax[base+i]-mn);
    rowm[row]=m; gidx[row]=g; rsp[row]=1.f/s; rmn[row]=mn; rsn[row]=1.f/sn;
    atomicAdd(&cnt[g], 1);
  } else {
    int c = (blockIdx.x - 64)*256 + threadIdx.x;
    float m = -1e30f;
    for (int r=0;r<512;++r) m = fmaxf(m, pcolmax[(size_t)r*M_SLOTS + c]);
    colmax[c] = m;
  }
}

// ============================ PV (S read once, 32x32x16 MFMA) ============================
#define PV_RB 32
#define PV_HB 256
__global__ __launch_bounds__(256, 3) void pv2(
    const unsigned short* __restrict__ Sb, const unsigned short* __restrict__ Kt,
    const float* __restrict__ rowm, const float* __restrict__ rsp,
    const float* __restrict__ rmn, const float* __restrict__ rsn,
    const unsigned short* __restrict__ Qhi, const unsigned short* __restrict__ Qlo,
    float* __restrict__ outP, float* __restrict__ outN)
{
  __shared__ char smem[40960];
  unsigned short* Ktile = (unsigned short*)smem;          // [256 h][64 slots], chunk-swizzled, 32KB
  unsigned short* Wp = (unsigned short*)(smem + 32768);   // [octet 0..7][row 0..31] 16B chunks, 4KB
  unsigned short* Wn = (unsigned short*)(smem + 36864);   // 4KB
  const int t = threadIdx.x, lane = t & 63, w = t >> 6;
  const int l31 = lane & 31, lh = lane >> 5;
  const int rowBase = blockIdx.y * PV_RB;
  const int hBase = blockIdx.x * PV_HB;
  const int hw = w * 64;
  const int rS = t >> 3;          // row for weight computation (coalesced S read)
  const int c8 = t & 7;           // slot-octet
  const float mp = rowm[rowBase + rS], mn = rmn[rowBase + rS];

  f32x16 accP[2], accN[2];
#pragma unroll
  for (int e=0;e<16;++e){ accP[0][e]=0.f; accP[1][e]=0.f; accN[0][e]=0.f; accN[1][e]=0.f; }

  for (int kt = 0; kt < 32; ++kt){
    const int k0 = kt*64;
#pragma unroll
    for (int p=0;p<8;++p){
      int idx = p*256 + t;
      int r = idx >> 3, c = idx & 7;
      int cc = c ^ (r & 7);
      glds16(Kt + (size_t)(hBase + r)*M_SLOTS + k0 + cc*8, (char*)Ktile + idx*16);
    }
    // exp-weights for this k-tile (32 rows x 64 slots, shared by all waves)
    short8v sv = *(const short8v*)&Sb[(size_t)(rowBase + rS)*M_SLOTS + k0 + c8*8];
    short8v wp, wn;
#pragma unroll
    for (int e=0;e<8;++e){
      float sval = bf16_to_f32((unsigned short)sv[e]);
      wp[e] = (short)bf16_rne(__expf(sval - mp));
      wn[e] = (short)bf16_rne(__expf(-sval - mn));
    }
    *(short8v*)(Wp + (c8*32 + rS)*8) = wp;
    *(short8v*)(Wn + (c8*32 + rS)*8) = wn;
    __syncthreads();
#pragma unroll
    for (int ks=0; ks<4; ++ks){
      int oct = ks*2 + lh;
      short8v ap = *(const short8v*)(Wp + (oct*32 + l31)*8);
      short8v an = *(const short8v*)(Wn + (oct*32 + l31)*8);
#pragma unroll
      for (int ct=0; ct<2; ++ct){
        int hr = hw + ct*32 + l31;
        short8v b = *(const short8v*)((const char*)Ktile + hr*128 + ((oct ^ (hr & 7))*16));
        accP[ct] = __builtin_amdgcn_mfma_f32_32x32x16_bf16(ap, b, accP[ct], 0,0,0);
        accN[ct] = __builtin_amdgcn_mfma_f32_32x32x16_bf16(an, b, accN[ct], 0,0,0);
      }
    }
    __syncthreads();
  }

  // epilogue: scale, gate by Q (hi+lo), write via LDS staging
  float isp[16], isn[16];
#pragma unroll
  for (int reg=0; reg<16; ++reg){
    int row = rowBase + ROW32(reg, lh);
    isp[reg] = rsp[row];
    isn[reg] = rsn[row];
  }
  float* Pout = (float*)smem;   // [32][260]
#pragma unroll
  for (int ct=0; ct<2; ++ct)
#pragma unroll
    for (int reg=0; reg<16; ++reg)
      Pout[ROW32(reg,lh)*260 + hw + ct*32 + l31] = accP[ct][reg]*isp[reg];
  __syncthreads();
#pragma unroll
  for (int i=0;i<8;++i){
    int row = t >> 3;
    int col = (t & 7)*4 + i*32;
    float4 pv = *(float4*)&Pout[row*260 + col];
    float4 qv = ld4bf(Qhi, Qlo, (size_t)(rowBase+row)*HID + hBase + col);
    float4 o; o.x=pv.x*qv.x; o.y=pv.y*qv.y; o.z=pv.z*qv.z; o.w=pv.w*qv.w;
    *(float4*)&outP[(size_t)(rowBase+row)*HID + hBase + col] = o;
  }
  __syncthreads();
#pragma unroll
  for (int ct=0; ct<2; ++ct)
#pragma unroll
    for (int reg=0; reg<16; ++reg)
      Pout[ROW32(reg,lh)*260 + hw + ct*32 + l31] = accN[ct][reg]*isn[reg];
  __syncthreads();
#pragma unroll
  for (int i=0;i<8;++i){
    int row = t >> 3;
    int col = (t & 7)*4 + i*32;
    float4 pv = *(float4*)&Pout[row*260 + col];
    float4 qv = ld4bf(Qhi, Qlo, (size_t)(rowBase+row)*HID + hBase + col);
    float4 o; o.x=pv.x*qv.x; o.y=pv.y*qv.y; o.z=pv.z*qv.z; o.w=pv.w*qv.w;
    *(float4*)&outN[(size_t)(rowBase+row)*HID + hBase + col] = o;
  }
}

// ============================ CSR upload (skew-independent) ============================

__global__ __launch_bounds__(256) void csr_scan(const int* __restrict__ cnt,
                                                int* __restrict__ off, int* __restrict__ woff){
  __shared__ int partial[256];
  const int t = threadIdx.x;
  const int base = t*8;
  int local[8]; int s = 0;
#pragma unroll
  for (int j=0;j<8;++j){ local[j] = s; s += cnt[base+j]; }
  partial[t] = s;
  __syncthreads();
  for (int d=1; d<256; d<<=1){
    int v = (t>=d) ? partial[t-d] : 0;
    __syncthreads();
    partial[t] += v;
    __syncthreads();
  }
  int pre = (t==0) ? 0 : partial[t-1];
#pragma unroll
  for (int j=0;j<8;++j){ int o = pre + local[j]; off[base+j]=o; woff[base+j]=o; }
  if (t==255) off[2048] = partial[255];
}

__global__ __launch_bounds__(256) void csr_fill(const int* __restrict__ gidx,
                                                const float* __restrict__ rowm,
                                                const float* __restrict__ colmax,
                                                int* __restrict__ woff,
                                                int* __restrict__ rows, float* __restrict__ wv,
                                                int* __restrict__ sid){
  int i = blockIdx.x*256 + threadIdx.x;
  int g = gidx[i];
  int p = atomicAdd(&woff[g], 1);
  rows[p] = i;
  wv[p] = __expf(rowm[i] - colmax[g]);
  sid[p] = g;
}

__global__ __launch_bounds__(256) void upload_scatter(
    const unsigned short* __restrict__ Qhi, const unsigned short* __restrict__ Qlo,
    const int* __restrict__ sid, const int* __restrict__ rows, const float* __restrict__ wv,
    const int* __restrict__ train, float* __restrict__ qacc)
{
  if (*train == 0) return;
  const int b = blockIdx.x, t = threadIdx.x;
  __shared__ int   s_sid[64];
  __shared__ int   s_row[64];
  __shared__ float s_w[64];
  if (t < 64){
    int p = b*64 + t;
    s_sid[t] = sid[p];
    s_row[t] = rows[p];
    s_w[t]   = wv[p];
  }
  __syncthreads();
  const int h0 = t*2;
  float a0 = 0.f, a1 = 0.f;
  int prev = s_sid[0];
#pragma unroll 4
  for (int p = 0; p < 64; ++p){
    int s = s_sid[p];
    if (s != prev){
      atomicAdd(&qacc[(size_t)prev*HID + h0],     a0);
      atomicAdd(&qacc[(size_t)prev*HID + h0 + 1], a1);
      a0 = 0.f; a1 = 0.f; prev = s;
    }
    int row = s_row[p];
    float w = s_w[p];
    unsigned h = *(const unsigned*)(Qhi + (size_t)row*HID + h0);
    unsigned l = *(const unsigned*)(Qlo + (size_t)row*HID + h0);
    a0 += w * (bf16_to_f32((unsigned short)(h & 0xffffu)) + bf16_to_f32((unsigned short)(l & 0xffffu)));
    a1 += w * (bf16_to_f32((unsigned short)(h >> 16))     + bf16_to_f32((unsigned short)(l >> 16)));
  }
  atomicAdd(&qacc[(size_t)prev*HID + h0],     a0);
  atomicAdd(&qacc[(size_t)prev*HID + h0 + 1], a1);
}

__global__ __launch_bounds__(256) void upload_finish(const float* __restrict__ qacc,
                                                     const float* __restrict__ Km,
                                                     const int* __restrict__ train,
                                                     float* __restrict__ mem)
{
  const int m = blockIdx.x, t = threadIdx.x;
  const int h0 = t * 2;
  float2 kv = *(const float2*)&Km[(size_t)m*HID + h0];
  if (*train == 0){
    mem[(size_t)m*HID + h0]     = kv.x;
    mem[(size_t)m*HID + h0 + 1] = kv.y;
    return;
  }
  float2 av = *(const float2*)&qacc[(size_t)m*HID + h0];
  float v0 = av.x + kv.x, v1 = av.y + kv.y;
  __shared__ float red[256];
  red[t] = v0*v0 + v1*v1;
  __syncthreads();
  for (int s = 128; s > 0; s >>= 1){
    if (t < s) red[t] += red[t + s];
    __syncthreads();
  }
  float rinv = 1.f / fmaxf(sqrtf(red[0]), 1e-12f);
  mem[(size_t)m*HID + h0]     = v0 * rinv;
  mem[(size_t)m*HID + h0 + 1] = v1 * rinv;
}

// ============================ host ============================

extern "C" void kernel_launch(void* const* d_in, const int* in_sizes, int n_in,
                              void* d_out, int out_size, void* d_ws, size_t ws_size,
                              hipStream_t stream)
{
  const float* x   = (const float*)d_in[0];
  const float* Km  = (const float*)d_in[1];
  const float* W1  = (const float*)d_in[2];
  const float* b1  = (const float*)d_in[3];
  const float* W2  = (const float*)d_in[4];
  const float* b2  = (const float*)d_in[5];
  const float* W3  = (const float*)d_in[6];
  const float* b3  = (const float*)d_in[7];
  const float* Wd  = (const float*)d_in[8];
  const float* bd  = (const float*)d_in[9];
  const int* train = (const int*)d_in[10];

  float* out  = (float*)d_out;
  float* pred = out;
  float* outN = out + 16384;
  float* outP = out + 16384 + 8388608;
  float* memo = out + 16384 + 2*8388608;

  char* ws = (char*)d_ws;
  unsigned short* Qhi   = (unsigned short*)(ws + 0);           // 16,777,216
  unsigned short* Qlo   = (unsigned short*)(ws + 16777216);    // 16,777,216
  unsigned short* xph   = (unsigned short*)(ws + 33554432);    // 12,582,912
  unsigned short* xpl   = (unsigned short*)(ws + 46137344);    // 12,582,912
  unsigned short* h1h   = (unsigned short*)(ws + 58720256);    // 16,777,216
  unsigned short* h1l   = (unsigned short*)(ws + 75497472);    // 16,777,216
  unsigned short* h2h   = (unsigned short*)(ws + 92274688);    // 16,777,216
  unsigned short* h2l   = (unsigned short*)(ws + 109051904);   // 16,777,216 (R0 end 125,829,120)
  unsigned short* Sb    = (unsigned short*)(ws + 33554432);    // 67,108,864 (aliases R0)
  unsigned short* Khi   = (unsigned short*)(ws + 125829120);   //  2,097,152
  unsigned short* Klo   = (unsigned short*)(ws + 127926272);   //  2,097,152
  unsigned short* Kt    = (unsigned short*)(ws + 130023424);   //  2,097,152
  unsigned short* W1ph  = (unsigned short*)(ws + 132120576);   //    393,216
  unsigned short* W1pl  = (unsigned short*)(ws + 132513792);   //    393,216
  unsigned short* W2h   = (unsigned short*)(ws + 132907008);   //    524,288
  unsigned short* W2l   = (unsigned short*)(ws + 133431296);   //    524,288
  unsigned short* W3h   = (unsigned short*)(ws + 133955584);   //    524,288
  unsigned short* W3l   = (unsigned short*)(ws + 134479872);   //    524,288
  float* pmax    = (float*)(ws + 135004160);                   //  2,097,152
  int*   pcol    = (int*)  (ws + 137101312);                   //  2,097,152
  float* psum    = (float*)(ws + 139198464);                   //  2,097,152
  float* pnmax   = (float*)(ws + 141295616);                   //  2,097,152
  float* pnsum   = (float*)(ws + 143392768);                   //  2,097,152
  float* pcolmax = (float*)(ws + 145489920);                   //  4,194,304 (512 rows)
  float* rowm    = (float*)(ws + 149684224);
  float* rsp     = (float*)(ws + 149749760);
  float* rmn     = (float*)(ws + 149815296);
  float* rsn     = (float*)(ws + 149880832);
  int*   gidx    = (int*)  (ws + 149946368);
  float* colmax  = (float*)(ws + 150011904);
  int*   cnt     = (int*)  (ws + 150020096);                   //      8,192
  int*   off     = (int*)  (ws + 150028288);                   //      8,448 (2049 ints)
  int*   woff    = (int*)  (ws + 150036736);                   //      8,192
  int*   rows    = (int*)  (ws + 150044928);                   //     65,536
  float* wv      = (float*)(ws + 150110464);                   //     65,536
  int*   sid     = (int*)  (ws + 150176000);                   //     65,536
  float* qacc    = (float*)(ws + 150241536);                   //  4,194,304
  const size_t NEED = 154435840ull;
  if (ws_size < NEED) return;  // harness provides >= 155 MB (proven round 2)

  dim3 blk(256);
  // conversions
  cvt_pad_split<<<(N_ROWS*KP1/4 + 255)/256, blk, 0, stream>>>(x,  xph,  xpl,  N_ROWS, D_INN, KP1);
  cvt_pad_split<<<(HID*KP1/4 + 255)/256,    blk, 0, stream>>>(W1, W1ph, W1pl, HID,    D_INN, KP1);
  cvt_split<<<HID*HID/2048,     blk, 0, stream>>>(W2, W2h, W2l, HID*HID);
  cvt_split<<<HID*HID/2048,     blk, 0, stream>>>(W3, W3h, W3l, HID*HID);
  cvt_split<<<M_SLOTS*HID/2048, blk, 0, stream>>>(Km, Khi, Klo, M_SLOTS*HID);
  kt_kernel<<<dim3(32, 8), blk, 0, stream>>>(Km, Kt);

  // MLP (split-bf16 MFMA); layer 3 fuses the pred dot (pred pre-init'd to bd)
  mlp_gemm<<<dim3(N_ROWS/64, 4), blk, 0, stream>>>(xph, xpl, W1ph, W1pl, b1, h1h, h1l, KP1,
                                                   (const float*)nullptr, (float*)nullptr);
  mlp_gemm<<<dim3(N_ROWS/64, 4), blk, 0, stream>>>(h1h, h1l, W2h, W2l, b2, h2h, h2l, HID,
                                                   (const float*)nullptr, (float*)nullptr);
  pred_init<<<N_ROWS/256, blk, 0, stream>>>(pred, bd);
  mlp_gemm<<<dim3(N_ROWS/64, 4), blk, 0, stream>>>(h2h, h2l, W3h, W3l, b3, Qhi, Qlo, HID,
                                                   Wd, pred);

  // attention stats + PV
  sgemm_stats<<<dim3(16, 256), blk, 0, stream>>>(Qhi, Qlo, Khi, Klo, Sb,
                                                 pmax, pcol, psum, pnmax, pnsum, pcolmax);
  hipMemsetAsync(cnt, 0, M_SLOTS*sizeof(int), stream);
  merge_all<<<72, blk, 0, stream>>>(pmax, pcol, psum, pnmax, pnsum, pcolmax,
                                    rowm, rsp, rmn, rsn, gidx, cnt, colmax);
  pv2<<<dim3(2, 512), blk, 0, stream>>>(Sb, Kt, rowm, rsp, rmn, rsn, Qhi, Qlo, outP, outN);

  // upload via CSR + bounded scatter
  hipMemsetAsync(qacc, 0, M_SLOTS*HID*sizeof(float), stream);
  csr_scan<<<1, blk, 0, stream>>>(cnt, off, woff);
  csr_fill<<<N_ROWS/256, blk, 0, stream>>>(gidx, rowm, colmax, woff, rows, wv, sid);
  upload_scatter<<<N_ROWS/64, blk, 0, stream>>>(Qhi, Qlo, sid, rows, wv, train, qacc);
  upload_finish<<<M_SLOTS, blk, 0, stream>>>(qacc, Km, train, memo);
}

// Round 10
// 579.599 us; speedup vs baseline: 1.0884x; 1.0884x over previous
//
#include <hip/hip_runtime.h>
#include <math.h>

// Problem constants (fixed by the reference).
#define N_ROWS 16384
#define D_INN  360
#define KP1    384      // D_INN padded to multiple of 64
#define HID    512
#define M_SLOTS 2048

typedef __attribute__((ext_vector_type(8))) short short8v;
typedef __attribute__((ext_vector_type(4))) float f32x4;
typedef __attribute__((ext_vector_type(16))) float f32x16;
typedef __attribute__((address_space(1))) unsigned int as1_uint;
typedef __attribute__((address_space(3))) unsigned int as3_uint;

// ---- bf16 helpers (manual, RNE) ----
__device__ __forceinline__ unsigned short bf16_rne(float f){
  unsigned u = __float_as_uint(f);
  unsigned r = u + 0x7FFFu + ((u >> 16) & 1u);
  return (unsigned short)(r >> 16);
}
__device__ __forceinline__ float bf16_to_f32(unsigned short h){
  return __uint_as_float(((unsigned)h) << 16);
}

__device__ __forceinline__ void glds16(const void* g, void* l){
  __builtin_amdgcn_global_load_lds((const as1_uint*)g, (as3_uint*)l, 16, 0, 0);
}

// reconstruct 4 consecutive f32 from hi/lo bf16 pair arrays
__device__ __forceinline__ float4 ld4bf(const unsigned short* hi, const unsigned short* lo, size_t off){
  uint2 h = *(const uint2*)(hi + off);
  uint2 l = *(const uint2*)(lo + off);
  float4 r;
  r.x = bf16_to_f32((unsigned short)(h.x & 0xffffu)) + bf16_to_f32((unsigned short)(l.x & 0xffffu));
  r.y = bf16_to_f32((unsigned short)(h.x >> 16))     + bf16_to_f32((unsigned short)(l.x >> 16));
  r.z = bf16_to_f32((unsigned short)(h.y & 0xffffu)) + bf16_to_f32((unsigned short)(l.y & 0xffffu));
  r.w = bf16_to_f32((unsigned short)(h.y >> 16))     + bf16_to_f32((unsigned short)(l.y >> 16));
  return r;
}

// C/D layout for mfma_f32_32x32x16: col = lane&31, row = (reg&3)+8*(reg>>2)+4*(lane>>5)
#define ROW32(reg, lh) (((reg) & 3) + 8*((reg) >> 2) + 4*(lh))

// ============================ conversion kernels ============================

__global__ __launch_bounds__(256) void cvt_split(const float* __restrict__ src,
                                                 unsigned short* __restrict__ hi,
                                                 unsigned short* __restrict__ lo,
                                                 int nelem)
{
  int idx = (blockIdx.x*256 + threadIdx.x) * 8;
  if (idx >= nelem) return;
  float4 a = *(const float4*)&src[idx];
  float4 b = *(const float4*)&src[idx+4];
  float v[8] = {a.x,a.y,a.z,a.w,b.x,b.y,b.z,b.w};
  short8v hv, lv;
#pragma unroll
  for (int e=0;e<8;++e){
    unsigned short h = bf16_rne(v[e]);
    float hf = bf16_to_f32(h);
    hv[e] = (short)h;
    lv[e] = (short)bf16_rne(v[e] - hf);
  }
  *(short8v*)&hi[idx] = hv;
  *(short8v*)&lo[idx] = lv;
}

__global__ __launch_bounds__(256) void cvt_pad_split(const float* __restrict__ src,
                                                     unsigned short* __restrict__ hi,
                                                     unsigned short* __restrict__ lo,
                                                     int R, int Ksrc, int Kp)
{
  long long e0 = ((long long)blockIdx.x*256 + threadIdx.x) * 4;
  if (e0 >= (long long)R*Kp) return;
  int row = (int)(e0 / Kp), c = (int)(e0 % Kp);
  unsigned short h4[4], l4[4];
  if (c < Ksrc){
    float4 v = *(const float4*)&src[(size_t)row*Ksrc + c];
    float vv[4] = {v.x, v.y, v.z, v.w};
#pragma unroll
    for (int e=0;e<4;++e){
      unsigned short h = bf16_rne(vv[e]);
      h4[e] = h;
      l4[e] = bf16_rne(vv[e] - bf16_to_f32(h));
    }
  } else {
#pragma unroll
    for (int e=0;e<4;++e){ h4[e]=0; l4[e]=0; }
  }
  *(uint2*)&hi[(size_t)row*Kp + c] = *(uint2*)h4;
  *(uint2*)&lo[(size_t)row*Kp + c] = *(uint2*)l4;
}

// Kt[h][slot] = bf16(K[slot][h])
__global__ __launch_bounds__(256) void kt_kernel(const float* __restrict__ K,
                                                 unsigned short* __restrict__ Kt)
{
  __shared__ float tile[64][65];
  const int sb = blockIdx.x * 64;
  const int hb = blockIdx.y * 64;
  const int t = threadIdx.x;
  {
    int r = t >> 2, cq = t & 3;
#pragma unroll
    for (int q=0;q<4;++q){
      float4 v = *(const float4*)&K[(size_t)(sb+r)*HID + hb + cq*16 + q*4];
      tile[r][cq*16+q*4+0]=v.x; tile[r][cq*16+q*4+1]=v.y;
      tile[r][cq*16+q*4+2]=v.z; tile[r][cq*16+q*4+3]=v.w;
    }
  }
  __syncthreads();
  {
    int hl = t >> 2, sq = t & 3;
    unsigned short w16[16];
#pragma unroll
    for (int q=0;q<16;++q) w16[q] = bf16_rne(tile[sq*16+q][hl]);
    *(uint4*)&Kt[(size_t)(hb+hl)*M_SLOTS + sb + sq*16]     = *(uint4*)&w16[0];
    *(uint4*)&Kt[(size_t)(hb+hl)*M_SLOTS + sb + sq*16 + 8] = *(uint4*)&w16[8];
  }
}

// ============================ MLP GEMM (3-term split bf16, 32x32x16 MFMA) ============================
__global__ __launch_bounds__(256) void mlp_gemm(
    const unsigned short* __restrict__ Ah_g, const unsigned short* __restrict__ Al_g,
    const unsigned short* __restrict__ Wh_g, const unsigned short* __restrict__ Wl_g,
    const float* __restrict__ bias,
    unsigned short* __restrict__ Ohi, unsigned short* __restrict__ Olo,
    int Kp)
{
  __shared__ char smem[49152];
  unsigned short* Ah = (unsigned short*)smem;            // [64][64] bf16, chunk-swizzled
  unsigned short* Al = (unsigned short*)(smem + 8192);
  unsigned short* Bh = (unsigned short*)(smem + 16384);  // [128][64]
  unsigned short* Bl = (unsigned short*)(smem + 32768);
  const int t = threadIdx.x;
  const int lane = t & 63, w = t >> 6;
  const int l31 = lane & 31, lh = lane >> 5;
  const int rowBase = blockIdx.x * 64;
  const int colBase = blockIdx.y * 128;
  const int wr = (w >> 1) * 32;
  const int wc = (w & 1) * 64;

  f32x16 acc[2];
#pragma unroll
  for (int e=0;e<16;++e){ acc[0][e]=0.f; acc[1][e]=0.f; }

  const int nkt = Kp >> 6;
  for (int kt = 0; kt < nkt; ++kt){
    const int k0 = kt * 64;
#pragma unroll
    for (int p = 0; p < 2; ++p){
      int idx = p*256 + t;
      int r = idx >> 3, c = idx & 7;
      int cc = c ^ (r & 7);
      size_t go = (size_t)(rowBase + r) * Kp + (k0 + cc*8);
      glds16(Ah_g + go, (char*)Ah + idx*16);
      glds16(Al_g + go, (char*)Al + idx*16);
    }
#pragma unroll
    for (int p = 0; p < 4; ++p){
      int idx = p*256 + t;
      int r = idx >> 3, c = idx & 7;
      int cc = c ^ (r & 7);
      size_t go = (size_t)(colBase + r) * Kp + (k0 + cc*8);
      glds16(Wh_g + go, (char*)Bh + idx*16);
      glds16(Wl_g + go, (char*)Bl + idx*16);
    }
    __syncthreads();

#pragma unroll
    for (int ks = 0; ks < 4; ++ks){
      short8v a_h, a_l, b_h[2], b_l[2];
      {
        int r = wr + l31;
        int off = r*128 + ((ks*2 + lh) ^ (r & 7))*16;
        a_h = *(const short8v*)((const char*)Ah + off);
        a_l = *(const short8v*)((const char*)Al + off);
      }
#pragma unroll
      for (int ct = 0; ct < 2; ++ct){
        int r = wc + ct*32 + l31;
        int off = r*128 + ((ks*2 + lh) ^ (r & 7))*16;
        b_h[ct] = *(const short8v*)((const char*)Bh + off);
        b_l[ct] = *(const short8v*)((const char*)Bl + off);
      }
#pragma unroll
      for (int ct = 0; ct < 2; ++ct){
        acc[ct] = __builtin_amdgcn_mfma_f32_32x32x16_bf16(a_h, b_h[ct], acc[ct], 0,0,0);
        acc[ct] = __builtin_amdgcn_mfma_f32_32x32x16_bf16(a_h, b_l[ct], acc[ct], 0,0,0);
        acc[ct] = __builtin_amdgcn_mfma_f32_32x32x16_bf16(a_l, b_h[ct], acc[ct], 0,0,0);
      }
    }
    __syncthreads();
  }

  // epilogue: bias + relu, split hi/lo, stage through LDS for coalesced writes
  float bcol[2];
#pragma unroll
  for (int ct=0; ct<2; ++ct) bcol[ct] = bias[colBase + wc + ct*32 + l31];
  unsigned short* Sout = (unsigned short*)smem;  // [64][136]
#pragma unroll
  for (int ct=0; ct<2; ++ct)
#pragma unroll
    for (int reg=0; reg<16; ++reg){
      float v = acc[ct][reg] + bcol[ct];
      v = v > 0.f ? v : 0.f;
      acc[ct][reg] = v;
      Sout[(wr + ROW32(reg,lh))*136 + wc + ct*32 + l31] = bf16_rne(v);
    }
  __syncthreads();
#pragma unroll
  for (int p = 0; p < 4; ++p){
    int row = (t >> 4) + p*16;
    int c8 = (t & 15) * 8;
    uint4 v = *(uint4*)&Sout[row*136 + c8];
    *(uint4*)&Ohi[(size_t)(rowBase+row)*HID + colBase + c8] = v;
  }
  __syncthreads();
#pragma unroll
  for (int ct=0; ct<2; ++ct)
#pragma unroll
    for (int reg=0; reg<16; ++reg){
      float v = acc[ct][reg];
      unsigned short h = bf16_rne(v);
      Sout[(wr + ROW32(reg,lh))*136 + wc + ct*32 + l31] = bf16_rne(v - bf16_to_f32(h));
    }
  __syncthreads();
#pragma unroll
  for (int p = 0; p < 4; ++p){
    int row = (t >> 4) + p*16;
    int c8 = (t & 15) * 8;
    uint4 v = *(uint4*)&Sout[row*136 + c8];
    *(uint4*)&Olo[(size_t)(rowBase+row)*HID + colBase + c8] = v;
  }
}

// ============================ S GEMM + stats (proven r7 16x16 structure) ============================
// BM=64 x BN=128, BK=64; all four operands LDS-staged via glds16. grid (16, 256).
__global__ __launch_bounds__(256) void sgemm_stats(
    const unsigned short* __restrict__ Qhi, const unsigned short* __restrict__ Qlo,
    const unsigned short* __restrict__ Khi, const unsigned short* __restrict__ Klo,
    unsigned short* __restrict__ Sb,
    float* __restrict__ pmax, int* __restrict__ pcol,
    float* __restrict__ psum, float* __restrict__ pnmax, float* __restrict__ pnsum,
    float* __restrict__ pcolmax)
{
  __shared__ char smem[49152];
  unsigned short* Ah = (unsigned short*)smem;
  unsigned short* Al = (unsigned short*)(smem + 8192);
  unsigned short* Bh = (unsigned short*)(smem + 16384);
  unsigned short* Bl = (unsigned short*)(smem + 32768);
  const int t = threadIdx.x;
  const int lane = t & 63, w = t >> 6;
  const int l15 = lane & 15, l4 = lane >> 4;
  const int cb = blockIdx.x;      // 0..15  col block
  const int rb = blockIdx.y;      // 0..255 row block
  const int rowBase = rb * 64;
  const int colBase = cb * 128;
  const int wr = (w >> 1) * 32;
  const int wc = (w & 1) * 64;

  f32x4 acc[2][4];
#pragma unroll
  for (int i=0;i<2;++i)
#pragma unroll
    for (int j=0;j<4;++j) acc[i][j] = (f32x4){0.f,0.f,0.f,0.f};

  for (int kt = 0; kt < 8; ++kt){
    const int k0 = kt * 64;
#pragma unroll
    for (int p = 0; p < 2; ++p){
      int idx = p*256 + t;
      int r = idx >> 3, c = idx & 7;
      int cc = c ^ (r & 7);
      size_t go = (size_t)(rowBase + r) * HID + (k0 + cc*8);
      glds16(Qhi + go, (char*)Ah + idx*16);
      glds16(Qlo + go, (char*)Al + idx*16);
    }
#pragma unroll
    for (int p = 0; p < 4; ++p){
      int idx = p*256 + t;
      int r = idx >> 3, c = idx & 7;
      int cc = c ^ (r & 7);
      size_t go = (size_t)(colBase + r) * HID + (k0 + cc*8);
      glds16(Khi + go, (char*)Bh + idx*16);
      glds16(Klo + go, (char*)Bl + idx*16);
    }
    __syncthreads();

#pragma unroll
    for (int s = 0; s < 2; ++s){
      short8v a_h[2], a_l[2], b_h[4], b_l[4];
#pragma unroll
      for (int rt = 0; rt < 2; ++rt){
        int r = wr + rt*16 + l15;
        int off = r*128 + ((s*4 + l4) ^ (r & 7))*16;
        a_h[rt] = *(const short8v*)((const char*)Ah + off);
        a_l[rt] = *(const short8v*)((const char*)Al + off);
      }
#pragma unroll
      for (int ct = 0; ct < 4; ++ct){
        int r = wc + ct*16 + l15;
        int off = r*128 + ((s*4 + l4) ^ (r & 7))*16;
        b_h[ct] = *(const short8v*)((const char*)Bh + off);
        b_l[ct] = *(const short8v*)((const char*)Bl + off);
      }
#pragma unroll
      for (int rt = 0; rt < 2; ++rt)
#pragma unroll
        for (int ct = 0; ct < 4; ++ct){
          acc[rt][ct] = __builtin_amdgcn_mfma_f32_16x16x32_bf16(a_h[rt], b_h[ct], acc[rt][ct], 0,0,0);
          acc[rt][ct] = __builtin_amdgcn_mfma_f32_16x16x32_bf16(a_h[rt], b_l[ct], acc[rt][ct], 0,0,0);
          acc[rt][ct] = __builtin_amdgcn_mfma_f32_16x16x32_bf16(a_l[rt], b_h[ct], acc[rt][ct], 0,0,0);
        }
    }
    __syncthreads();
  }

  // ---- row stats (per wave over its 64-col half) ----
#pragma unroll
  for (int rt = 0; rt < 2; ++rt){
#pragma unroll
    for (int reg = 0; reg < 4; ++reg){
      float v0 = acc[rt][0][reg], v1 = acc[rt][1][reg];
      float v2 = acc[rt][2][reg], v3 = acc[rt][3][reg];
      float bvv = v0; int bcc = colBase + wc + l15;
      if (v1 > bvv){ bvv = v1; bcc = colBase + wc + 16 + l15; }
      if (v2 > bvv){ bvv = v2; bcc = colBase + wc + 32 + l15; }
      if (v3 > bvv){ bvv = v3; bcc = colBase + wc + 48 + l15; }
      float mnv = fminf(fminf(v0,v1), fminf(v2,v3));
#pragma unroll
      for (int d = 1; d < 16; d <<= 1){
        float ov = __shfl_xor(bvv, d);
        int   oc = __shfl_xor(bcc, d);
        float om = __shfl_xor(mnv, d);
        if (ov > bvv || (ov == bvv && oc < bcc)){ bvv = ov; bcc = oc; }
        mnv = fminf(mnv, om);
      }
      float sp = __expf(v0-bvv)+__expf(v1-bvv)+__expf(v2-bvv)+__expf(v3-bvv);
      float sn = __expf(mnv-v0)+__expf(mnv-v1)+__expf(mnv-v2)+__expf(mnv-v3);
#pragma unroll
      for (int d = 1; d < 16; d <<= 1){ sp += __shfl_xor(sp,d); sn += __shfl_xor(sn,d); }
      if (l15 == 0){
        int row = rowBase + wr + rt*16 + l4*4 + reg;
        size_t pi = (size_t)row*32 + cb*2 + (w & 1);
        pmax[pi] = bvv; pcol[pi] = bcc; psum[pi] = sp;
        pnmax[pi] = -mnv; pnsum[pi] = sn;
      }
    }
  }

  // ---- per-column tile max ----
#pragma unroll
  for (int ct = 0; ct < 4; ++ct){
    float cm = -1e30f;
#pragma unroll
    for (int rt=0; rt<2; ++rt)
#pragma unroll
      for (int reg=0; reg<4; ++reg) cm = fmaxf(cm, acc[rt][ct][reg]);
    cm = fmaxf(cm, __shfl_xor(cm, 16));
    cm = fmaxf(cm, __shfl_xor(cm, 32));
    if (l4 == 0)
      pcolmax[(size_t)(rb*2 + (w>>1))*M_SLOTS + colBase + wc + ct*16 + l15] = cm;
  }

  // ---- S bf16 write (staged through LDS for coalescing) ----
  __syncthreads();
  unsigned short* Sout = (unsigned short*)smem;  // [64][136]
#pragma unroll
  for (int rt=0; rt<2; ++rt)
#pragma unroll
    for (int ct=0; ct<4; ++ct)
#pragma unroll
      for (int reg=0; reg<4; ++reg)
        Sout[(wr + rt*16 + l4*4 + reg)*136 + wc + ct*16 + l15] = bf16_rne(acc[rt][ct][reg]);
  __syncthreads();
#pragma unroll
  for (int p = 0; p < 4; ++p){
    int row = (t >> 4) + p*16;
    int c8 = (t & 15) * 8;
    uint4 v = *(uint4*)&Sout[row*136 + c8];
    *(uint4*)&Sb[(size_t)(rowBase+row)*M_SLOTS + colBase + c8] = v;
  }
}

// fused merge_rows (blocks 0..63) + merge_cols (blocks 64..71)
__global__ __launch_bounds__(256) void merge_all(
    const float* __restrict__ pmax, const int* __restrict__ pcol,
    const float* __restrict__ psum, const float* __restrict__ pnmax,
    const float* __restrict__ pnsum, const float* __restrict__ pcolmax,
    float* __restrict__ rowm, float* __restrict__ rsp,
    float* __restrict__ rmn, float* __restrict__ rsn, int* __restrict__ gidx,
    int* __restrict__ cnt, float* __restrict__ colmax)
{
  if (blockIdx.x < 64){
    int row = blockIdx.x*256 + threadIdx.x;
    const size_t base = (size_t)row*32;
    float m = -1e30f; int g = 0;
    for (int i=0;i<32;++i){
      float v = pmax[base+i];
      if (v > m){ m = v; g = pcol[base+i]; }
    }
    float s = 0.f;
    for (int i=0;i<32;++i) s += psum[base+i] * __expf(pmax[base+i]-m);
    float mn = -1e30f;
    for (int i=0;i<32;++i) mn = fmaxf(mn, pnmax[base+i]);
    float sn = 0.f;
    for (int i=0;i<32;++i) sn += pnsum[base+i] * __expf(pnmax[base+i]-mn);
    rowm[row]=m; gidx[row]=g; rsp[row]=1.f/s; rmn[row]=mn; rsn[row]=1.f/sn;
    atomicAdd(&cnt[g], 1);
  } else {
    int c = (blockIdx.x - 64)*256 + threadIdx.x;
    float m = -1e30f;
    for (int r=0;r<512;++r) m = fmaxf(m, pcolmax[(size_t)r*M_SLOTS + c]);
    colmax[c] = m;
  }
}

// ============================ PV (S read once, 32x32x16 MFMA) ============================
#define PV_RB 32
#define PV_HB 256
__global__ __launch_bounds__(256, 3) void pv2(
    const unsigned short* __restrict__ Sb, const unsigned short* __restrict__ Kt,
    const float* __restrict__ rowm, const float* __restrict__ rsp,
    const float* __restrict__ rmn, const float* __restrict__ rsn,
    const unsigned short* __restrict__ Qhi, const unsigned short* __restrict__ Qlo,
    float* __restrict__ outP, float* __restrict__ outN)
{
  __shared__ char smem[40960];
  unsigned short* Ktile = (unsigned short*)smem;          // [256 h][64 slots], chunk-swizzled, 32KB
  unsigned short* Wp = (unsigned short*)(smem + 32768);   // [octet 0..7][row 0..31] 16B chunks, 4KB
  unsigned short* Wn = (unsigned short*)(smem + 36864);   // 4KB
  const int t = threadIdx.x, lane = t & 63, w = t >> 6;
  const int l31 = lane & 31, lh = lane >> 5;
  const int rowBase = blockIdx.y * PV_RB;
  const int hBase = blockIdx.x * PV_HB;
  const int hw = w * 64;
  const int rS = t >> 3;          // row for weight computation (coalesced S read)
  const int c8 = t & 7;           // slot-octet
  const float mp = rowm[rowBase + rS], mn = rmn[rowBase + rS];

  f32x16 accP[2], accN[2];
#pragma unroll
  for (int e=0;e<16;++e){ accP[0][e]=0.f; accP[1][e]=0.f; accN[0][e]=0.f; accN[1][e]=0.f; }

  for (int kt = 0; kt < 32; ++kt){
    const int k0 = kt*64;
#pragma unroll
    for (int p=0;p<8;++p){
      int idx = p*256 + t;
      int r = idx >> 3, c = idx & 7;
      int cc = c ^ (r & 7);
      glds16(Kt + (size_t)(hBase + r)*M_SLOTS + k0 + cc*8, (char*)Ktile + idx*16);
    }
    // exp-weights for this k-tile (32 rows x 64 slots, shared by all waves)
    short8v sv = *(const short8v*)&Sb[(size_t)(rowBase + rS)*M_SLOTS + k0 + c8*8];
    short8v wp, wn;
#pragma unroll
    for (int e=0;e<8;++e){
      float sval = bf16_to_f32((unsigned short)sv[e]);
      wp[e] = (short)bf16_rne(__expf(sval - mp));
      wn[e] = (short)bf16_rne(__expf(-sval - mn));
    }
    *(short8v*)(Wp + (c8*32 + rS)*8) = wp;
    *(short8v*)(Wn + (c8*32 + rS)*8) = wn;
    __syncthreads();
#pragma unroll
    for (int ks=0; ks<4; ++ks){
      int oct = ks*2 + lh;
      short8v ap = *(const short8v*)(Wp + (oct*32 + l31)*8);
      short8v an = *(const short8v*)(Wn + (oct*32 + l31)*8);
#pragma unroll
      for (int ct=0; ct<2; ++ct){
        int hr = hw + ct*32 + l31;
        short8v b = *(const short8v*)((const char*)Ktile + hr*128 + ((oct ^ (hr & 7))*16));
        accP[ct] = __builtin_amdgcn_mfma_f32_32x32x16_bf16(ap, b, accP[ct], 0,0,0);
        accN[ct] = __builtin_amdgcn_mfma_f32_32x32x16_bf16(an, b, accN[ct], 0,0,0);
      }
    }
    __syncthreads();
  }

  // epilogue: scale, gate by Q (hi+lo), write via LDS staging
  float isp[16], isn[16];
#pragma unroll
  for (int reg=0; reg<16; ++reg){
    int row = rowBase + ROW32(reg, lh);
    isp[reg] = rsp[row];
    isn[reg] = rsn[row];
  }
  float* Pout = (float*)smem;   // [32][260]
#pragma unroll
  for (int ct=0; ct<2; ++ct)
#pragma unroll
    for (int reg=0; reg<16; ++reg)
      Pout[ROW32(reg,lh)*260 + hw + ct*32 + l31] = accP[ct][reg]*isp[reg];
  __syncthreads();
#pragma unroll
  for (int i=0;i<8;++i){
    int row = t >> 3;
    int col = (t & 7)*4 + i*32;
    float4 pv = *(float4*)&Pout[row*260 + col];
    float4 qv = ld4bf(Qhi, Qlo, (size_t)(rowBase+row)*HID + hBase + col);
    float4 o; o.x=pv.x*qv.x; o.y=pv.y*qv.y; o.z=pv.z*qv.z; o.w=pv.w*qv.w;
    *(float4*)&outP[(size_t)(rowBase+row)*HID + hBase + col] = o;
  }
  __syncthreads();
#pragma unroll
  for (int ct=0; ct<2; ++ct)
#pragma unroll
    for (int reg=0; reg<16; ++reg)
      Pout[ROW32(reg,lh)*260 + hw + ct*32 + l31] = accN[ct][reg]*isn[reg];
  __syncthreads();
#pragma unroll
  for (int i=0;i<8;++i){
    int row = t >> 3;
    int col = (t & 7)*4 + i*32;
    float4 pv = *(float4*)&Pout[row*260 + col];
    float4 qv = ld4bf(Qhi, Qlo, (size_t)(rowBase+row)*HID + hBase + col);
    float4 o; o.x=pv.x*qv.x; o.y=pv.y*qv.y; o.z=pv.z*qv.z; o.w=pv.w*qv.w;
    *(float4*)&outN[(size_t)(rowBase+row)*HID + hBase + col] = o;
  }
}

// ============================ CSR upload (skew-independent) ============================

__global__ __launch_bounds__(256) void csr_scan(const int* __restrict__ cnt,
                                                int* __restrict__ off, int* __restrict__ woff){
  __shared__ int partial[256];
  const int t = threadIdx.x;
  const int base = t*8;
  int local[8]; int s = 0;
#pragma unroll
  for (int j=0;j<8;++j){ local[j] = s; s += cnt[base+j]; }
  partial[t] = s;
  __syncthreads();
  for (int d=1; d<256; d<<=1){
    int v = (t>=d) ? partial[t-d] : 0;
    __syncthreads();
    partial[t] += v;
    __syncthreads();
  }
  int pre = (t==0) ? 0 : partial[t-1];
#pragma unroll
  for (int j=0;j<8;++j){ int o = pre + local[j]; off[base+j]=o; woff[base+j]=o; }
  if (t==255) off[2048] = partial[255];
}

__global__ __launch_bounds__(256) void csr_fill(const int* __restrict__ gidx,
                                                const float* __restrict__ rowm,
                                                const float* __restrict__ colmax,
                                                int* __restrict__ woff,
                                                int* __restrict__ rows, float* __restrict__ wv,
                                                int* __restrict__ sid){
  int i = blockIdx.x*256 + threadIdx.x;
  int g = gidx[i];
  int p = atomicAdd(&woff[g], 1);
  rows[p] = i;
  wv[p] = __expf(rowm[i] - colmax[g]);
  sid[p] = g;
}

__global__ __launch_bounds__(256) void upload_scatter(
    const unsigned short* __restrict__ Qhi, const unsigned short* __restrict__ Qlo,
    const int* __restrict__ sid, const int* __restrict__ rows, const float* __restrict__ wv,
    const int* __restrict__ train, float* __restrict__ qacc)
{
  if (*train == 0) return;
  const int b = blockIdx.x, t = threadIdx.x;
  __shared__ int   s_sid[64];
  __shared__ int   s_row[64];
  __shared__ float s_w[64];
  if (t < 64){
    int p = b*64 + t;
    s_sid[t] = sid[p];
    s_row[t] = rows[p];
    s_w[t]   = wv[p];
  }
  __syncthreads();
  const int h0 = t*2;
  float a0 = 0.f, a1 = 0.f;
  int prev = s_sid[0];
#pragma unroll 4
  for (int p = 0; p < 64; ++p){
    int s = s_sid[p];
    if (s != prev){
      atomicAdd(&qacc[(size_t)prev*HID + h0],     a0);
      atomicAdd(&qacc[(size_t)prev*HID + h0 + 1], a1);
      a0 = 0.f; a1 = 0.f; prev = s;
    }
    int row = s_row[p];
    float w = s_w[p];
    unsigned h = *(const unsigned*)(Qhi + (size_t)row*HID + h0);
    unsigned l = *(const unsigned*)(Qlo + (size_t)row*HID + h0);
    a0 += w * (bf16_to_f32((unsigned short)(h & 0xffffu)) + bf16_to_f32((unsigned short)(l & 0xffffu)));
    a1 += w * (bf16_to_f32((unsigned short)(h >> 16))     + bf16_to_f32((unsigned short)(l >> 16)));
  }
  atomicAdd(&qacc[(size_t)prev*HID + h0],     a0);
  atomicAdd(&qacc[(size_t)prev*HID + h0 + 1], a1);
}

__global__ __launch_bounds__(256) void upload_finish(const float* __restrict__ qacc,
                                                     const float* __restrict__ Km,
                                                     const int* __restrict__ train,
                                                     float* __restrict__ mem)
{
  const int m = blockIdx.x, t = threadIdx.x;
  const int h0 = t * 2;
  float2 kv = *(const float2*)&Km[(size_t)m*HID + h0];
  if (*train == 0){
    mem[(size_t)m*HID + h0]     = kv.x;
    mem[(size_t)m*HID + h0 + 1] = kv.y;
    return;
  }
  float2 av = *(const float2*)&qacc[(size_t)m*HID + h0];
  float v0 = av.x + kv.x, v1 = av.y + kv.y;
  __shared__ float red[256];
  red[t] = v0*v0 + v1*v1;
  __syncthreads();
  for (int s = 128; s > 0; s >>= 1){
    if (t < s) red[t] += red[t + s];
    __syncthreads();
  }
  float rinv = 1.f / fmaxf(sqrtf(red[0]), 1e-12f);
  mem[(size_t)m*HID + h0]     = v0 * rinv;
  mem[(size_t)m*HID + h0 + 1] = v1 * rinv;
}

// pred[i] = dot(Q[i], Wd) + bd ; one wave per row, Q reconstructed hi+lo.
// Standalone (no atomics, no cross-kernel accumulation): deterministic per call.
__global__ __launch_bounds__(256) void pred_kernel(const unsigned short* __restrict__ Qhi,
                                                   const unsigned short* __restrict__ Qlo,
                                                   const float* __restrict__ Wd,
                                                   const float* __restrict__ bd,
                                                   float* __restrict__ pred)
{
  const int w = threadIdx.x >> 6, lane = threadIdx.x & 63;
  const int row = blockIdx.x * 4 + w;
  size_t base = (size_t)row * HID + lane*8;
  float4 a = ld4bf(Qhi, Qlo, base);
  float4 b = ld4bf(Qhi, Qlo, base + 4);
  float4 wa = *(const float4*)&Wd[lane*8];
  float4 wb = *(const float4*)&Wd[lane*8 + 4];
  float p = a.x*wa.x + a.y*wa.y + a.z*wa.z + a.w*wa.w
          + b.x*wb.x + b.y*wb.y + b.z*wb.z + b.w*wb.w;
#pragma unroll
  for (int d = 32; d > 0; d >>= 1) p += __shfl_down(p, d);
  if (lane == 0) pred[row] = p + bd[0];
}

// ============================ host ============================

extern "C" void kernel_launch(void* const* d_in, const int* in_sizes, int n_in,
                              void* d_out, int out_size, void* d_ws, size_t ws_size,
                              hipStream_t stream)
{
  const float* x   = (const float*)d_in[0];
  const float* Km  = (const float*)d_in[1];
  const float* W1  = (const float*)d_in[2];
  const float* b1  = (const float*)d_in[3];
  const float* W2  = (const float*)d_in[4];
  const float* b2  = (const float*)d_in[5];
  const float* W3  = (const float*)d_in[6];
  const float* b3  = (const float*)d_in[7];
  const float* Wd  = (const float*)d_in[8];
  const float* bd  = (const float*)d_in[9];
  const int* train = (const int*)d_in[10];

  float* out  = (float*)d_out;
  float* pred = out;
  float* outN = out + 16384;
  float* outP = out + 16384 + 8388608;
  float* memo = out + 16384 + 2*8388608;

  char* ws = (char*)d_ws;
  unsigned short* Qhi   = (unsigned short*)(ws + 0);           // 16,777,216
  unsigned short* Qlo   = (unsigned short*)(ws + 16777216);    // 16,777,216
  unsigned short* xph   = (unsigned short*)(ws + 33554432);    // 12,582,912
  unsigned short* xpl   = (unsigned short*)(ws + 46137344);    // 12,582,912
  unsigned short* h1h   = (unsigned short*)(ws + 58720256);    // 16,777,216
  unsigned short* h1l   = (unsigned short*)(ws + 75497472);    // 16,777,216
  unsigned short* h2h   = (unsigned short*)(ws + 92274688);    // 16,777,216
  unsigned short* h2l   = (unsigned short*)(ws + 109051904);   // 16,777,216 (R0 end 125,829,120)
  unsigned short* Sb    = (unsigned short*)(ws + 33554432);    // 67,108,864 (aliases R0)
  unsigned short* Khi   = (unsigned short*)(ws + 125829120);   //  2,097,152
  unsigned short* Klo   = (unsigned short*)(ws + 127926272);   //  2,097,152
  unsigned short* Kt    = (unsigned short*)(ws + 130023424);   //  2,097,152
  unsigned short* W1ph  = (unsigned short*)(ws + 132120576);   //    393,216
  unsigned short* W1pl  = (unsigned short*)(ws + 132513792);   //    393,216
  unsigned short* W2h   = (unsigned short*)(ws + 132907008);   //    524,288
  unsigned short* W2l   = (unsigned short*)(ws + 133431296);   //    524,288
  unsigned short* W3h   = (unsigned short*)(ws + 133955584);   //    524,288
  unsigned short* W3l   = (unsigned short*)(ws + 134479872);   //    524,288
  float* pmax    = (float*)(ws + 135004160);                   //  2,097,152
  int*   pcol    = (int*)  (ws + 137101312);                   //  2,097,152
  float* psum    = (float*)(ws + 139198464);                   //  2,097,152
  float* pnmax   = (float*)(ws + 141295616);                   //  2,097,152
  float* pnsum   = (float*)(ws + 143392768);                   //  2,097,152
  float* pcolmax = (float*)(ws + 145489920);                   //  4,194,304 (512 rows)
  float* rowm    = (float*)(ws + 149684224);
  float* rsp     = (float*)(ws + 149749760);
  float* rmn     = (float*)(ws + 149815296);
  float* rsn     = (float*)(ws + 149880832);
  int*   gidx    = (int*)  (ws + 149946368);
  float* colmax  = (float*)(ws + 150011904);
  int*   cnt     = (int*)  (ws + 150020096);                   //      8,192
  int*   off     = (int*)  (ws + 150028288);                   //      8,448 (2049 ints)
  int*   woff    = (int*)  (ws + 150036736);                   //      8,192
  int*   rows    = (int*)  (ws + 150044928);                   //     65,536
  float* wv      = (float*)(ws + 150110464);                   //     65,536
  int*   sid     = (int*)  (ws + 150176000);                   //     65,536
  float* qacc    = (float*)(ws + 150241536);                   //  4,194,304
  const size_t NEED = 154435840ull;
  if (ws_size < NEED) return;  // harness provides >= 155 MB (proven round 2)

  dim3 blk(256);
  // conversions
  cvt_pad_split<<<(N_ROWS*KP1/4 + 255)/256, blk, 0, stream>>>(x,  xph,  xpl,  N_ROWS, D_INN, KP1);
  cvt_pad_split<<<(HID*KP1/4 + 255)/256,    blk, 0, stream>>>(W1, W1ph, W1pl, HID,    D_INN, KP1);
  cvt_split<<<HID*HID/2048,     blk, 0, stream>>>(W2, W2h, W2l, HID*HID);
  cvt_split<<<HID*HID/2048,     blk, 0, stream>>>(W3, W3h, W3l, HID*HID);
  cvt_split<<<M_SLOTS*HID/2048, blk, 0, stream>>>(Km, Khi, Klo, M_SLOTS*HID);
  kt_kernel<<<dim3(32, 8), blk, 0, stream>>>(Km, Kt);

  // MLP (split-bf16 MFMA, 32x32x16)
  mlp_gemm<<<dim3(N_ROWS/64, 4), blk, 0, stream>>>(xph, xpl, W1ph, W1pl, b1, h1h, h1l, KP1);
  mlp_gemm<<<dim3(N_ROWS/64, 4), blk, 0, stream>>>(h1h, h1l, W2h, W2l, b2, h2h, h2l, HID);
  mlp_gemm<<<dim3(N_ROWS/64, 4), blk, 0, stream>>>(h2h, h2l, W3h, W3l, b3, Qhi, Qlo, HID);

  // attention stats + PV
  sgemm_stats<<<dim3(16, 256), blk, 0, stream>>>(Qhi, Qlo, Khi, Klo, Sb,
                                                 pmax, pcol, psum, pnmax, pnsum, pcolmax);
  hipMemsetAsync(cnt, 0, M_SLOTS*sizeof(int), stream);
  merge_all<<<72, blk, 0, stream>>>(pmax, pcol, psum, pnmax, pnsum, pcolmax,
                                    rowm, rsp, rmn, rsn, gidx, cnt, colmax);
  pv2<<<dim3(2, 512), blk, 0, stream>>>(Sb, Kt, rowm, rsp, rmn, rsn, Qhi, Qlo, outP, outN);

  // upload via CSR + bounded scatter
  hipMemsetAsync(qacc, 0, M_SLOTS*HID*sizeof(float), stream);
  csr_scan<<<1, blk, 0, stream>>>(cnt, off, woff);
  csr_fill<<<N_ROWS/256, blk, 0, stream>>>(gidx, rowm, colmax, woff, rows, wv, sid);
  upload_scatter<<<N_ROWS/64, blk, 0, stream>>>(Qhi, Qlo, sid, rows, wv, train, qacc);
  upload_finish<<<M_SLOTS, blk, 0, stream>>>(qacc, Km, train, memo);

  // pred last (standalone, deterministic)
  pred_kernel<<<N_ROWS/4, blk, 0, stream>>>(Qhi, Qlo, Wd, bd, pred);
}

// Round 11
// 558.583 us; speedup vs baseline: 1.1293x; 1.0376x over previous
//
#include <hip/hip_runtime.h>
#include <math.h>

// Problem constants (fixed by the reference).
#define N_ROWS 16384
#define D_INN  360
#define KP1    384      // D_INN padded to multiple of 64
#define HID    512
#define M_SLOTS 2048

typedef __attribute__((ext_vector_type(8))) short short8v;
typedef __attribute__((ext_vector_type(4))) float f32x4;
typedef __attribute__((ext_vector_type(16))) float f32x16;
typedef __attribute__((address_space(1))) unsigned int as1_uint;
typedef __attribute__((address_space(3))) unsigned int as3_uint;

// ---- bf16 helpers (manual, RNE) ----
__device__ __forceinline__ unsigned short bf16_rne(float f){
  unsigned u = __float_as_uint(f);
  unsigned r = u + 0x7FFFu + ((u >> 16) & 1u);
  return (unsigned short)(r >> 16);
}
__device__ __forceinline__ float bf16_to_f32(unsigned short h){
  return __uint_as_float(((unsigned)h) << 16);
}

__device__ __forceinline__ void glds16(const void* g, void* l){
  __builtin_amdgcn_global_load_lds((const as1_uint*)g, (as3_uint*)l, 16, 0, 0);
}

// reconstruct 4 consecutive f32 from hi/lo bf16 pair arrays
__device__ __forceinline__ float4 ld4bf(const unsigned short* hi, const unsigned short* lo, size_t off){
  uint2 h = *(const uint2*)(hi + off);
  uint2 l = *(const uint2*)(lo + off);
  float4 r;
  r.x = bf16_to_f32((unsigned short)(h.x & 0xffffu)) + bf16_to_f32((unsigned short)(l.x & 0xffffu));
  r.y = bf16_to_f32((unsigned short)(h.x >> 16))     + bf16_to_f32((unsigned short)(l.x >> 16));
  r.z = bf16_to_f32((unsigned short)(h.y & 0xffffu)) + bf16_to_f32((unsigned short)(l.y & 0xffffu));
  r.w = bf16_to_f32((unsigned short)(h.y >> 16))     + bf16_to_f32((unsigned short)(l.y >> 16));
  return r;
}

// C/D layout for mfma_f32_32x32x16: col = lane&31, row = (reg&3)+8*(reg>>2)+4*(lane>>5)
#define ROW32(reg, lh) (((reg) & 3) + 8*((reg) >> 2) + 4*(lh))

// ============================ conversion kernels ============================

__global__ __launch_bounds__(256) void cvt_split(const float* __restrict__ src,
                                                 unsigned short* __restrict__ hi,
                                                 unsigned short* __restrict__ lo,
                                                 int nelem)
{
  int idx = (blockIdx.x*256 + threadIdx.x) * 8;
  if (idx >= nelem) return;
  float4 a = *(const float4*)&src[idx];
  float4 b = *(const float4*)&src[idx+4];
  float v[8] = {a.x,a.y,a.z,a.w,b.x,b.y,b.z,b.w};
  short8v hv, lv;
#pragma unroll
  for (int e=0;e<8;++e){
    unsigned short h = bf16_rne(v[e]);
    float hf = bf16_to_f32(h);
    hv[e] = (short)h;
    lv[e] = (short)bf16_rne(v[e] - hf);
  }
  *(short8v*)&hi[idx] = hv;
  *(short8v*)&lo[idx] = lv;
}

__global__ __launch_bounds__(256) void cvt_pad_split(const float* __restrict__ src,
                                                     unsigned short* __restrict__ hi,
                                                     unsigned short* __restrict__ lo,
                                                     int R, int Ksrc, int Kp)
{
  long long e0 = ((long long)blockIdx.x*256 + threadIdx.x) * 4;
  if (e0 >= (long long)R*Kp) return;
  int row = (int)(e0 / Kp), c = (int)(e0 % Kp);
  unsigned short h4[4], l4[4];
  if (c < Ksrc){
    float4 v = *(const float4*)&src[(size_t)row*Ksrc + c];
    float vv[4] = {v.x, v.y, v.z, v.w};
#pragma unroll
    for (int e=0;e<4;++e){
      unsigned short h = bf16_rne(vv[e]);
      h4[e] = h;
      l4[e] = bf16_rne(vv[e] - bf16_to_f32(h));
    }
  } else {
#pragma unroll
    for (int e=0;e<4;++e){ h4[e]=0; l4[e]=0; }
  }
  *(uint2*)&hi[(size_t)row*Kp + c] = *(uint2*)h4;
  *(uint2*)&lo[(size_t)row*Kp + c] = *(uint2*)l4;
}

// Kt[h][slot] = bf16(K[slot][h])
__global__ __launch_bounds__(256) void kt_kernel(const float* __restrict__ K,
                                                 unsigned short* __restrict__ Kt)
{
  __shared__ float tile[64][65];
  const int sb = blockIdx.x * 64;
  const int hb = blockIdx.y * 64;
  const int t = threadIdx.x;
  {
    int r = t >> 2, cq = t & 3;
#pragma unroll
    for (int q=0;q<4;++q){
      float4 v = *(const float4*)&K[(size_t)(sb+r)*HID + hb + cq*16 + q*4];
      tile[r][cq*16+q*4+0]=v.x; tile[r][cq*16+q*4+1]=v.y;
      tile[r][cq*16+q*4+2]=v.z; tile[r][cq*16+q*4+3]=v.w;
    }
  }
  __syncthreads();
  {
    int hl = t >> 2, sq = t & 3;
    unsigned short w16[16];
#pragma unroll
    for (int q=0;q<16;++q) w16[q] = bf16_rne(tile[sq*16+q][hl]);
    *(uint4*)&Kt[(size_t)(hb+hl)*M_SLOTS + sb + sq*16]     = *(uint4*)&w16[0];
    *(uint4*)&Kt[(size_t)(hb+hl)*M_SLOTS + sb + sq*16 + 8] = *(uint4*)&w16[8];
  }
}

// ============================ MLP GEMM (3-term split bf16, 32x32x16 MFMA) ============================
__global__ __launch_bounds__(256) void mlp_gemm(
    const unsigned short* __restrict__ Ah_g, const unsigned short* __restrict__ Al_g,
    const unsigned short* __restrict__ Wh_g, const unsigned short* __restrict__ Wl_g,
    const float* __restrict__ bias,
    unsigned short* __restrict__ Ohi, unsigned short* __restrict__ Olo,
    int Kp)
{
  __shared__ char smem[49152];
  unsigned short* Ah = (unsigned short*)smem;            // [64][64] bf16, chunk-swizzled
  unsigned short* Al = (unsigned short*)(smem + 8192);
  unsigned short* Bh = (unsigned short*)(smem + 16384);  // [128][64]
  unsigned short* Bl = (unsigned short*)(smem + 32768);
  const int t = threadIdx.x;
  const int lane = t & 63, w = t >> 6;
  const int l31 = lane & 31, lh = lane >> 5;
  const int rowBase = blockIdx.x * 64;
  const int colBase = blockIdx.y * 128;
  const int wr = (w >> 1) * 32;
  const int wc = (w & 1) * 64;

  f32x16 acc[2];
#pragma unroll
  for (int e=0;e<16;++e){ acc[0][e]=0.f; acc[1][e]=0.f; }

  const int nkt = Kp >> 6;
  for (int kt = 0; kt < nkt; ++kt){
    const int k0 = kt * 64;
#pragma unroll
    for (int p = 0; p < 2; ++p){
      int idx = p*256 + t;
      int r = idx >> 3, c = idx & 7;
      int cc = c ^ (r & 7);
      size_t go = (size_t)(rowBase + r) * Kp + (k0 + cc*8);
      glds16(Ah_g + go, (char*)Ah + idx*16);
      glds16(Al_g + go, (char*)Al + idx*16);
    }
#pragma unroll
    for (int p = 0; p < 4; ++p){
      int idx = p*256 + t;
      int r = idx >> 3, c = idx & 7;
      int cc = c ^ (r & 7);
      size_t go = (size_t)(colBase + r) * Kp + (k0 + cc*8);
      glds16(Wh_g + go, (char*)Bh + idx*16);
      glds16(Wl_g + go, (char*)Bl + idx*16);
    }
    __syncthreads();

#pragma unroll
    for (int ks = 0; ks < 4; ++ks){
      short8v a_h, a_l, b_h[2], b_l[2];
      {
        int r = wr + l31;
        int off = r*128 + ((ks*2 + lh) ^ (r & 7))*16;
        a_h = *(const short8v*)((const char*)Ah + off);
        a_l = *(const short8v*)((const char*)Al + off);
      }
#pragma unroll
      for (int ct = 0; ct < 2; ++ct){
        int r = wc + ct*32 + l31;
        int off = r*128 + ((ks*2 + lh) ^ (r & 7))*16;
        b_h[ct] = *(const short8v*)((const char*)Bh + off);
        b_l[ct] = *(const short8v*)((const char*)Bl + off);
      }
#pragma unroll
      for (int ct = 0; ct < 2; ++ct){
        acc[ct] = __builtin_amdgcn_mfma_f32_32x32x16_bf16(a_h, b_h[ct], acc[ct], 0,0,0);
        acc[ct] = __builtin_amdgcn_mfma_f32_32x32x16_bf16(a_h, b_l[ct], acc[ct], 0,0,0);
        acc[ct] = __builtin_amdgcn_mfma_f32_32x32x16_bf16(a_l, b_h[ct], acc[ct], 0,0,0);
      }
    }
    __syncthreads();
  }

  // epilogue: bias + relu, split hi/lo, stage through LDS for coalesced writes
  float bcol[2];
#pragma unroll
  for (int ct=0; ct<2; ++ct) bcol[ct] = bias[colBase + wc + ct*32 + l31];
  unsigned short* Sout = (unsigned short*)smem;  // [64][136]
#pragma unroll
  for (int ct=0; ct<2; ++ct)
#pragma unroll
    for (int reg=0; reg<16; ++reg){
      float v = acc[ct][reg] + bcol[ct];
      v = v > 0.f ? v : 0.f;
      acc[ct][reg] = v;
      Sout[(wr + ROW32(reg,lh))*136 + wc + ct*32 + l31] = bf16_rne(v);
    }
  __syncthreads();
#pragma unroll
  for (int p = 0; p < 4; ++p){
    int row = (t >> 4) + p*16;
    int c8 = (t & 15) * 8;
    uint4 v = *(uint4*)&Sout[row*136 + c8];
    *(uint4*)&Ohi[(size_t)(rowBase+row)*HID + colBase + c8] = v;
  }
  __syncthreads();
#pragma unroll
  for (int ct=0; ct<2; ++ct)
#pragma unroll
    for (int reg=0; reg<16; ++reg){
      float v = acc[ct][reg];
      unsigned short h = bf16_rne(v);
      Sout[(wr + ROW32(reg,lh))*136 + wc + ct*32 + l31] = bf16_rne(v - bf16_to_f32(h));
    }
  __syncthreads();
#pragma unroll
  for (int p = 0; p < 4; ++p){
    int row = (t >> 4) + p*16;
    int c8 = (t & 15) * 8;
    uint4 v = *(uint4*)&Sout[row*136 + c8];
    *(uint4*)&Olo[(size_t)(rowBase+row)*HID + colBase + c8] = v;
  }
}

// ============================ S GEMM + stats (16x16, BM=128 x BN=128, 512 thr) ============================
// All four operands LDS-staged (64 KB). 8 waves: wr=(w>>1)*32, wc=(w&1)*64 —
// per-wave fragment layout identical to the proven r7 kernel; partial-stats
// layouts (pmax/pcol/psum/pnmax/pnsum row*32+cb*2+(w&1); pcolmax 512 rows)
// bit-compatible with merge_all. grid (16 colblocks, 128 rowblocks).
__global__ __launch_bounds__(512) void sgemm_stats(
    const unsigned short* __restrict__ Qhi, const unsigned short* __restrict__ Qlo,
    const unsigned short* __restrict__ Khi, const unsigned short* __restrict__ Klo,
    unsigned short* __restrict__ Sb,
    float* __restrict__ pmax, int* __restrict__ pcol,
    float* __restrict__ psum, float* __restrict__ pnmax, float* __restrict__ pnsum,
    float* __restrict__ pcolmax)
{
  __shared__ char smem[65536];
  unsigned short* Ah = (unsigned short*)smem;            // [128][64] hi
  unsigned short* Al = (unsigned short*)(smem + 16384);  // [128][64] lo
  unsigned short* Bh = (unsigned short*)(smem + 32768);  // [128][64] hi
  unsigned short* Bl = (unsigned short*)(smem + 49152);  // [128][64] lo
  const int t = threadIdx.x;
  const int lane = t & 63, w = t >> 6;            // 8 waves
  const int l15 = lane & 15, l4 = lane >> 4;
  const int cb = blockIdx.x;      // 0..15  col block
  const int rb = blockIdx.y;      // 0..127 row block
  const int rowBase = rb * 128;
  const int colBase = cb * 128;
  const int wr = (w >> 1) * 32;   // row quarter (0,32,64,96)
  const int wc = (w & 1) * 64;    // col half

  f32x4 acc[2][4];
#pragma unroll
  for (int i=0;i<2;++i)
#pragma unroll
    for (int j=0;j<4;++j) acc[i][j] = (f32x4){0.f,0.f,0.f,0.f};

  for (int kt = 0; kt < 8; ++kt){
    const int k0 = kt * 64;
#pragma unroll
    for (int p = 0; p < 2; ++p){
      int idx = p*512 + t;            // 1024 chunks: 128 rows x 8
      int r = idx >> 3, c = idx & 7;
      int cc = c ^ (r & 7);
      size_t go = (size_t)(rowBase + r) * HID + (k0 + cc*8);
      glds16(Qhi + go, (char*)Ah + idx*16);
      glds16(Qlo + go, (char*)Al + idx*16);
    }
#pragma unroll
    for (int p = 0; p < 2; ++p){
      int idx = p*512 + t;
      int r = idx >> 3, c = idx & 7;
      int cc = c ^ (r & 7);
      size_t go = (size_t)(colBase + r) * HID + (k0 + cc*8);
      glds16(Khi + go, (char*)Bh + idx*16);
      glds16(Klo + go, (char*)Bl + idx*16);
    }
    __syncthreads();

#pragma unroll
    for (int s = 0; s < 2; ++s){
      short8v a_h[2], a_l[2], b_h[4], b_l[4];
#pragma unroll
      for (int rt = 0; rt < 2; ++rt){
        int r = wr + rt*16 + l15;
        int off = r*128 + ((s*4 + l4) ^ (r & 7))*16;
        a_h[rt] = *(const short8v*)((const char*)Ah + off);
        a_l[rt] = *(const short8v*)((const char*)Al + off);
      }
#pragma unroll
      for (int ct = 0; ct < 4; ++ct){
        int r = wc + ct*16 + l15;
        int off = r*128 + ((s*4 + l4) ^ (r & 7))*16;
        b_h[ct] = *(const short8v*)((const char*)Bh + off);
        b_l[ct] = *(const short8v*)((const char*)Bl + off);
      }
#pragma unroll
      for (int rt = 0; rt < 2; ++rt)
#pragma unroll
        for (int ct = 0; ct < 4; ++ct){
          acc[rt][ct] = __builtin_amdgcn_mfma_f32_16x16x32_bf16(a_h[rt], b_h[ct], acc[rt][ct], 0,0,0);
          acc[rt][ct] = __builtin_amdgcn_mfma_f32_16x16x32_bf16(a_h[rt], b_l[ct], acc[rt][ct], 0,0,0);
          acc[rt][ct] = __builtin_amdgcn_mfma_f32_16x16x32_bf16(a_l[rt], b_h[ct], acc[rt][ct], 0,0,0);
        }
    }
    __syncthreads();
  }

  // ---- row stats (per wave over its 64-col half) ----
#pragma unroll
  for (int rt = 0; rt < 2; ++rt){
#pragma unroll
    for (int reg = 0; reg < 4; ++reg){
      float v0 = acc[rt][0][reg], v1 = acc[rt][1][reg];
      float v2 = acc[rt][2][reg], v3 = acc[rt][3][reg];
      float bvv = v0; int bcc = colBase + wc + l15;
      if (v1 > bvv){ bvv = v1; bcc = colBase + wc + 16 + l15; }
      if (v2 > bvv){ bvv = v2; bcc = colBase + wc + 32 + l15; }
      if (v3 > bvv){ bvv = v3; bcc = colBase + wc + 48 + l15; }
      float mnv = fminf(fminf(v0,v1), fminf(v2,v3));
#pragma unroll
      for (int d = 1; d < 16; d <<= 1){
        float ov = __shfl_xor(bvv, d);
        int   oc = __shfl_xor(bcc, d);
        float om = __shfl_xor(mnv, d);
        if (ov > bvv || (ov == bvv && oc < bcc)){ bvv = ov; bcc = oc; }
        mnv = fminf(mnv, om);
      }
      float sp = __expf(v0-bvv)+__expf(v1-bvv)+__expf(v2-bvv)+__expf(v3-bvv);
      float sn = __expf(mnv-v0)+__expf(mnv-v1)+__expf(mnv-v2)+__expf(mnv-v3);
#pragma unroll
      for (int d = 1; d < 16; d <<= 1){ sp += __shfl_xor(sp,d); sn += __shfl_xor(sn,d); }
      if (l15 == 0){
        int row = rowBase + wr + rt*16 + l4*4 + reg;
        size_t pi = (size_t)row*32 + cb*2 + (w & 1);
        pmax[pi] = bvv; pcol[pi] = bcc; psum[pi] = sp;
        pnmax[pi] = -mnv; pnsum[pi] = sn;
      }
    }
  }

  // ---- per-column tile max (over this wave's 32 rows) ----
#pragma unroll
  for (int ct = 0; ct < 4; ++ct){
    float cm = -1e30f;
#pragma unroll
    for (int rt=0; rt<2; ++rt)
#pragma unroll
      for (int reg=0; reg<4; ++reg) cm = fmaxf(cm, acc[rt][ct][reg]);
    cm = fmaxf(cm, __shfl_xor(cm, 16));
    cm = fmaxf(cm, __shfl_xor(cm, 32));
    if (l4 == 0)
      pcolmax[(size_t)(rb*4 + (w>>1))*M_SLOTS + colBase + wc + ct*16 + l15] = cm;
  }

  // ---- S bf16 write (staged through LDS for coalescing) ----
  __syncthreads();
  unsigned short* Sout = (unsigned short*)smem;  // [128][136] = 34816 B
#pragma unroll
  for (int rt=0; rt<2; ++rt)
#pragma unroll
    for (int ct=0; ct<4; ++ct)
#pragma unroll
      for (int reg=0; reg<4; ++reg)
        Sout[(wr + rt*16 + l4*4 + reg)*136 + wc + ct*16 + l15] = bf16_rne(acc[rt][ct][reg]);
  __syncthreads();
#pragma unroll
  for (int p = 0; p < 4; ++p){
    int row = (t >> 4) + p*32;
    int c8 = (t & 15) * 8;
    uint4 v = *(uint4*)&Sout[row*136 + c8];
    *(uint4*)&Sb[(size_t)(rowBase+row)*M_SLOTS + colBase + c8] = v;
  }
}

// fused merge_rows (blocks 0..63) + merge_cols (blocks 64..71)
__global__ __launch_bounds__(256) void merge_all(
    const float* __restrict__ pmax, const int* __restrict__ pcol,
    const float* __restrict__ psum, const float* __restrict__ pnmax,
    const float* __restrict__ pnsum, const float* __restrict__ pcolmax,
    float* __restrict__ rowm, float* __restrict__ rsp,
    float* __restrict__ rmn, float* __restrict__ rsn, int* __restrict__ gidx,
    int* __restrict__ cnt, float* __restrict__ colmax)
{
  if (blockIdx.x < 64){
    int row = blockIdx.x*256 + threadIdx.x;
    const size_t base = (size_t)row*32;
    float m = -1e30f; int g = 0;
    for (int i=0;i<32;++i){
      float v = pmax[base+i];
      if (v > m){ m = v; g = pcol[base+i]; }
    }
    float s = 0.f;
    for (int i=0;i<32;++i) s += psum[base+i] * __expf(pmax[base+i]-m);
    float mn = -1e30f;
    for (int i=0;i<32;++i) mn = fmaxf(mn, pnmax[base+i]);
    float sn = 0.f;
    for (int i=0;i<32;++i) sn += pnsum[base+i] * __expf(pnmax[base+i]-mn);
    rowm[row]=m; gidx[row]=g; rsp[row]=1.f/s; rmn[row]=mn; rsn[row]=1.f/sn;
    atomicAdd(&cnt[g], 1);
  } else {
    int c = (blockIdx.x - 64)*256 + threadIdx.x;
    float m = -1e30f;
    for (int r=0;r<512;++r) m = fmaxf(m, pcolmax[(size_t)r*M_SLOTS + c]);
    colmax[c] = m;
  }
}

// ============================ PV (S read once, 32x32x16 MFMA) ============================
#define PV_RB 32
#define PV_HB 256
__global__ __launch_bounds__(256, 3) void pv2(
    const unsigned short* __restrict__ Sb, const unsigned short* __restrict__ Kt,
    const float* __restrict__ rowm, const float* __restrict__ rsp,
    const float* __restrict__ rmn, const float* __restrict__ rsn,
    const unsigned short* __restrict__ Qhi, const unsigned short* __restrict__ Qlo,
    float* __restrict__ outP, float* __restrict__ outN)
{
  __shared__ char smem[40960];
  unsigned short* Ktile = (unsigned short*)smem;          // [256 h][64 slots], chunk-swizzled, 32KB
  unsigned short* Wp = (unsigned short*)(smem + 32768);   // [octet 0..7][row 0..31] 16B chunks, 4KB
  unsigned short* Wn = (unsigned short*)(smem + 36864);   // 4KB
  const int t = threadIdx.x, lane = t & 63, w = t >> 6;
  const int l31 = lane & 31, lh = lane >> 5;
  const int rowBase = blockIdx.y * PV_RB;
  const int hBase = blockIdx.x * PV_HB;
  const int hw = w * 64;
  const int rS = t >> 3;          // row for weight computation (coalesced S read)
  const int c8 = t & 7;           // slot-octet
  const float mp = rowm[rowBase + rS], mn = rmn[rowBase + rS];

  f32x16 accP[2], accN[2];
#pragma unroll
  for (int e=0;e<16;++e){ accP[0][e]=0.f; accP[1][e]=0.f; accN[0][e]=0.f; accN[1][e]=0.f; }

  for (int kt = 0; kt < 32; ++kt){
    const int k0 = kt*64;
#pragma unroll
    for (int p=0;p<8;++p){
      int idx = p*256 + t;
      int r = idx >> 3, c = idx & 7;
      int cc = c ^ (r & 7);
      glds16(Kt + (size_t)(hBase + r)*M_SLOTS + k0 + cc*8, (char*)Ktile + idx*16);
    }
    // exp-weights for this k-tile (32 rows x 64 slots, shared by all waves)
    short8v sv = *(const short8v*)&Sb[(size_t)(rowBase + rS)*M_SLOTS + k0 + c8*8];
    short8v wp, wn;
#pragma unroll
    for (int e=0;e<8;++e){
      float sval = bf16_to_f32((unsigned short)sv[e]);
      wp[e] = (short)bf16_rne(__expf(sval - mp));
      wn[e] = (short)bf16_rne(__expf(-sval - mn));
    }
    *(short8v*)(Wp + (c8*32 + rS)*8) = wp;
    *(short8v*)(Wn + (c8*32 + rS)*8) = wn;
    __syncthreads();
#pragma unroll
    for (int ks=0; ks<4; ++ks){
      int oct = ks*2 + lh;
      short8v ap = *(const short8v*)(Wp + (oct*32 + l31)*8);
      short8v an = *(const short8v*)(Wn + (oct*32 + l31)*8);
#pragma unroll
      for (int ct=0; ct<2; ++ct){
        int hr = hw + ct*32 + l31;
        short8v b = *(const short8v*)((const char*)Ktile + hr*128 + ((oct ^ (hr & 7))*16));
        accP[ct] = __builtin_amdgcn_mfma_f32_32x32x16_bf16(ap, b, accP[ct], 0,0,0);
        accN[ct] = __builtin_amdgcn_mfma_f32_32x32x16_bf16(an, b, accN[ct], 0,0,0);
      }
    }
    __syncthreads();
  }

  // epilogue: scale, gate by Q (hi+lo), write via LDS staging
  float isp[16], isn[16];
#pragma unroll
  for (int reg=0; reg<16; ++reg){
    int row = rowBase + ROW32(reg, lh);
    isp[reg] = rsp[row];
    isn[reg] = rsn[row];
  }
  float* Pout = (float*)smem;   // [32][260]
#pragma unroll
  for (int ct=0; ct<2; ++ct)
#pragma unroll
    for (int reg=0; reg<16; ++reg)
      Pout[ROW32(reg,lh)*260 + hw + ct*32 + l31] = accP[ct][reg]*isp[reg];
  __syncthreads();
#pragma unroll
  for (int i=0;i<8;++i){
    int row = t >> 3;
    int col = (t & 7)*4 + i*32;
    float4 pv = *(float4*)&Pout[row*260 + col];
    float4 qv = ld4bf(Qhi, Qlo, (size_t)(rowBase+row)*HID + hBase + col);
    float4 o; o.x=pv.x*qv.x; o.y=pv.y*qv.y; o.z=pv.z*qv.z; o.w=pv.w*qv.w;
    *(float4*)&outP[(size_t)(rowBase+row)*HID + hBase + col] = o;
  }
  __syncthreads();
#pragma unroll
  for (int ct=0; ct<2; ++ct)
#pragma unroll
    for (int reg=0; reg<16; ++reg)
      Pout[ROW32(reg,lh)*260 + hw + ct*32 + l31] = accN[ct][reg]*isn[reg];
  __syncthreads();
#pragma unroll
  for (int i=0;i<8;++i){
    int row = t >> 3;
    int col = (t & 7)*4 + i*32;
    float4 pv = *(float4*)&Pout[row*260 + col];
    float4 qv = ld4bf(Qhi, Qlo, (size_t)(rowBase+row)*HID + hBase + col);
    float4 o; o.x=pv.x*qv.x; o.y=pv.y*qv.y; o.z=pv.z*qv.z; o.w=pv.w*qv.w;
    *(float4*)&outN[(size_t)(rowBase+row)*HID + hBase + col] = o;
  }
}

// ============================ CSR upload (skew-independent) ============================

__global__ __launch_bounds__(256) void csr_scan(const int* __restrict__ cnt,
                                                int* __restrict__ off, int* __restrict__ woff){
  __shared__ int partial[256];
  const int t = threadIdx.x;
  const int base = t*8;
  int local[8]; int s = 0;
#pragma unroll
  for (int j=0;j<8;++j){ local[j] = s; s += cnt[base+j]; }
  partial[t] = s;
  __syncthreads();
  for (int d=1; d<256; d<<=1){
    int v = (t>=d) ? partial[t-d] : 0;
    __syncthreads();
    partial[t] += v;
    __syncthreads();
  }
  int pre = (t==0) ? 0 : partial[t-1];
#pragma unroll
  for (int j=0;j<8;++j){ int o = pre + local[j]; off[base+j]=o; woff[base+j]=o; }
  if (t==255) off[2048] = partial[255];
}

__global__ __launch_bounds__(256) void csr_fill(const int* __restrict__ gidx,
                                                const float* __restrict__ rowm,
                                                const float* __restrict__ colmax,
                                                int* __restrict__ woff,
                                                int* __restrict__ rows, float* __restrict__ wv,
                                                int* __restrict__ sid){
  int i = blockIdx.x*256 + threadIdx.x;
  int g = gidx[i];
  int p = atomicAdd(&woff[g], 1);
  rows[p] = i;
  wv[p] = __expf(rowm[i] - colmax[g]);
  sid[p] = g;
}

__global__ __launch_bounds__(256) void upload_scatter(
    const unsigned short* __restrict__ Qhi, const unsigned short* __restrict__ Qlo,
    const int* __restrict__ sid, const int* __restrict__ rows, const float* __restrict__ wv,
    const int* __restrict__ train, float* __restrict__ qacc)
{
  if (*train == 0) return;
  const int b = blockIdx.x, t = threadIdx.x;
  __shared__ int   s_sid[64];
  __shared__ int   s_row[64];
  __shared__ float s_w[64];
  if (t < 64){
    int p = b*64 + t;
    s_sid[t] = sid[p];
    s_row[t] = rows[p];
    s_w[t]   = wv[p];
  }
  __syncthreads();
  const int h0 = t*2;
  float a0 = 0.f, a1 = 0.f;
  int prev = s_sid[0];
#pragma unroll 4
  for (int p = 0; p < 64; ++p){
    int s = s_sid[p];
    if (s != prev){
      atomicAdd(&qacc[(size_t)prev*HID + h0],     a0);
      atomicAdd(&qacc[(size_t)prev*HID + h0 + 1], a1);
      a0 = 0.f; a1 = 0.f; prev = s;
    }
    int row = s_row[p];
    float w = s_w[p];
    unsigned h = *(const unsigned*)(Qhi + (size_t)row*HID + h0);
    unsigned l = *(const unsigned*)(Qlo + (size_t)row*HID + h0);
    a0 += w * (bf16_to_f32((unsigned short)(h & 0xffffu)) + bf16_to_f32((unsigned short)(l & 0xffffu)));
    a1 += w * (bf16_to_f32((unsigned short)(h >> 16))     + bf16_to_f32((unsigned short)(l >> 16)));
  }
  atomicAdd(&qacc[(size_t)prev*HID + h0],     a0);
  atomicAdd(&qacc[(size_t)prev*HID + h0 + 1], a1);
}

__global__ __launch_bounds__(256) void upload_finish(const float* __restrict__ qacc,
                                                     const float* __restrict__ Km,
                                                     const int* __restrict__ train,
                                                     float* __restrict__ mem)
{
  const int m = blockIdx.x, t = threadIdx.x;
  const int h0 = t * 2;
  float2 kv = *(const float2*)&Km[(size_t)m*HID + h0];
  if (*train == 0){
    mem[(size_t)m*HID + h0]     = kv.x;
    mem[(size_t)m*HID + h0 + 1] = kv.y;
    return;
  }
  float2 av = *(const float2*)&qacc[(size_t)m*HID + h0];
  float v0 = av.x + kv.x, v1 = av.y + kv.y;
  __shared__ float red[256];
  red[t] = v0*v0 + v1*v1;
  __syncthreads();
  for (int s = 128; s > 0; s >>= 1){
    if (t < s) red[t] += red[t + s];
    __syncthreads();
  }
  float rinv = 1.f / fmaxf(sqrtf(red[0]), 1e-12f);
  mem[(size_t)m*HID + h0]     = v0 * rinv;
  mem[(size_t)m*HID + h0 + 1] = v1 * rinv;
}

// pred[i] = dot(Q[i], Wd) + bd ; one wave per row, Q reconstructed hi+lo.
// Standalone (no atomics, no cross-kernel accumulation): deterministic per call.
__global__ __launch_bounds__(256) void pred_kernel(const unsigned short* __restrict__ Qhi,
                                                   const unsigned short* __restrict__ Qlo,
                                                   const float* __restrict__ Wd,
                                                   const float* __restrict__ bd,
                                                   float* __restrict__ pred)
{
  const int w = threadIdx.x >> 6, lane = threadIdx.x & 63;
  const int row = blockIdx.x * 4 + w;
  size_t base = (size_t)row * HID + lane*8;
  float4 a = ld4bf(Qhi, Qlo, base);
  float4 b = ld4bf(Qhi, Qlo, base + 4);
  float4 wa = *(const float4*)&Wd[lane*8];
  float4 wb = *(const float4*)&Wd[lane*8 + 4];
  float p = a.x*wa.x + a.y*wa.y + a.z*wa.z + a.w*wa.w
          + b.x*wb.x + b.y*wb.y + b.z*wb.z + b.w*wb.w;
#pragma unroll
  for (int d = 32; d > 0; d >>= 1) p += __shfl_down(p, d);
  if (lane == 0) pred[row] = p + bd[0];
}

// ============================ host ============================

extern "C" void kernel_launch(void* const* d_in, const int* in_sizes, int n_in,
                              void* d_out, int out_size, void* d_ws, size_t ws_size,
                              hipStream_t stream)
{
  const float* x   = (const float*)d_in[0];
  const float* Km  = (const float*)d_in[1];
  const float* W1  = (const float*)d_in[2];
  const float* b1  = (const float*)d_in[3];
  const float* W2  = (const float*)d_in[4];
  const float* b2  = (const float*)d_in[5];
  const float* W3  = (const float*)d_in[6];
  const float* b3  = (const float*)d_in[7];
  const float* Wd  = (const float*)d_in[8];
  const float* bd  = (const float*)d_in[9];
  const int* train = (const int*)d_in[10];

  float* out  = (float*)d_out;
  float* pred = out;
  float* outN = out + 16384;
  float* outP = out + 16384 + 8388608;
  float* memo = out + 16384 + 2*8388608;

  char* ws = (char*)d_ws;
  unsigned short* Qhi   = (unsigned short*)(ws + 0);           // 16,777,216
  unsigned short* Qlo   = (unsigned short*)(ws + 16777216);    // 16,777,216
  unsigned short* xph   = (unsigned short*)(ws + 33554432);    // 12,582,912
  unsigned short* xpl   = (unsigned short*)(ws + 46137344);    // 12,582,912
  unsigned short* h1h   = (unsigned short*)(ws + 58720256);    // 16,777,216
  unsigned short* h1l   = (unsigned short*)(ws + 75497472);    // 16,777,216
  unsigned short* h2h   = (unsigned short*)(ws + 92274688);    // 16,777,216
  unsigned short* h2l   = (unsigned short*)(ws + 109051904);   // 16,777,216 (R0 end 125,829,120)
  unsigned short* Sb    = (unsigned short*)(ws + 33554432);    // 67,108,864 (aliases R0)
  unsigned short* Khi   = (unsigned short*)(ws + 125829120);   //  2,097,152
  unsigned short* Klo   = (unsigned short*)(ws + 127926272);   //  2,097,152
  unsigned short* Kt    = (unsigned short*)(ws + 130023424);   //  2,097,152
  unsigned short* W1ph  = (unsigned short*)(ws + 132120576);   //    393,216
  unsigned short* W1pl  = (unsigned short*)(ws + 132513792);   //    393,216
  unsigned short* W2h   = (unsigned short*)(ws + 132907008);   //    524,288
  unsigned short* W2l   = (unsigned short*)(ws + 133431296);   //    524,288
  unsigned short* W3h   = (unsigned short*)(ws + 133955584);   //    524,288
  unsigned short* W3l   = (unsigned short*)(ws + 134479872);   //    524,288
  float* pmax    = (float*)(ws + 135004160);                   //  2,097,152
  int*   pcol    = (int*)  (ws + 137101312);                   //  2,097,152
  float* psum    = (float*)(ws + 139198464);                   //  2,097,152
  float* pnmax   = (float*)(ws + 141295616);                   //  2,097,152
  float* pnsum   = (float*)(ws + 143392768);                   //  2,097,152
  float* pcolmax = (float*)(ws + 145489920);                   //  4,194,304 (512 rows)
  float* rowm    = (float*)(ws + 149684224);
  float* rsp     = (float*)(ws + 149749760);
  float* rmn     = (float*)(ws + 149815296);
  float* rsn     = (float*)(ws + 149880832);
  int*   gidx    = (int*)  (ws + 149946368);
  float* colmax  = (float*)(ws + 150011904);
  int*   cnt     = (int*)  (ws + 150020096);                   //      8,192
  int*   off     = (int*)  (ws + 150028288);                   //      8,448 (2049 ints)
  int*   woff    = (int*)  (ws + 150036736);                   //      8,192
  int*   rows    = (int*)  (ws + 150044928);                   //     65,536
  float* wv      = (float*)(ws + 150110464);                   //     65,536
  int*   sid     = (int*)  (ws + 150176000);                   //     65,536
  float* qacc    = (float*)(ws + 150241536);                   //  4,194,304
  const size_t NEED = 154435840ull;
  if (ws_size < NEED) return;  // harness provides >= 155 MB (proven round 2)

  dim3 blk(256);
  // conversions
  cvt_pad_split<<<(N_ROWS*KP1/4 + 255)/256, blk, 0, stream>>>(x,  xph,  xpl,  N_ROWS, D_INN, KP1);
  cvt_pad_split<<<(HID*KP1/4 + 255)/256,    blk, 0, stream>>>(W1, W1ph, W1pl, HID,    D_INN, KP1);
  cvt_split<<<HID*HID/2048,     blk, 0, stream>>>(W2, W2h, W2l, HID*HID);
  cvt_split<<<HID*HID/2048,     blk, 0, stream>>>(W3, W3h, W3l, HID*HID);
  cvt_split<<<M_SLOTS*HID/2048, blk, 0, stream>>>(Km, Khi, Klo, M_SLOTS*HID);
  kt_kernel<<<dim3(32, 8), blk, 0, stream>>>(Km, Kt);

  // MLP (split-bf16 MFMA, 32x32x16)
  mlp_gemm<<<dim3(N_ROWS/64, 4), blk, 0, stream>>>(xph, xpl, W1ph, W1pl, b1, h1h, h1l, KP1);
  mlp_gemm<<<dim3(N_ROWS/64, 4), blk, 0, stream>>>(h1h, h1l, W2h, W2l, b2, h2h, h2l, HID);
  mlp_gemm<<<dim3(N_ROWS/64, 4), blk, 0, stream>>>(h2h, h2l, W3h, W3l, b3, Qhi, Qlo, HID);

  // attention stats + PV (sgemm: BM=128 tile, 512 threads)
  sgemm_stats<<<dim3(16, 128), dim3(512), 0, stream>>>(Qhi, Qlo, Khi, Klo, Sb,
                                                       pmax, pcol, psum, pnmax, pnsum, pcolmax);
  hipMemsetAsync(cnt, 0, M_SLOTS*sizeof(int), stream);
  merge_all<<<72, blk, 0, stream>>>(pmax, pcol, psum, pnmax, pnsum, pcolmax,
                                    rowm, rsp, rmn, rsn, gidx, cnt, colmax);
  pv2<<<dim3(2, 512), blk, 0, stream>>>(Sb, Kt, rowm, rsp, rmn, rsn, Qhi, Qlo, outP, outN);

  // upload via CSR + bounded scatter
  hipMemsetAsync(qacc, 0, M_SLOTS*HID*sizeof(float), stream);
  csr_scan<<<1, blk, 0, stream>>>(cnt, off, woff);
  csr_fill<<<N_ROWS/256, blk, 0, stream>>>(gidx, rowm, colmax, woff, rows, wv, sid);
  upload_scatter<<<N_ROWS/64, blk, 0, stream>>>(Qhi, Qlo, sid, rows, wv, train, qacc);
  upload_finish<<<M_SLOTS, blk, 0, stream>>>(qacc, Km, train, memo);

  // pred last (standalone, deterministic)
  pred_kernel<<<N_ROWS/4, blk, 0, stream>>>(Qhi, Qlo, Wd, bd, pred);
}

// Round 12
// 485.777 us; speedup vs baseline: 1.2986x; 1.1499x over previous
//
#include <hip/hip_runtime.h>
#include <math.h>

// Problem constants (fixed by the reference).
#define N_ROWS 16384
#define D_INN  360
#define KP1    384      // D_INN padded to multiple of 64
#define HID    512
#define M_SLOTS 2048

typedef __attribute__((ext_vector_type(8))) short short8v;
typedef __attribute__((ext_vector_type(4))) float f32x4;
typedef __attribute__((address_space(1))) unsigned int as1_uint;
typedef __attribute__((address_space(3))) unsigned int as3_uint;

// ---- bf16 helpers (manual, RNE) ----
__device__ __forceinline__ unsigned short bf16_rne(float f){
  unsigned u = __float_as_uint(f);
  unsigned r = u + 0x7FFFu + ((u >> 16) & 1u);
  return (unsigned short)(r >> 16);
}
__device__ __forceinline__ float bf16_to_f32(unsigned short h){
  return __uint_as_float(((unsigned)h) << 16);
}

__device__ __forceinline__ void glds16(const void* g, void* l){
  __builtin_amdgcn_global_load_lds((const as1_uint*)g, (as3_uint*)l, 16, 0, 0);
}

// reconstruct 4 consecutive f32 from hi/lo bf16 pair arrays
__device__ __forceinline__ float4 ld4bf(const unsigned short* hi, const unsigned short* lo, size_t off){
  uint2 h = *(const uint2*)(hi + off);
  uint2 l = *(const uint2*)(lo + off);
  float4 r;
  r.x = bf16_to_f32((unsigned short)(h.x & 0xffffu)) + bf16_to_f32((unsigned short)(l.x & 0xffffu));
  r.y = bf16_to_f32((unsigned short)(h.x >> 16))     + bf16_to_f32((unsigned short)(l.x >> 16));
  r.z = bf16_to_f32((unsigned short)(h.y & 0xffffu)) + bf16_to_f32((unsigned short)(l.y & 0xffffu));
  r.w = bf16_to_f32((unsigned short)(h.y >> 16))     + bf16_to_f32((unsigned short)(l.y >> 16));
  return r;
}

// ============================ conversion kernels ============================

__global__ __launch_bounds__(256) void cvt_split(const float* __restrict__ src,
                                                 unsigned short* __restrict__ hi,
                                                 unsigned short* __restrict__ lo,
                                                 int nelem)
{
  int idx = (blockIdx.x*256 + threadIdx.x) * 8;
  if (idx >= nelem) return;
  float4 a = *(const float4*)&src[idx];
  float4 b = *(const float4*)&src[idx+4];
  float v[8] = {a.x,a.y,a.z,a.w,b.x,b.y,b.z,b.w};
  short8v hv, lv;
#pragma unroll
  for (int e=0;e<8;++e){
    unsigned short h = bf16_rne(v[e]);
    float hf = bf16_to_f32(h);
    hv[e] = (short)h;
    lv[e] = (short)bf16_rne(v[e] - hf);
  }
  *(short8v*)&hi[idx] = hv;
  *(short8v*)&lo[idx] = lv;
}

__global__ __launch_bounds__(256) void cvt_pad_split(const float* __restrict__ src,
                                                     unsigned short* __restrict__ hi,
                                                     unsigned short* __restrict__ lo,
                                                     int R, int Ksrc, int Kp)
{
  long long e0 = ((long long)blockIdx.x*256 + threadIdx.x) * 4;
  if (e0 >= (long long)R*Kp) return;
  int row = (int)(e0 / Kp), c = (int)(e0 % Kp);
  unsigned short h4[4], l4[4];
  if (c < Ksrc){
    float4 v = *(const float4*)&src[(size_t)row*Ksrc + c];
    float vv[4] = {v.x, v.y, v.z, v.w};
#pragma unroll
    for (int e=0;e<4;++e){
      unsigned short h = bf16_rne(vv[e]);
      h4[e] = h;
      l4[e] = bf16_rne(vv[e] - bf16_to_f32(h));
    }
  } else {
#pragma unroll
    for (int e=0;e<4;++e){ h4[e]=0; l4[e]=0; }
  }
  *(uint2*)&hi[(size_t)row*Kp + c] = *(uint2*)h4;
  *(uint2*)&lo[(size_t)row*Kp + c] = *(uint2*)l4;
}

// Kt[h][slot] = bf16(K[slot][h])
__global__ __launch_bounds__(256) void kt_kernel(const float* __restrict__ K,
                                                 unsigned short* __restrict__ Kt)
{
  __shared__ float tile[64][65];
  const int sb = blockIdx.x * 64;
  const int hb = blockIdx.y * 64;
  const int t = threadIdx.x;
  {
    int r = t >> 2, cq = t & 3;
#pragma unroll
    for (int q=0;q<4;++q){
      float4 v = *(const float4*)&K[(size_t)(sb+r)*HID + hb + cq*16 + q*4];
      tile[r][cq*16+q*4+0]=v.x; tile[r][cq*16+q*4+1]=v.y;
      tile[r][cq*16+q*4+2]=v.z; tile[r][cq*16+q*4+3]=v.w;
    }
  }
  __syncthreads();
  {
    int hl = t >> 2, sq = t & 3;
    unsigned short w16[16];
#pragma unroll
    for (int q=0;q<16;++q) w16[q] = bf16_rne(tile[sq*16+q][hl]);
    *(uint4*)&Kt[(size_t)(hb+hl)*M_SLOTS + sb + sq*16]     = *(uint4*)&w16[0];
    *(uint4*)&Kt[(size_t)(hb+hl)*M_SLOTS + sb + sq*16 + 8] = *(uint4*)&w16[8];
  }
}

// ============================ MLP GEMM (3-term split bf16, 16x16, BM=128, 512 thr) ============================
// Same staging/fragment structure as the proven sgemm_stats r11 core.
__global__ __launch_bounds__(512) void mlp_gemm(
    const unsigned short* __restrict__ Ah_g, const unsigned short* __restrict__ Al_g,
    const unsigned short* __restrict__ Wh_g, const unsigned short* __restrict__ Wl_g,
    const float* __restrict__ bias,
    unsigned short* __restrict__ Ohi, unsigned short* __restrict__ Olo,
    int Kp)
{
  __shared__ char smem[65536];
  unsigned short* Ah = (unsigned short*)smem;            // [128][64] hi
  unsigned short* Al = (unsigned short*)(smem + 16384);  // [128][64] lo
  unsigned short* Bh = (unsigned short*)(smem + 32768);  // [128][64] hi
  unsigned short* Bl = (unsigned short*)(smem + 49152);  // [128][64] lo
  const int t = threadIdx.x;
  const int lane = t & 63, w = t >> 6;            // 8 waves
  const int l15 = lane & 15, l4 = lane >> 4;
  const int rowBase = blockIdx.x * 128;
  const int colBase = blockIdx.y * 128;
  const int wr = (w >> 1) * 32;
  const int wc = (w & 1) * 64;

  f32x4 acc[2][4];
#pragma unroll
  for (int i=0;i<2;++i)
#pragma unroll
    for (int j=0;j<4;++j) acc[i][j] = (f32x4){0.f,0.f,0.f,0.f};

  const int nkt = Kp >> 6;
  for (int kt = 0; kt < nkt; ++kt){
    const int k0 = kt * 64;
#pragma unroll
    for (int p = 0; p < 2; ++p){
      int idx = p*512 + t;
      int r = idx >> 3, c = idx & 7;
      int cc = c ^ (r & 7);
      size_t go = (size_t)(rowBase + r) * Kp + (k0 + cc*8);
      glds16(Ah_g + go, (char*)Ah + idx*16);
      glds16(Al_g + go, (char*)Al + idx*16);
    }
#pragma unroll
    for (int p = 0; p < 2; ++p){
      int idx = p*512 + t;
      int r = idx >> 3, c = idx & 7;
      int cc = c ^ (r & 7);
      size_t go = (size_t)(colBase + r) * Kp + (k0 + cc*8);
      glds16(Wh_g + go, (char*)Bh + idx*16);
      glds16(Wl_g + go, (char*)Bl + idx*16);
    }
    __syncthreads();

#pragma unroll
    for (int s = 0; s < 2; ++s){
      short8v a_h[2], a_l[2], b_h[4], b_l[4];
#pragma unroll
      for (int rt = 0; rt < 2; ++rt){
        int r = wr + rt*16 + l15;
        int off = r*128 + ((s*4 + l4) ^ (r & 7))*16;
        a_h[rt] = *(const short8v*)((const char*)Ah + off);
        a_l[rt] = *(const short8v*)((const char*)Al + off);
      }
#pragma unroll
      for (int ct = 0; ct < 4; ++ct){
        int r = wc + ct*16 + l15;
        int off = r*128 + ((s*4 + l4) ^ (r & 7))*16;
        b_h[ct] = *(const short8v*)((const char*)Bh + off);
        b_l[ct] = *(const short8v*)((const char*)Bl + off);
      }
#pragma unroll
      for (int rt = 0; rt < 2; ++rt)
#pragma unroll
        for (int ct = 0; ct < 4; ++ct){
          acc[rt][ct] = __builtin_amdgcn_mfma_f32_16x16x32_bf16(a_h[rt], b_h[ct], acc[rt][ct], 0,0,0);
          acc[rt][ct] = __builtin_amdgcn_mfma_f32_16x16x32_bf16(a_h[rt], b_l[ct], acc[rt][ct], 0,0,0);
          acc[rt][ct] = __builtin_amdgcn_mfma_f32_16x16x32_bf16(a_l[rt], b_h[ct], acc[rt][ct], 0,0,0);
        }
    }
    __syncthreads();
  }

  // epilogue: bias + relu, split hi/lo, stage through LDS for coalesced writes
  float bcol[4];
#pragma unroll
  for (int ct=0; ct<4; ++ct) bcol[ct] = bias[colBase + wc + ct*16 + l15];
  unsigned short* Sout = (unsigned short*)smem;  // [128][136] = 34816 B
#pragma unroll
  for (int rt=0; rt<2; ++rt)
#pragma unroll
    for (int ct=0; ct<4; ++ct)
#pragma unroll
      for (int reg=0; reg<4; ++reg){
        float v = acc[rt][ct][reg] + bcol[ct];
        v = v > 0.f ? v : 0.f;
        acc[rt][ct][reg] = v;
        Sout[(wr + rt*16 + l4*4 + reg)*136 + wc + ct*16 + l15] = bf16_rne(v);
      }
  __syncthreads();
#pragma unroll
  for (int p = 0; p < 4; ++p){
    int row = (t >> 4) + p*32;
    int c8 = (t & 15) * 8;
    uint4 v = *(uint4*)&Sout[row*136 + c8];
    *(uint4*)&Ohi[(size_t)(rowBase+row)*HID + colBase + c8] = v;
  }
  __syncthreads();
#pragma unroll
  for (int rt=0; rt<2; ++rt)
#pragma unroll
    for (int ct=0; ct<4; ++ct)
#pragma unroll
      for (int reg=0; reg<4; ++reg){
        float v = acc[rt][ct][reg];
        unsigned short h = bf16_rne(v);
        Sout[(wr + rt*16 + l4*4 + reg)*136 + wc + ct*16 + l15] = bf16_rne(v - bf16_to_f32(h));
      }
  __syncthreads();
#pragma unroll
  for (int p = 0; p < 4; ++p){
    int row = (t >> 4) + p*32;
    int c8 = (t & 15) * 8;
    uint4 v = *(uint4*)&Sout[row*136 + c8];
    *(uint4*)&Olo[(size_t)(rowBase+row)*HID + colBase + c8] = v;
  }
}

// ============================ S GEMM + stats (16x16, BM=128 x BN=128, 512 thr) ============================
__global__ __launch_bounds__(512) void sgemm_stats(
    const unsigned short* __restrict__ Qhi, const unsigned short* __restrict__ Qlo,
    const unsigned short* __restrict__ Khi, const unsigned short* __restrict__ Klo,
    unsigned short* __restrict__ Sb,
    float* __restrict__ pmax, int* __restrict__ pcol,
    float* __restrict__ psum, float* __restrict__ pnmax, float* __restrict__ pnsum,
    float* __restrict__ pcolmax)
{
  __shared__ char smem[65536];
  unsigned short* Ah = (unsigned short*)smem;            // [128][64] hi
  unsigned short* Al = (unsigned short*)(smem + 16384);  // [128][64] lo
  unsigned short* Bh = (unsigned short*)(smem + 32768);  // [128][64] hi
  unsigned short* Bl = (unsigned short*)(smem + 49152);  // [128][64] lo
  const int t = threadIdx.x;
  const int lane = t & 63, w = t >> 6;            // 8 waves
  const int l15 = lane & 15, l4 = lane >> 4;
  const int cb = blockIdx.x;      // 0..15  col block
  const int rb = blockIdx.y;      // 0..127 row block
  const int rowBase = rb * 128;
  const int colBase = cb * 128;
  const int wr = (w >> 1) * 32;   // row quarter (0,32,64,96)
  const int wc = (w & 1) * 64;    // col half

  f32x4 acc[2][4];
#pragma unroll
  for (int i=0;i<2;++i)
#pragma unroll
    for (int j=0;j<4;++j) acc[i][j] = (f32x4){0.f,0.f,0.f,0.f};

  for (int kt = 0; kt < 8; ++kt){
    const int k0 = kt * 64;
#pragma unroll
    for (int p = 0; p < 2; ++p){
      int idx = p*512 + t;
      int r = idx >> 3, c = idx & 7;
      int cc = c ^ (r & 7);
      size_t go = (size_t)(rowBase + r) * HID + (k0 + cc*8);
      glds16(Qhi + go, (char*)Ah + idx*16);
      glds16(Qlo + go, (char*)Al + idx*16);
    }
#pragma unroll
    for (int p = 0; p < 2; ++p){
      int idx = p*512 + t;
      int r = idx >> 3, c = idx & 7;
      int cc = c ^ (r & 7);
      size_t go = (size_t)(colBase + r) * HID + (k0 + cc*8);
      glds16(Khi + go, (char*)Bh + idx*16);
      glds16(Klo + go, (char*)Bl + idx*16);
    }
    __syncthreads();

#pragma unroll
    for (int s = 0; s < 2; ++s){
      short8v a_h[2], a_l[2], b_h[4], b_l[4];
#pragma unroll
      for (int rt = 0; rt < 2; ++rt){
        int r = wr + rt*16 + l15;
        int off = r*128 + ((s*4 + l4) ^ (r & 7))*16;
        a_h[rt] = *(const short8v*)((const char*)Ah + off);
        a_l[rt] = *(const short8v*)((const char*)Al + off);
      }
#pragma unroll
      for (int ct = 0; ct < 4; ++ct){
        int r = wc + ct*16 + l15;
        int off = r*128 + ((s*4 + l4) ^ (r & 7))*16;
        b_h[ct] = *(const short8v*)((const char*)Bh + off);
        b_l[ct] = *(const short8v*)((const char*)Bl + off);
      }
#pragma unroll
      for (int rt = 0; rt < 2; ++rt)
#pragma unroll
        for (int ct = 0; ct < 4; ++ct){
          acc[rt][ct] = __builtin_amdgcn_mfma_f32_16x16x32_bf16(a_h[rt], b_h[ct], acc[rt][ct], 0,0,0);
          acc[rt][ct] = __builtin_amdgcn_mfma_f32_16x16x32_bf16(a_h[rt], b_l[ct], acc[rt][ct], 0,0,0);
          acc[rt][ct] = __builtin_amdgcn_mfma_f32_16x16x32_bf16(a_l[rt], b_h[ct], acc[rt][ct], 0,0,0);
        }
    }
    __syncthreads();
  }

  // ---- row stats (per wave over its 64-col half) ----
#pragma unroll
  for (int rt = 0; rt < 2; ++rt){
#pragma unroll
    for (int reg = 0; reg < 4; ++reg){
      float v0 = acc[rt][0][reg], v1 = acc[rt][1][reg];
      float v2 = acc[rt][2][reg], v3 = acc[rt][3][reg];
      float bvv = v0; int bcc = colBase + wc + l15;
      if (v1 > bvv){ bvv = v1; bcc = colBase + wc + 16 + l15; }
      if (v2 > bvv){ bvv = v2; bcc = colBase + wc + 32 + l15; }
      if (v3 > bvv){ bvv = v3; bcc = colBase + wc + 48 + l15; }
      float mnv = fminf(fminf(v0,v1), fminf(v2,v3));
#pragma unroll
      for (int d = 1; d < 16; d <<= 1){
        float ov = __shfl_xor(bvv, d);
        int   oc = __shfl_xor(bcc, d);
        float om = __shfl_xor(mnv, d);
        if (ov > bvv || (ov == bvv && oc < bcc)){ bvv = ov; bcc = oc; }
        mnv = fminf(mnv, om);
      }
      float sp = __expf(v0-bvv)+__expf(v1-bvv)+__expf(v2-bvv)+__expf(v3-bvv);
      float sn = __expf(mnv-v0)+__expf(mnv-v1)+__expf(mnv-v2)+__expf(mnv-v3);
#pragma unroll
      for (int d = 1; d < 16; d <<= 1){ sp += __shfl_xor(sp,d); sn += __shfl_xor(sn,d); }
      if (l15 == 0){
        int row = rowBase + wr + rt*16 + l4*4 + reg;
        size_t pi = (size_t)row*32 + cb*2 + (w & 1);
        pmax[pi] = bvv; pcol[pi] = bcc; psum[pi] = sp;
        pnmax[pi] = -mnv; pnsum[pi] = sn;
      }
    }
  }

  // ---- per-column tile max (over this wave's 32 rows) ----
#pragma unroll
  for (int ct = 0; ct < 4; ++ct){
    float cm = -1e30f;
#pragma unroll
    for (int rt=0; rt<2; ++rt)
#pragma unroll
      for (int reg=0; reg<4; ++reg) cm = fmaxf(cm, acc[rt][ct][reg]);
    cm = fmaxf(cm, __shfl_xor(cm, 16));
    cm = fmaxf(cm, __shfl_xor(cm, 32));
    if (l4 == 0)
      pcolmax[(size_t)(rb*4 + (w>>1))*M_SLOTS + colBase + wc + ct*16 + l15] = cm;
  }

  // ---- S bf16 write (staged through LDS for coalescing) ----
  __syncthreads();
  unsigned short* Sout = (unsigned short*)smem;  // [128][136] = 34816 B
#pragma unroll
  for (int rt=0; rt<2; ++rt)
#pragma unroll
    for (int ct=0; ct<4; ++ct)
#pragma unroll
      for (int reg=0; reg<4; ++reg)
        Sout[(wr + rt*16 + l4*4 + reg)*136 + wc + ct*16 + l15] = bf16_rne(acc[rt][ct][reg]);
  __syncthreads();
#pragma unroll
  for (int p = 0; p < 4; ++p){
    int row = (t >> 4) + p*32;
    int c8 = (t & 15) * 8;
    uint4 v = *(uint4*)&Sout[row*136 + c8];
    *(uint4*)&Sb[(size_t)(rowBase+row)*M_SLOTS + colBase + c8] = v;
  }
}

// fused merge_rows (blocks 0..63) + merge_cols (blocks 64..71)
__global__ __launch_bounds__(256) void merge_all(
    const float* __restrict__ pmax, const int* __restrict__ pcol,
    const float* __restrict__ psum, const float* __restrict__ pnmax,
    const float* __restrict__ pnsum, const float* __restrict__ pcolmax,
    float* __restrict__ rowm, float* __restrict__ rsp,
    float* __restrict__ rmn, float* __restrict__ rsn, int* __restrict__ gidx,
    int* __restrict__ cnt, float* __restrict__ colmax)
{
  if (blockIdx.x < 64){
    int row = blockIdx.x*256 + threadIdx.x;
    const size_t base = (size_t)row*32;
    float m = -1e30f; int g = 0;
    for (int i=0;i<32;++i){
      float v = pmax[base+i];
      if (v > m){ m = v; g = pcol[base+i]; }
    }
    float s = 0.f;
    for (int i=0;i<32;++i) s += psum[base+i] * __expf(pmax[base+i]-m);
    float mn = -1e30f;
    for (int i=0;i<32;++i) mn = fmaxf(mn, pnmax[base+i]);
    float sn = 0.f;
    for (int i=0;i<32;++i) sn += pnsum[base+i] * __expf(pnmax[base+i]-mn);
    rowm[row]=m; gidx[row]=g; rsp[row]=1.f/s; rmn[row]=mn; rsn[row]=1.f/sn;
    atomicAdd(&cnt[g], 1);
  } else {
    int c = (blockIdx.x - 64)*256 + threadIdx.x;
    float m = -1e30f;
    for (int r=0;r<512;++r) m = fmaxf(m, pcolmax[(size_t)r*M_SLOTS + c]);
    colmax[c] = m;
  }
}

// ============================ PV (S read once, 16x16, 64 rows, 512 thr) ============================
// Block = 64 rows x 256 h-cols; 8 waves: rows (w>>2)*32..+32, cols (w&3)*64..+64.
// Weights in row-major XOR-swizzled [64 rows][8 octets] LDS (linear writes,
// chunk-spread reads — same bijection discipline as the staged tiles).
#define PV_RB 64
#define PV_HB 256
__global__ __launch_bounds__(512) void pv2(
    const unsigned short* __restrict__ Sb, const unsigned short* __restrict__ Kt,
    const float* __restrict__ rowm, const float* __restrict__ rsp,
    const float* __restrict__ rmn, const float* __restrict__ rsn,
    const unsigned short* __restrict__ Qhi, const unsigned short* __restrict__ Qlo,
    float* __restrict__ outP, float* __restrict__ outN)
{
  __shared__ char smem[49152];
  unsigned short* Ktile = (unsigned short*)smem;          // [256 h][64 slots], chunk-swizzled, 32KB
  unsigned short* Wp = (unsigned short*)(smem + 32768);   // [64 rows][8 octets] 16B chunks, 8KB
  unsigned short* Wn = (unsigned short*)(smem + 40960);   // 8KB
  const int t = threadIdx.x, lane = t & 63, w = t >> 6;
  const int l15 = lane & 15, l4 = lane >> 4;
  const int rowBase = blockIdx.y * PV_RB;
  const int hBase = blockIdx.x * PV_HB;
  const int wrq = (w >> 2) * 32;       // wave row half (0 or 32)
  const int hw = (w & 3) * 64;         // wave col group
  const int rS = t >> 3;               // 0..63: row for weight computation
  const int c8 = t & 7;                // slot-octet
  const float mp = rowm[rowBase + rS], mn = rmn[rowBase + rS];

  f32x4 accP[2][4], accN[2][4];
#pragma unroll
  for (int i=0;i<2;++i)
#pragma unroll
    for (int j=0;j<4;++j){ accP[i][j]=(f32x4){0.f,0.f,0.f,0.f}; accN[i][j]=(f32x4){0.f,0.f,0.f,0.f}; }

  for (int kt = 0; kt < 32; ++kt){
    const int k0 = kt*64;
#pragma unroll
    for (int p=0;p<4;++p){
      int idx = p*512 + t;
      int r = idx >> 3, c = idx & 7;
      int cc = c ^ (r & 7);
      glds16(Kt + (size_t)(hBase + r)*M_SLOTS + k0 + cc*8, (char*)Ktile + idx*16);
    }
    // exp-weights (64 rows x 64 slots), linear conflict-free write
    short8v sv = *(const short8v*)&Sb[(size_t)(rowBase + rS)*M_SLOTS + k0 + c8*8];
    short8v wp, wn;
#pragma unroll
    for (int e=0;e<8;++e){
      float sval = bf16_to_f32((unsigned short)sv[e]);
      wp[e] = (short)bf16_rne(__expf(sval - mp));
      wn[e] = (short)bf16_rne(__expf(-sval - mn));
    }
    {
      int ch = rS*8 + (c8 ^ (rS & 7));
      *(short8v*)(Wp + ch*8) = wp;
      *(short8v*)(Wn + ch*8) = wn;
    }
    __syncthreads();
#pragma unroll
    for (int s=0; s<2; ++s){
      short8v ap[2], an[2], b[4];
#pragma unroll
      for (int rt=0; rt<2; ++rt){
        int r = wrq + rt*16 + l15;
        int ch = r*8 + ((s*4 + l4) ^ (r & 7));
        ap[rt] = *(const short8v*)(Wp + ch*8);
        an[rt] = *(const short8v*)(Wn + ch*8);
      }
#pragma unroll
      for (int ct=0; ct<4; ++ct){
        int hr = hw + ct*16 + l15;
        b[ct] = *(const short8v*)((const char*)Ktile + hr*128 + ((s*4 + l4) ^ (hr & 7))*16);
      }
#pragma unroll
      for (int rt=0; rt<2; ++rt)
#pragma unroll
        for (int ct=0; ct<4; ++ct){
          accP[rt][ct] = __builtin_amdgcn_mfma_f32_16x16x32_bf16(ap[rt], b[ct], accP[rt][ct], 0,0,0);
          accN[rt][ct] = __builtin_amdgcn_mfma_f32_16x16x32_bf16(an[rt], b[ct], accN[rt][ct], 0,0,0);
        }
    }
    __syncthreads();
  }

  // epilogue: scale, gate by Q (hi+lo), staged 32-row phases through reused LDS
  float isp[2][4], isn[2][4];
#pragma unroll
  for (int rt=0; rt<2; ++rt)
#pragma unroll
    for (int reg=0; reg<4; ++reg){
      int row = rowBase + wrq + rt*16 + l4*4 + reg;
      isp[rt][reg] = rsp[row];
      isn[rt][reg] = rsn[row];
    }
  float* Pout = (float*)smem;   // [32][260] = 33280 B
#pragma unroll
  for (int sign=0; sign<2; ++sign){
#pragma unroll
    for (int rh=0; rh<2; ++rh){
      if ((w >> 2) == rh){
#pragma unroll
        for (int rt=0; rt<2; ++rt)
#pragma unroll
          for (int ct=0; ct<4; ++ct)
#pragma unroll
            for (int reg=0; reg<4; ++reg){
              float v = sign ? accN[rt][ct][reg]*isn[rt][reg]
                             : accP[rt][ct][reg]*isp[rt][reg];
              Pout[(rt*16 + l4*4 + reg)*260 + hw + ct*16 + l15] = v;
            }
      }
      __syncthreads();
      float* outX = sign ? outN : outP;
#pragma unroll
      for (int p=0; p<4; ++p){
        int row = t >> 4;                 // 0..31
        int col = (t & 15)*4 + p*64;      // 0..252
        int grow = rowBase + rh*32 + row;
        float4 pv = *(float4*)&Pout[row*260 + col];
        float4 qv = ld4bf(Qhi, Qlo, (size_t)grow*HID + hBase + col);
        float4 o; o.x=pv.x*qv.x; o.y=pv.y*qv.y; o.z=pv.z*qv.z; o.w=pv.w*qv.w;
        *(float4*)&outX[(size_t)grow*HID + hBase + col] = o;
      }
      __syncthreads();
    }
  }
}

// ============================ CSR upload (skew-independent) ============================

__global__ __launch_bounds__(256) void csr_scan(const int* __restrict__ cnt,
                                                int* __restrict__ off, int* __restrict__ woff){
  __shared__ int partial[256];
  const int t = threadIdx.x;
  const int base = t*8;
  int local[8]; int s = 0;
#pragma unroll
  for (int j=0;j<8;++j){ local[j] = s; s += cnt[base+j]; }
  partial[t] = s;
  __syncthreads();
  for (int d=1; d<256; d<<=1){
    int v = (t>=d) ? partial[t-d] : 0;
    __syncthreads();
    partial[t] += v;
    __syncthreads();
  }
  int pre = (t==0) ? 0 : partial[t-1];
#pragma unroll
  for (int j=0;j<8;++j){ int o = pre + local[j]; off[base+j]=o; woff[base+j]=o; }
  if (t==255) off[2048] = partial[255];
}

__global__ __launch_bounds__(256) void csr_fill(const int* __restrict__ gidx,
                                                const float* __restrict__ rowm,
                                                const float* __restrict__ colmax,
                                                int* __restrict__ woff,
                                                int* __restrict__ rows, float* __restrict__ wv,
                                                int* __restrict__ sid){
  int i = blockIdx.x*256 + threadIdx.x;
  int g = gidx[i];
  int p = atomicAdd(&woff[g], 1);
  rows[p] = i;
  wv[p] = __expf(rowm[i] - colmax[g]);
  sid[p] = g;
}

__global__ __launch_bounds__(256) void upload_scatter(
    const unsigned short* __restrict__ Qhi, const unsigned short* __restrict__ Qlo,
    const int* __restrict__ sid, const int* __restrict__ rows, const float* __restrict__ wv,
    const int* __restrict__ train, float* __restrict__ qacc)
{
  if (*train == 0) return;
  const int b = blockIdx.x, t = threadIdx.x;
  __shared__ int   s_sid[64];
  __shared__ int   s_row[64];
  __shared__ float s_w[64];
  if (t < 64){
    int p = b*64 + t;
    s_sid[t] = sid[p];
    s_row[t] = rows[p];
    s_w[t]   = wv[p];
  }
  __syncthreads();
  const int h0 = t*2;
  float a0 = 0.f, a1 = 0.f;
  int prev = s_sid[0];
#pragma unroll 4
  for (int p = 0; p < 64; ++p){
    int s = s_sid[p];
    if (s != prev){
      atomicAdd(&qacc[(size_t)prev*HID + h0],     a0);
      atomicAdd(&qacc[(size_t)prev*HID + h0 + 1], a1);
      a0 = 0.f; a1 = 0.f; prev = s;
    }
    int row = s_row[p];
    float w = s_w[p];
    unsigned h = *(const unsigned*)(Qhi + (size_t)row*HID + h0);
    unsigned l = *(const unsigned*)(Qlo + (size_t)row*HID + h0);
    a0 += w * (bf16_to_f32((unsigned short)(h & 0xffffu)) + bf16_to_f32((unsigned short)(l & 0xffffu)));
    a1 += w * (bf16_to_f32((unsigned short)(h >> 16))     + bf16_to_f32((unsigned short)(l >> 16)));
  }
  atomicAdd(&qacc[(size_t)prev*HID + h0],     a0);
  atomicAdd(&qacc[(size_t)prev*HID + h0 + 1], a1);
}

__global__ __launch_bounds__(256) void upload_finish(const float* __restrict__ qacc,
                                                     const float* __restrict__ Km,
                                                     const int* __restrict__ train,
                                                     float* __restrict__ mem)
{
  const int m = blockIdx.x, t = threadIdx.x;
  const int h0 = t * 2;
  float2 kv = *(const float2*)&Km[(size_t)m*HID + h0];
  if (*train == 0){
    mem[(size_t)m*HID + h0]     = kv.x;
    mem[(size_t)m*HID + h0 + 1] = kv.y;
    return;
  }
  float2 av = *(const float2*)&qacc[(size_t)m*HID + h0];
  float v0 = av.x + kv.x, v1 = av.y + kv.y;
  __shared__ float red[256];
  red[t] = v0*v0 + v1*v1;
  __syncthreads();
  for (int s = 128; s > 0; s >>= 1){
    if (t < s) red[t] += red[t + s];
    __syncthreads();
  }
  float rinv = 1.f / fmaxf(sqrtf(red[0]), 1e-12f);
  mem[(size_t)m*HID + h0]     = v0 * rinv;
  mem[(size_t)m*HID + h0 + 1] = v1 * rinv;
}

// pred[i] = dot(Q[i], Wd) + bd ; one wave per row, standalone & deterministic.
__global__ __launch_bounds__(256) void pred_kernel(const unsigned short* __restrict__ Qhi,
                                                   const unsigned short* __restrict__ Qlo,
                                                   const float* __restrict__ Wd,
                                                   const float* __restrict__ bd,
                                                   float* __restrict__ pred)
{
  const int w = threadIdx.x >> 6, lane = threadIdx.x & 63;
  const int row = blockIdx.x * 4 + w;
  size_t base = (size_t)row * HID + lane*8;
  float4 a = ld4bf(Qhi, Qlo, base);
  float4 b = ld4bf(Qhi, Qlo, base + 4);
  float4 wa = *(const float4*)&Wd[lane*8];
  float4 wb = *(const float4*)&Wd[lane*8 + 4];
  float p = a.x*wa.x + a.y*wa.y + a.z*wa.z + a.w*wa.w
          + b.x*wb.x + b.y*wb.y + b.z*wb.z + b.w*wb.w;
#pragma unroll
  for (int d = 32; d > 0; d >>= 1) p += __shfl_down(p, d);
  if (lane == 0) pred[row] = p + bd[0];
}

// ============================ host ============================

extern "C" void kernel_launch(void* const* d_in, const int* in_sizes, int n_in,
                              void* d_out, int out_size, void* d_ws, size_t ws_size,
                              hipStream_t stream)
{
  const float* x   = (const float*)d_in[0];
  const float* Km  = (const float*)d_in[1];
  const float* W1  = (const float*)d_in[2];
  const float* b1  = (const float*)d_in[3];
  const float* W2  = (const float*)d_in[4];
  const float* b2  = (const float*)d_in[5];
  const float* W3  = (const float*)d_in[6];
  const float* b3  = (const float*)d_in[7];
  const float* Wd  = (const float*)d_in[8];
  const float* bd  = (const float*)d_in[9];
  const int* train = (const int*)d_in[10];

  float* out  = (float*)d_out;
  float* pred = out;
  float* outN = out + 16384;
  float* outP = out + 16384 + 8388608;
  float* memo = out + 16384 + 2*8388608;

  char* ws = (char*)d_ws;
  unsigned short* Qhi   = (unsigned short*)(ws + 0);           // 16,777,216
  unsigned short* Qlo   = (unsigned short*)(ws + 16777216);    // 16,777,216
  unsigned short* xph   = (unsigned short*)(ws + 33554432);    // 12,582,912
  unsigned short* xpl   = (unsigned short*)(ws + 46137344);    // 12,582,912
  unsigned short* h1h   = (unsigned short*)(ws + 58720256);    // 16,777,216
  unsigned short* h1l   = (unsigned short*)(ws + 75497472);    // 16,777,216
  unsigned short* h2h   = (unsigned short*)(ws + 92274688);    // 16,777,216
  unsigned short* h2l   = (unsigned short*)(ws + 109051904);   // 16,777,216 (R0 end 125,829,120)
  unsigned short* Sb    = (unsigned short*)(ws + 33554432);    // 67,108,864 (aliases R0)
  unsigned short* Khi   = (unsigned short*)(ws + 125829120);   //  2,097,152
  unsigned short* Klo   = (unsigned short*)(ws + 127926272);   //  2,097,152
  unsigned short* Kt    = (unsigned short*)(ws + 130023424);   //  2,097,152
  unsigned short* W1ph  = (unsigned short*)(ws + 132120576);   //    393,216
  unsigned short* W1pl  = (unsigned short*)(ws + 132513792);   //    393,216
  unsigned short* W2h   = (unsigned short*)(ws + 132907008);   //    524,288
  unsigned short* W2l   = (unsigned short*)(ws + 133431296);   //    524,288
  unsigned short* W3h   = (unsigned short*)(ws + 133955584);   //    524,288
  unsigned short* W3l   = (unsigned short*)(ws + 134479872);   //    524,288
  float* pmax    = (float*)(ws + 135004160);                   //  2,097,152
  int*   pcol    = (int*)  (ws + 137101312);                   //  2,097,152
  float* psum    = (float*)(ws + 139198464);                   //  2,097,152
  float* pnmax   = (float*)(ws + 141295616);                   //  2,097,152
  float* pnsum   = (float*)(ws + 143392768);                   //  2,097,152
  float* pcolmax = (float*)(ws + 145489920);                   //  4,194,304 (512 rows)
  float* rowm    = (float*)(ws + 149684224);
  float* rsp     = (float*)(ws + 149749760);
  float* rmn     = (float*)(ws + 149815296);
  float* rsn     = (float*)(ws + 149880832);
  int*   gidx    = (int*)  (ws + 149946368);
  float* colmax  = (float*)(ws + 150011904);
  int*   cnt     = (int*)  (ws + 150020096);                   //      8,192
  int*   off     = (int*)  (ws + 150028288);                   //      8,448 (2049 ints)
  int*   woff    = (int*)  (ws + 150036736);                   //      8,192
  int*   rows    = (int*)  (ws + 150044928);                   //     65,536
  float* wv      = (float*)(ws + 150110464);                   //     65,536
  int*   sid     = (int*)  (ws + 150176000);                   //     65,536
  float* qacc    = (float*)(ws + 150241536);                   //  4,194,304
  const size_t NEED = 154435840ull;
  if (ws_size < NEED) return;  // harness provides >= 155 MB (proven round 2)

  dim3 blk(256);
  // conversions
  cvt_pad_split<<<(N_ROWS*KP1/4 + 255)/256, blk, 0, stream>>>(x,  xph,  xpl,  N_ROWS, D_INN, KP1);
  cvt_pad_split<<<(HID*KP1/4 + 255)/256,    blk, 0, stream>>>(W1, W1ph, W1pl, HID,    D_INN, KP1);
  cvt_split<<<HID*HID/2048,     blk, 0, stream>>>(W2, W2h, W2l, HID*HID);
  cvt_split<<<HID*HID/2048,     blk, 0, stream>>>(W3, W3h, W3l, HID*HID);
  cvt_split<<<M_SLOTS*HID/2048, blk, 0, stream>>>(Km, Khi, Klo, M_SLOTS*HID);
  kt_kernel<<<dim3(32, 8), blk, 0, stream>>>(Km, Kt);

  // MLP (split-bf16 MFMA, BM=128 16x16)
  mlp_gemm<<<dim3(N_ROWS/128, 4), dim3(512), 0, stream>>>(xph, xpl, W1ph, W1pl, b1, h1h, h1l, KP1);
  mlp_gemm<<<dim3(N_ROWS/128, 4), dim3(512), 0, stream>>>(h1h, h1l, W2h, W2l, b2, h2h, h2l, HID);
  mlp_gemm<<<dim3(N_ROWS/128, 4), dim3(512), 0, stream>>>(h2h, h2l, W3h, W3l, b3, Qhi, Qlo, HID);

  // attention stats + PV
  sgemm_stats<<<dim3(16, 128), dim3(512), 0, stream>>>(Qhi, Qlo, Khi, Klo, Sb,
                                                       pmax, pcol, psum, pnmax, pnsum, pcolmax);
  hipMemsetAsync(cnt, 0, M_SLOTS*sizeof(int), stream);
  merge_all<<<72, blk, 0, stream>>>(pmax, pcol, psum, pnmax, pnsum, pcolmax,
                                    rowm, rsp, rmn, rsn, gidx, cnt, colmax);
  pv2<<<dim3(2, 256), dim3(512), 0, stream>>>(Sb, Kt, rowm, rsp, rmn, rsn, Qhi, Qlo, outP, outN);

  // upload via CSR + bounded scatter
  hipMemsetAsync(qacc, 0, M_SLOTS*HID*sizeof(float), stream);
  csr_scan<<<1, blk, 0, stream>>>(cnt, off, woff);
  csr_fill<<<N_ROWS/256, blk, 0, stream>>>(gidx, rowm, colmax, woff, rows, wv, sid);
  upload_scatter<<<N_ROWS/64, blk, 0, stream>>>(Qhi, Qlo, sid, rows, wv, train, qacc);
  upload_finish<<<M_SLOTS, blk, 0, stream>>>(qacc, Km, train, memo);

  // pred last (standalone, deterministic)
  pred_kernel<<<N_ROWS/4, blk, 0, stream>>>(Qhi, Qlo, Wd, bd, pred);
}

// Round 13
// 474.384 us; speedup vs baseline: 1.3298x; 1.0240x over previous
//
#include <hip/hip_runtime.h>
#include <math.h>

// Problem constants (fixed by the reference).
#define N_ROWS 16384
#define D_INN  360
#define KP1    384      // D_INN padded to multiple of 64
#define HID    512
#define M_SLOTS 2048

typedef __attribute__((ext_vector_type(8))) short short8v;
typedef __attribute__((ext_vector_type(4))) float f32x4;
typedef __attribute__((address_space(1))) unsigned int as1_uint;
typedef __attribute__((address_space(3))) unsigned int as3_uint;

// ---- bf16 helpers (manual, RNE) ----
__device__ __forceinline__ unsigned short bf16_rne(float f){
  unsigned u = __float_as_uint(f);
  unsigned r = u + 0x7FFFu + ((u >> 16) & 1u);
  return (unsigned short)(r >> 16);
}
__device__ __forceinline__ float bf16_to_f32(unsigned short h){
  return __uint_as_float(((unsigned)h) << 16);
}

__device__ __forceinline__ void glds16(const void* g, void* l){
  __builtin_amdgcn_global_load_lds((const as1_uint*)g, (as3_uint*)l, 16, 0, 0);
}

// reconstruct 4 consecutive f32 from hi/lo bf16 pair arrays
__device__ __forceinline__ float4 ld4bf(const unsigned short* hi, const unsigned short* lo, size_t off){
  uint2 h = *(const uint2*)(hi + off);
  uint2 l = *(const uint2*)(lo + off);
  float4 r;
  r.x = bf16_to_f32((unsigned short)(h.x & 0xffffu)) + bf16_to_f32((unsigned short)(l.x & 0xffffu));
  r.y = bf16_to_f32((unsigned short)(h.x >> 16))     + bf16_to_f32((unsigned short)(l.x >> 16));
  r.z = bf16_to_f32((unsigned short)(h.y & 0xffffu)) + bf16_to_f32((unsigned short)(l.y & 0xffffu));
  r.w = bf16_to_f32((unsigned short)(h.y >> 16))     + bf16_to_f32((unsigned short)(l.y >> 16));
  return r;
}

// ============================ fused init kernel ============================
// All conversions + Kt transpose + cnt/qacc zeroing in ONE launch.
// Block ranges: [0,6144) cvt x | [6144,6336) cvt W1 | [6336,6464) W2 |
// [6464,6592) W3 | [6592,7104) Km | [7104,7360) kt | [7360,7872) qacc zero |
// [7872,7880) cnt zero. Bodies identical to the proven standalone kernels.

__device__ __forceinline__ void split_body(const float* __restrict__ src,
                                           unsigned short* __restrict__ hi,
                                           unsigned short* __restrict__ lo, int b){
  int idx = (b*256 + (int)threadIdx.x) * 8;
  float4 a = *(const float4*)&src[idx];
  float4 bb = *(const float4*)&src[idx+4];
  float v[8] = {a.x,a.y,a.z,a.w,bb.x,bb.y,bb.z,bb.w};
  short8v hv, lv;
#pragma unroll
  for (int e=0;e<8;++e){
    unsigned short h = bf16_rne(v[e]);
    hv[e] = (short)h;
    lv[e] = (short)bf16_rne(v[e] - bf16_to_f32(h));
  }
  *(short8v*)&hi[idx] = hv;
  *(short8v*)&lo[idx] = lv;
}

__device__ __forceinline__ void pad_split_body(const float* __restrict__ src,
                                               unsigned short* __restrict__ hi,
                                               unsigned short* __restrict__ lo,
                                               int R, int Ksrc, int Kp, int b){
  long long e0 = ((long long)b*256 + threadIdx.x) * 4;
  if (e0 >= (long long)R*Kp) return;
  int row = (int)(e0 / Kp), c = (int)(e0 % Kp);
  unsigned short h4[4], l4[4];
  if (c < Ksrc){
    float4 v = *(const float4*)&src[(size_t)row*Ksrc + c];
    float vv[4] = {v.x, v.y, v.z, v.w};
#pragma unroll
    for (int e=0;e<4;++e){
      unsigned short h = bf16_rne(vv[e]);
      h4[e] = h;
      l4[e] = bf16_rne(vv[e] - bf16_to_f32(h));
    }
  } else {
#pragma unroll
    for (int e=0;e<4;++e){ h4[e]=0; l4[e]=0; }
  }
  *(uint2*)&hi[(size_t)row*Kp + c] = *(uint2*)h4;
  *(uint2*)&lo[(size_t)row*Kp + c] = *(uint2*)l4;
}

__global__ __launch_bounds__(256) void init_all(
    const float* __restrict__ x,  const float* __restrict__ W1,
    const float* __restrict__ W2, const float* __restrict__ W3,
    const float* __restrict__ Km,
    unsigned short* __restrict__ xph,  unsigned short* __restrict__ xpl,
    unsigned short* __restrict__ W1ph, unsigned short* __restrict__ W1pl,
    unsigned short* __restrict__ W2h,  unsigned short* __restrict__ W2l,
    unsigned short* __restrict__ W3h,  unsigned short* __restrict__ W3l,
    unsigned short* __restrict__ Khi,  unsigned short* __restrict__ Klo,
    unsigned short* __restrict__ Kt,
    float* __restrict__ qacc, int* __restrict__ cnt)
{
  __shared__ float tile[64][65];  // used by the kt branch only
  int b = blockIdx.x;
  const int t = threadIdx.x;
  if (b < 6144){ pad_split_body(x, xph, xpl, N_ROWS, D_INN, KP1, b); return; }
  b -= 6144;
  if (b < 192){ pad_split_body(W1, W1ph, W1pl, HID, D_INN, KP1, b); return; }
  b -= 192;
  if (b < 128){ split_body(W2, W2h, W2l, b); return; }
  b -= 128;
  if (b < 128){ split_body(W3, W3h, W3l, b); return; }
  b -= 128;
  if (b < 512){ split_body(Km, Khi, Klo, b); return; }
  b -= 512;
  if (b < 256){
    // kt transpose: Kt[h][slot] = bf16(K[slot][h])
    const int sb = (b & 31) * 64;
    const int hb = (b >> 5) * 64;
    {
      int r = t >> 2, cq = t & 3;
#pragma unroll
      for (int q=0;q<4;++q){
        float4 v = *(const float4*)&Km[(size_t)(sb+r)*HID + hb + cq*16 + q*4];
        tile[r][cq*16+q*4+0]=v.x; tile[r][cq*16+q*4+1]=v.y;
        tile[r][cq*16+q*4+2]=v.z; tile[r][cq*16+q*4+3]=v.w;
      }
    }
    __syncthreads();
    {
      int hl = t >> 2, sq = t & 3;
      unsigned short w16[16];
#pragma unroll
      for (int q=0;q<16;++q) w16[q] = bf16_rne(tile[sq*16+q][hl]);
      *(uint4*)&Kt[(size_t)(hb+hl)*M_SLOTS + sb + sq*16]     = *(uint4*)&w16[0];
      *(uint4*)&Kt[(size_t)(hb+hl)*M_SLOTS + sb + sq*16 + 8] = *(uint4*)&w16[8];
    }
    return;
  }
  b -= 256;
  if (b < 512){
    int idx = (b*256 + t)*8;
    float4 z = {0.f,0.f,0.f,0.f};
    *(float4*)&qacc[idx]     = z;
    *(float4*)&qacc[idx + 4] = z;
    return;
  }
  b -= 512;
  { int i = b*256 + t; if (i < M_SLOTS) cnt[i] = 0; }
}

// ============================ MLP GEMM (3-term split bf16, 16x16, BM=128, 512 thr) ============================
__global__ __launch_bounds__(512) void mlp_gemm(
    const unsigned short* __restrict__ Ah_g, const unsigned short* __restrict__ Al_g,
    const unsigned short* __restrict__ Wh_g, const unsigned short* __restrict__ Wl_g,
    const float* __restrict__ bias,
    unsigned short* __restrict__ Ohi, unsigned short* __restrict__ Olo,
    int Kp)
{
  __shared__ char smem[65536];
  unsigned short* Ah = (unsigned short*)smem;            // [128][64] hi
  unsigned short* Al = (unsigned short*)(smem + 16384);  // [128][64] lo
  unsigned short* Bh = (unsigned short*)(smem + 32768);  // [128][64] hi
  unsigned short* Bl = (unsigned short*)(smem + 49152);  // [128][64] lo
  const int t = threadIdx.x;
  const int lane = t & 63, w = t >> 6;            // 8 waves
  const int l15 = lane & 15, l4 = lane >> 4;
  const int rowBase = blockIdx.x * 128;
  const int colBase = blockIdx.y * 128;
  const int wr = (w >> 1) * 32;
  const int wc = (w & 1) * 64;

  f32x4 acc[2][4];
#pragma unroll
  for (int i=0;i<2;++i)
#pragma unroll
    for (int j=0;j<4;++j) acc[i][j] = (f32x4){0.f,0.f,0.f,0.f};

  const int nkt = Kp >> 6;
  for (int kt = 0; kt < nkt; ++kt){
    const int k0 = kt * 64;
#pragma unroll
    for (int p = 0; p < 2; ++p){
      int idx = p*512 + t;
      int r = idx >> 3, c = idx & 7;
      int cc = c ^ (r & 7);
      size_t go = (size_t)(rowBase + r) * Kp + (k0 + cc*8);
      glds16(Ah_g + go, (char*)Ah + idx*16);
      glds16(Al_g + go, (char*)Al + idx*16);
    }
#pragma unroll
    for (int p = 0; p < 2; ++p){
      int idx = p*512 + t;
      int r = idx >> 3, c = idx & 7;
      int cc = c ^ (r & 7);
      size_t go = (size_t)(colBase + r) * Kp + (k0 + cc*8);
      glds16(Wh_g + go, (char*)Bh + idx*16);
      glds16(Wl_g + go, (char*)Bl + idx*16);
    }
    __syncthreads();

#pragma unroll
    for (int s = 0; s < 2; ++s){
      short8v a_h[2], a_l[2], b_h[4], b_l[4];
#pragma unroll
      for (int rt = 0; rt < 2; ++rt){
        int r = wr + rt*16 + l15;
        int off = r*128 + ((s*4 + l4) ^ (r & 7))*16;
        a_h[rt] = *(const short8v*)((const char*)Ah + off);
        a_l[rt] = *(const short8v*)((const char*)Al + off);
      }
#pragma unroll
      for (int ct = 0; ct < 4; ++ct){
        int r = wc + ct*16 + l15;
        int off = r*128 + ((s*4 + l4) ^ (r & 7))*16;
        b_h[ct] = *(const short8v*)((const char*)Bh + off);
        b_l[ct] = *(const short8v*)((const char*)Bl + off);
      }
#pragma unroll
      for (int rt = 0; rt < 2; ++rt)
#pragma unroll
        for (int ct = 0; ct < 4; ++ct){
          acc[rt][ct] = __builtin_amdgcn_mfma_f32_16x16x32_bf16(a_h[rt], b_h[ct], acc[rt][ct], 0,0,0);
          acc[rt][ct] = __builtin_amdgcn_mfma_f32_16x16x32_bf16(a_h[rt], b_l[ct], acc[rt][ct], 0,0,0);
          acc[rt][ct] = __builtin_amdgcn_mfma_f32_16x16x32_bf16(a_l[rt], b_h[ct], acc[rt][ct], 0,0,0);
        }
    }
    __syncthreads();
  }

  // epilogue: bias + relu, split hi/lo, stage through LDS for coalesced writes
  float bcol[4];
#pragma unroll
  for (int ct=0; ct<4; ++ct) bcol[ct] = bias[colBase + wc + ct*16 + l15];
  unsigned short* Sout = (unsigned short*)smem;  // [128][136] = 34816 B
#pragma unroll
  for (int rt=0; rt<2; ++rt)
#pragma unroll
    for (int ct=0; ct<4; ++ct)
#pragma unroll
      for (int reg=0; reg<4; ++reg){
        float v = acc[rt][ct][reg] + bcol[ct];
        v = v > 0.f ? v : 0.f;
        acc[rt][ct][reg] = v;
        Sout[(wr + rt*16 + l4*4 + reg)*136 + wc + ct*16 + l15] = bf16_rne(v);
      }
  __syncthreads();
#pragma unroll
  for (int p = 0; p < 4; ++p){
    int row = (t >> 4) + p*32;
    int c8 = (t & 15) * 8;
    uint4 v = *(uint4*)&Sout[row*136 + c8];
    *(uint4*)&Ohi[(size_t)(rowBase+row)*HID + colBase + c8] = v;
  }
  __syncthreads();
#pragma unroll
  for (int rt=0; rt<2; ++rt)
#pragma unroll
    for (int ct=0; ct<4; ++ct)
#pragma unroll
      for (int reg=0; reg<4; ++reg){
        float v = acc[rt][ct][reg];
        unsigned short h = bf16_rne(v);
        Sout[(wr + rt*16 + l4*4 + reg)*136 + wc + ct*16 + l15] = bf16_rne(v - bf16_to_f32(h));
      }
  __syncthreads();
#pragma unroll
  for (int p = 0; p < 4; ++p){
    int row = (t >> 4) + p*32;
    int c8 = (t & 15) * 8;
    uint4 v = *(uint4*)&Sout[row*136 + c8];
    *(uint4*)&Olo[(size_t)(rowBase+row)*HID + colBase + c8] = v;
  }
}

// ============================ S GEMM + stats (16x16, BM=128 x BN=128, 512 thr) ============================
__global__ __launch_bounds__(512) void sgemm_stats(
    const unsigned short* __restrict__ Qhi, const unsigned short* __restrict__ Qlo,
    const unsigned short* __restrict__ Khi, const unsigned short* __restrict__ Klo,
    unsigned short* __restrict__ Sb,
    float* __restrict__ pmax, int* __restrict__ pcol,
    float* __restrict__ psum, float* __restrict__ pnmax, float* __restrict__ pnsum,
    float* __restrict__ pcolmax)
{
  __shared__ char smem[65536];
  unsigned short* Ah = (unsigned short*)smem;            // [128][64] hi
  unsigned short* Al = (unsigned short*)(smem + 16384);  // [128][64] lo
  unsigned short* Bh = (unsigned short*)(smem + 32768);  // [128][64] hi
  unsigned short* Bl = (unsigned short*)(smem + 49152);  // [128][64] lo
  const int t = threadIdx.x;
  const int lane = t & 63, w = t >> 6;            // 8 waves
  const int l15 = lane & 15, l4 = lane >> 4;
  const int cb = blockIdx.x;      // 0..15  col block
  const int rb = blockIdx.y;      // 0..127 row block
  const int rowBase = rb * 128;
  const int colBase = cb * 128;
  const int wr = (w >> 1) * 32;   // row quarter (0,32,64,96)
  const int wc = (w & 1) * 64;    // col half

  f32x4 acc[2][4];
#pragma unroll
  for (int i=0;i<2;++i)
#pragma unroll
    for (int j=0;j<4;++j) acc[i][j] = (f32x4){0.f,0.f,0.f,0.f};

  for (int kt = 0; kt < 8; ++kt){
    const int k0 = kt * 64;
#pragma unroll
    for (int p = 0; p < 2; ++p){
      int idx = p*512 + t;
      int r = idx >> 3, c = idx & 7;
      int cc = c ^ (r & 7);
      size_t go = (size_t)(rowBase + r) * HID + (k0 + cc*8);
      glds16(Qhi + go, (char*)Ah + idx*16);
      glds16(Qlo + go, (char*)Al + idx*16);
    }
#pragma unroll
    for (int p = 0; p < 2; ++p){
      int idx = p*512 + t;
      int r = idx >> 3, c = idx & 7;
      int cc = c ^ (r & 7);
      size_t go = (size_t)(colBase + r) * HID + (k0 + cc*8);
      glds16(Khi + go, (char*)Bh + idx*16);
      glds16(Klo + go, (char*)Bl + idx*16);
    }
    __syncthreads();

#pragma unroll
    for (int s = 0; s < 2; ++s){
      short8v a_h[2], a_l[2], b_h[4], b_l[4];
#pragma unroll
      for (int rt = 0; rt < 2; ++rt){
        int r = wr + rt*16 + l15;
        int off = r*128 + ((s*4 + l4) ^ (r & 7))*16;
        a_h[rt] = *(const short8v*)((const char*)Ah + off);
        a_l[rt] = *(const short8v*)((const char*)Al + off);
      }
#pragma unroll
      for (int ct = 0; ct < 4; ++ct){
        int r = wc + ct*16 + l15;
        int off = r*128 + ((s*4 + l4) ^ (r & 7))*16;
        b_h[ct] = *(const short8v*)((const char*)Bh + off);
        b_l[ct] = *(const short8v*)((const char*)Bl + off);
      }
#pragma unroll
      for (int rt = 0; rt < 2; ++rt)
#pragma unroll
        for (int ct = 0; ct < 4; ++ct){
          acc[rt][ct] = __builtin_amdgcn_mfma_f32_16x16x32_bf16(a_h[rt], b_h[ct], acc[rt][ct], 0,0,0);
          acc[rt][ct] = __builtin_amdgcn_mfma_f32_16x16x32_bf16(a_h[rt], b_l[ct], acc[rt][ct], 0,0,0);
          acc[rt][ct] = __builtin_amdgcn_mfma_f32_16x16x32_bf16(a_l[rt], b_h[ct], acc[rt][ct], 0,0,0);
        }
    }
    __syncthreads();
  }

  // ---- row stats (per wave over its 64-col half) ----
#pragma unroll
  for (int rt = 0; rt < 2; ++rt){
#pragma unroll
    for (int reg = 0; reg < 4; ++reg){
      float v0 = acc[rt][0][reg], v1 = acc[rt][1][reg];
      float v2 = acc[rt][2][reg], v3 = acc[rt][3][reg];
      float bvv = v0; int bcc = colBase + wc + l15;
      if (v1 > bvv){ bvv = v1; bcc = colBase + wc + 16 + l15; }
      if (v2 > bvv){ bvv = v2; bcc = colBase + wc + 32 + l15; }
      if (v3 > bvv){ bvv = v3; bcc = colBase + wc + 48 + l15; }
      float mnv = fminf(fminf(v0,v1), fminf(v2,v3));
#pragma unroll
      for (int d = 1; d < 16; d <<= 1){
        float ov = __shfl_xor(bvv, d);
        int   oc = __shfl_xor(bcc, d);
        float om = __shfl_xor(mnv, d);
        if (ov > bvv || (ov == bvv && oc < bcc)){ bvv = ov; bcc = oc; }
        mnv = fminf(mnv, om);
      }
      float sp = __expf(v0-bvv)+__expf(v1-bvv)+__expf(v2-bvv)+__expf(v3-bvv);
      float sn = __expf(mnv-v0)+__expf(mnv-v1)+__expf(mnv-v2)+__expf(mnv-v3);
#pragma unroll
      for (int d = 1; d < 16; d <<= 1){ sp += __shfl_xor(sp,d); sn += __shfl_xor(sn,d); }
      if (l15 == 0){
        int row = rowBase + wr + rt*16 + l4*4 + reg;
        size_t pi = (size_t)row*32 + cb*2 + (w & 1);
        pmax[pi] = bvv; pcol[pi] = bcc; psum[pi] = sp;
        pnmax[pi] = -mnv; pnsum[pi] = sn;
      }
    }
  }

  // ---- per-column tile max (over this wave's 32 rows) ----
#pragma unroll
  for (int ct = 0; ct < 4; ++ct){
    float cm = -1e30f;
#pragma unroll
    for (int rt=0; rt<2; ++rt)
#pragma unroll
      for (int reg=0; reg<4; ++reg) cm = fmaxf(cm, acc[rt][ct][reg]);
    cm = fmaxf(cm, __shfl_xor(cm, 16));
    cm = fmaxf(cm, __shfl_xor(cm, 32));
    if (l4 == 0)
      pcolmax[(size_t)(rb*4 + (w>>1))*M_SLOTS + colBase + wc + ct*16 + l15] = cm;
  }

  // ---- S bf16 write (staged through LDS for coalescing) ----
  __syncthreads();
  unsigned short* Sout = (unsigned short*)smem;  // [128][136] = 34816 B
#pragma unroll
  for (int rt=0; rt<2; ++rt)
#pragma unroll
    for (int ct=0; ct<4; ++ct)
#pragma unroll
      for (int reg=0; reg<4; ++reg)
        Sout[(wr + rt*16 + l4*4 + reg)*136 + wc + ct*16 + l15] = bf16_rne(acc[rt][ct][reg]);
  __syncthreads();
#pragma unroll
  for (int p = 0; p < 4; ++p){
    int row = (t >> 4) + p*32;
    int c8 = (t & 15) * 8;
    uint4 v = *(uint4*)&Sout[row*136 + c8];
    *(uint4*)&Sb[(size_t)(rowBase+row)*M_SLOTS + colBase + c8] = v;
  }
}

// fused merge_rows (blocks 0..63) + merge_cols (blocks 64..71)
__global__ __launch_bounds__(256) void merge_all(
    const float* __restrict__ pmax, const int* __restrict__ pcol,
    const float* __restrict__ psum, const float* __restrict__ pnmax,
    const float* __restrict__ pnsum, const float* __restrict__ pcolmax,
    float* __restrict__ rowm, float* __restrict__ rsp,
    float* __restrict__ rmn, float* __restrict__ rsn, int* __restrict__ gidx,
    int* __restrict__ cnt, float* __restrict__ colmax)
{
  if (blockIdx.x < 64){
    int row = blockIdx.x*256 + threadIdx.x;
    const size_t base = (size_t)row*32;
    float m = -1e30f; int g = 0;
    for (int i=0;i<32;++i){
      float v = pmax[base+i];
      if (v > m){ m = v; g = pcol[base+i]; }
    }
    float s = 0.f;
    for (int i=0;i<32;++i) s += psum[base+i] * __expf(pmax[base+i]-m);
    float mn = -1e30f;
    for (int i=0;i<32;++i) mn = fmaxf(mn, pnmax[base+i]);
    float sn = 0.f;
    for (int i=0;i<32;++i) sn += pnsum[base+i] * __expf(pnmax[base+i]-mn);
    rowm[row]=m; gidx[row]=g; rsp[row]=1.f/s; rmn[row]=mn; rsn[row]=1.f/sn;
    atomicAdd(&cnt[g], 1);
  } else {
    int c = (blockIdx.x - 64)*256 + threadIdx.x;
    float m = -1e30f;
    for (int r=0;r<512;++r) m = fmaxf(m, pcolmax[(size_t)r*M_SLOTS + c]);
    colmax[c] = m;
  }
}

// ============================ PV (S read once, 16x16, 64 rows, 512 thr) ============================
#define PV_RB 64
#define PV_HB 256
__global__ __launch_bounds__(512) void pv2(
    const unsigned short* __restrict__ Sb, const unsigned short* __restrict__ Kt,
    const float* __restrict__ rowm, const float* __restrict__ rsp,
    const float* __restrict__ rmn, const float* __restrict__ rsn,
    const unsigned short* __restrict__ Qhi, const unsigned short* __restrict__ Qlo,
    float* __restrict__ outP, float* __restrict__ outN)
{
  __shared__ char smem[49152];
  unsigned short* Ktile = (unsigned short*)smem;          // [256 h][64 slots], chunk-swizzled, 32KB
  unsigned short* Wp = (unsigned short*)(smem + 32768);   // [64 rows][8 octets] 16B chunks, 8KB
  unsigned short* Wn = (unsigned short*)(smem + 40960);   // 8KB
  const int t = threadIdx.x, lane = t & 63, w = t >> 6;
  const int l15 = lane & 15, l4 = lane >> 4;
  const int rowBase = blockIdx.y * PV_RB;
  const int hBase = blockIdx.x * PV_HB;
  const int wrq = (w >> 2) * 32;       // wave row half (0 or 32)
  const int hw = (w & 3) * 64;         // wave col group
  const int rS = t >> 3;               // 0..63: row for weight computation
  const int c8 = t & 7;                // slot-octet
  const float mp = rowm[rowBase + rS], mn = rmn[rowBase + rS];

  f32x4 accP[2][4], accN[2][4];
#pragma unroll
  for (int i=0;i<2;++i)
#pragma unroll
    for (int j=0;j<4;++j){ accP[i][j]=(f32x4){0.f,0.f,0.f,0.f}; accN[i][j]=(f32x4){0.f,0.f,0.f,0.f}; }

  for (int kt = 0; kt < 32; ++kt){
    const int k0 = kt*64;
#pragma unroll
    for (int p=0;p<4;++p){
      int idx = p*512 + t;
      int r = idx >> 3, c = idx & 7;
      int cc = c ^ (r & 7);
      glds16(Kt + (size_t)(hBase + r)*M_SLOTS + k0 + cc*8, (char*)Ktile + idx*16);
    }
    // exp-weights (64 rows x 64 slots), linear conflict-free write
    short8v sv = *(const short8v*)&Sb[(size_t)(rowBase + rS)*M_SLOTS + k0 + c8*8];
    short8v wp, wn;
#pragma unroll
    for (int e=0;e<8;++e){
      float sval = bf16_to_f32((unsigned short)sv[e]);
      wp[e] = (short)bf16_rne(__expf(sval - mp));
      wn[e] = (short)bf16_rne(__expf(-sval - mn));
    }
    {
      int ch = rS*8 + (c8 ^ (rS & 7));
      *(short8v*)(Wp + ch*8) = wp;
      *(short8v*)(Wn + ch*8) = wn;
    }
    __syncthreads();
#pragma unroll
    for (int s=0; s<2; ++s){
      short8v ap[2], an[2], b[4];
#pragma unroll
      for (int rt=0; rt<2; ++rt){
        int r = wrq + rt*16 + l15;
        int ch = r*8 + ((s*4 + l4) ^ (r & 7));
        ap[rt] = *(const short8v*)(Wp + ch*8);
        an[rt] = *(const short8v*)(Wn + ch*8);
      }
#pragma unroll
      for (int ct=0; ct<4; ++ct){
        int hr = hw + ct*16 + l15;
        b[ct] = *(const short8v*)((const char*)Ktile + hr*128 + ((s*4 + l4) ^ (hr & 7))*16);
      }
#pragma unroll
      for (int rt=0; rt<2; ++rt)
#pragma unroll
        for (int ct=0; ct<4; ++ct){
          accP[rt][ct] = __builtin_amdgcn_mfma_f32_16x16x32_bf16(ap[rt], b[ct], accP[rt][ct], 0,0,0);
          accN[rt][ct] = __builtin_amdgcn_mfma_f32_16x16x32_bf16(an[rt], b[ct], accN[rt][ct], 0,0,0);
        }
    }
    __syncthreads();
  }

  // epilogue: scale, gate by Q (hi+lo), staged 32-row phases through reused LDS
  float isp[2][4], isn[2][4];
#pragma unroll
  for (int rt=0; rt<2; ++rt)
#pragma unroll
    for (int reg=0; reg<4; ++reg){
      int row = rowBase + wrq + rt*16 + l4*4 + reg;
      isp[rt][reg] = rsp[row];
      isn[rt][reg] = rsn[row];
    }
  float* Pout = (float*)smem;   // [32][260] = 33280 B
#pragma unroll
  for (int sign=0; sign<2; ++sign){
#pragma unroll
    for (int rh=0; rh<2; ++rh){
      if ((w >> 2) == rh){
#pragma unroll
        for (int rt=0; rt<2; ++rt)
#pragma unroll
          for (int ct=0; ct<4; ++ct)
#pragma unroll
            for (int reg=0; reg<4; ++reg){
              float v = sign ? accN[rt][ct][reg]*isn[rt][reg]
                             : accP[rt][ct][reg]*isp[rt][reg];
              Pout[(rt*16 + l4*4 + reg)*260 + hw + ct*16 + l15] = v;
            }
      }
      __syncthreads();
      float* outX = sign ? outN : outP;
#pragma unroll
      for (int p=0; p<4; ++p){
        int row = t >> 4;                 // 0..31
        int col = (t & 15)*4 + p*64;      // 0..252
        int grow = rowBase + rh*32 + row;
        float4 pv = *(float4*)&Pout[row*260 + col];
        float4 qv = ld4bf(Qhi, Qlo, (size_t)grow*HID + hBase + col);
        float4 o; o.x=pv.x*qv.x; o.y=pv.y*qv.y; o.z=pv.z*qv.z; o.w=pv.w*qv.w;
        *(float4*)&outX[(size_t)grow*HID + hBase + col] = o;
      }
      __syncthreads();
    }
  }
}

// ============================ CSR upload (skew-independent) ============================

__global__ __launch_bounds__(256) void csr_scan(const int* __restrict__ cnt,
                                                int* __restrict__ off, int* __restrict__ woff){
  __shared__ int partial[256];
  const int t = threadIdx.x;
  const int base = t*8;
  int local[8]; int s = 0;
#pragma unroll
  for (int j=0;j<8;++j){ local[j] = s; s += cnt[base+j]; }
  partial[t] = s;
  __syncthreads();
  for (int d=1; d<256; d<<=1){
    int v = (t>=d) ? partial[t-d] : 0;
    __syncthreads();
    partial[t] += v;
    __syncthreads();
  }
  int pre = (t==0) ? 0 : partial[t-1];
#pragma unroll
  for (int j=0;j<8;++j){ int o = pre + local[j]; off[base+j]=o; woff[base+j]=o; }
  if (t==255) off[2048] = partial[255];
}

__global__ __launch_bounds__(256) void csr_fill(const int* __restrict__ gidx,
                                                const float* __restrict__ rowm,
                                                const float* __restrict__ colmax,
                                                int* __restrict__ woff,
                                                int* __restrict__ rows, float* __restrict__ wv,
                                                int* __restrict__ sid){
  int i = blockIdx.x*256 + threadIdx.x;
  int g = gidx[i];
  int p = atomicAdd(&woff[g], 1);
  rows[p] = i;
  wv[p] = __expf(rowm[i] - colmax[g]);
  sid[p] = g;
}

__global__ __launch_bounds__(256) void upload_scatter(
    const unsigned short* __restrict__ Qhi, const unsigned short* __restrict__ Qlo,
    const int* __restrict__ sid, const int* __restrict__ rows, const float* __restrict__ wv,
    const int* __restrict__ train, float* __restrict__ qacc)
{
  if (*train == 0) return;
  const int b = blockIdx.x, t = threadIdx.x;
  __shared__ int   s_sid[64];
  __shared__ int   s_row[64];
  __shared__ float s_w[64];
  if (t < 64){
    int p = b*64 + t;
    s_sid[t] = sid[p];
    s_row[t] = rows[p];
    s_w[t]   = wv[p];
  }
  __syncthreads();
  const int h0 = t*2;
  float a0 = 0.f, a1 = 0.f;
  int prev = s_sid[0];
#pragma unroll 4
  for (int p = 0; p < 64; ++p){
    int s = s_sid[p];
    if (s != prev){
      atomicAdd(&qacc[(size_t)prev*HID + h0],     a0);
      atomicAdd(&qacc[(size_t)prev*HID + h0 + 1], a1);
      a0 = 0.f; a1 = 0.f; prev = s;
    }
    int row = s_row[p];
    float w = s_w[p];
    unsigned h = *(const unsigned*)(Qhi + (size_t)row*HID + h0);
    unsigned l = *(const unsigned*)(Qlo + (size_t)row*HID + h0);
    a0 += w * (bf16_to_f32((unsigned short)(h & 0xffffu)) + bf16_to_f32((unsigned short)(l & 0xffffu)));
    a1 += w * (bf16_to_f32((unsigned short)(h >> 16))     + bf16_to_f32((unsigned short)(l >> 16)));
  }
  atomicAdd(&qacc[(size_t)prev*HID + h0],     a0);
  atomicAdd(&qacc[(size_t)prev*HID + h0 + 1], a1);
}

__global__ __launch_bounds__(256) void upload_finish(const float* __restrict__ qacc,
                                                     const float* __restrict__ Km,
                                                     const int* __restrict__ train,
                                                     float* __restrict__ mem)
{
  const int m = blockIdx.x, t = threadIdx.x;
  const int h0 = t * 2;
  float2 kv = *(const float2*)&Km[(size_t)m*HID + h0];
  if (*train == 0){
    mem[(size_t)m*HID + h0]     = kv.x;
    mem[(size_t)m*HID + h0 + 1] = kv.y;
    return;
  }
  float2 av = *(const float2*)&qacc[(size_t)m*HID + h0];
  float v0 = av.x + kv.x, v1 = av.y + kv.y;
  __shared__ float red[256];
  red[t] = v0*v0 + v1*v1;
  __syncthreads();
  for (int s = 128; s > 0; s >>= 1){
    if (t < s) red[t] += red[t + s];
    __syncthreads();
  }
  float rinv = 1.f / fmaxf(sqrtf(red[0]), 1e-12f);
  mem[(size_t)m*HID + h0]     = v0 * rinv;
  mem[(size_t)m*HID + h0 + 1] = v1 * rinv;
}

// pred[i] = dot(Q[i], Wd) + bd ; one wave per row, standalone & deterministic.
__global__ __launch_bounds__(256) void pred_kernel(const unsigned short* __restrict__ Qhi,
                                                   const unsigned short* __restrict__ Qlo,
                                                   const float* __restrict__ Wd,
                                                   const float* __restrict__ bd,
                                                   float* __restrict__ pred)
{
  const int w = threadIdx.x >> 6, lane = threadIdx.x & 63;
  const int row = blockIdx.x * 4 + w;
  size_t base = (size_t)row * HID + lane*8;
  float4 a = ld4bf(Qhi, Qlo, base);
  float4 b = ld4bf(Qhi, Qlo, base + 4);
  float4 wa = *(const float4*)&Wd[lane*8];
  float4 wb = *(const float4*)&Wd[lane*8 + 4];
  float p = a.x*wa.x + a.y*wa.y + a.z*wa.z + a.w*wa.w
          + b.x*wb.x + b.y*wb.y + b.z*wb.z + b.w*wb.w;
#pragma unroll
  for (int d = 32; d > 0; d >>= 1) p += __shfl_down(p, d);
  if (lane == 0) pred[row] = p + bd[0];
}

// ============================ host ============================

extern "C" void kernel_launch(void* const* d_in, const int* in_sizes, int n_in,
                              void* d_out, int out_size, void* d_ws, size_t ws_size,
                              hipStream_t stream)
{
  const float* x   = (const float*)d_in[0];
  const float* Km  = (const float*)d_in[1];
  const float* W1  = (const float*)d_in[2];
  const float* b1  = (const float*)d_in[3];
  const float* W2  = (const float*)d_in[4];
  const float* b2  = (const float*)d_in[5];
  const float* W3  = (const float*)d_in[6];
  const float* b3  = (const float*)d_in[7];
  const float* Wd  = (const float*)d_in[8];
  const float* bd  = (const float*)d_in[9];
  const int* train = (const int*)d_in[10];

  float* out  = (float*)d_out;
  float* pred = out;
  float* outN = out + 16384;
  float* outP = out + 16384 + 8388608;
  float* memo = out + 16384 + 2*8388608;

  char* ws = (char*)d_ws;
  unsigned short* Qhi   = (unsigned short*)(ws + 0);           // 16,777,216
  unsigned short* Qlo   = (unsigned short*)(ws + 16777216);    // 16,777,216
  unsigned short* xph   = (unsigned short*)(ws + 33554432);    // 12,582,912
  unsigned short* xpl   = (unsigned short*)(ws + 46137344);    // 12,582,912
  unsigned short* h1h   = (unsigned short*)(ws + 58720256);    // 16,777,216
  unsigned short* h1l   = (unsigned short*)(ws + 75497472);    // 16,777,216
  unsigned short* h2h   = (unsigned short*)(ws + 92274688);    // 16,777,216
  unsigned short* h2l   = (unsigned short*)(ws + 109051904);   // 16,777,216 (R0 end 125,829,120)
  unsigned short* Sb    = (unsigned short*)(ws + 33554432);    // 67,108,864 (aliases R0)
  unsigned short* Khi   = (unsigned short*)(ws + 125829120);   //  2,097,152
  unsigned short* Klo   = (unsigned short*)(ws + 127926272);   //  2,097,152
  unsigned short* Kt    = (unsigned short*)(ws + 130023424);   //  2,097,152
  unsigned short* W1ph  = (unsigned short*)(ws + 132120576);   //    393,216
  unsigned short* W1pl  = (unsigned short*)(ws + 132513792);   //    393,216
  unsigned short* W2h   = (unsigned short*)(ws + 132907008);   //    524,288
  unsigned short* W2l   = (unsigned short*)(ws + 133431296);   //    524,288
  unsigned short* W3h   = (unsigned short*)(ws + 133955584);   //    524,288
  unsigned short* W3l   = (unsigned short*)(ws + 134479872);   //    524,288
  float* pmax    = (float*)(ws + 135004160);                   //  2,097,152
  int*   pcol    = (int*)  (ws + 137101312);                   //  2,097,152
  float* psum    = (float*)(ws + 139198464);                   //  2,097,152
  float* pnmax   = (float*)(ws + 141295616);                   //  2,097,152
  float* pnsum   = (float*)(ws + 143392768);                   //  2,097,152
  float* pcolmax = (float*)(ws + 145489920);                   //  4,194,304 (512 rows)
  float* rowm    = (float*)(ws + 149684224);
  float* rsp     = (float*)(ws + 149749760);
  float* rmn     = (float*)(ws + 149815296);
  float* rsn     = (float*)(ws + 149880832);
  int*   gidx    = (int*)  (ws + 149946368);
  float* colmax  = (float*)(ws + 150011904);
  int*   cnt     = (int*)  (ws + 150020096);                   //      8,192
  int*   off     = (int*)  (ws + 150028288);                   //      8,448 (2049 ints)
  int*   woff    = (int*)  (ws + 150036736);                   //      8,192
  int*   rows    = (int*)  (ws + 150044928);                   //     65,536
  float* wv      = (float*)(ws + 150110464);                   //     65,536
  int*   sid     = (int*)  (ws + 150176000);                   //     65,536
  float* qacc    = (float*)(ws + 150241536);                   //  4,194,304
  const size_t NEED = 154435840ull;
  if (ws_size < NEED) return;  // harness provides >= 155 MB (proven round 2)

  dim3 blk(256);

  // fused conversions + Kt transpose + cnt/qacc zeroing (one launch)
  init_all<<<7880, blk, 0, stream>>>(x, W1, W2, W3, Km,
                                     xph, xpl, W1ph, W1pl, W2h, W2l, W3h, W3l,
                                     Khi, Klo, Kt, qacc, cnt);

  // MLP (split-bf16 MFMA, BM=128 16x16)
  mlp_gemm<<<dim3(N_ROWS/128, 4), dim3(512), 0, stream>>>(xph, xpl, W1ph, W1pl, b1, h1h, h1l, KP1);
  mlp_gemm<<<dim3(N_ROWS/128, 4), dim3(512), 0, stream>>>(h1h, h1l, W2h, W2l, b2, h2h, h2l, HID);
  mlp_gemm<<<dim3(N_ROWS/128, 4), dim3(512), 0, stream>>>(h2h, h2l, W3h, W3l, b3, Qhi, Qlo, HID);

  // attention stats + PV
  sgemm_stats<<<dim3(16, 128), dim3(512), 0, stream>>>(Qhi, Qlo, Khi, Klo, Sb,
                                                       pmax, pcol, psum, pnmax, pnsum, pcolmax);
  merge_all<<<72, blk, 0, stream>>>(pmax, pcol, psum, pnmax, pnsum, pcolmax,
                                    rowm, rsp, rmn, rsn, gidx, cnt, colmax);
  pv2<<<dim3(2, 256), dim3(512), 0, stream>>>(Sb, Kt, rowm, rsp, rmn, rsn, Qhi, Qlo, outP, outN);

  // upload via CSR + bounded scatter
  csr_scan<<<1, blk, 0, stream>>>(cnt, off, woff);
  csr_fill<<<N_ROWS/256, blk, 0, stream>>>(gidx, rowm, colmax, woff, rows, wv, sid);
  upload_scatter<<<N_ROWS/64, blk, 0, stream>>>(Qhi, Qlo, sid, rows, wv, train, qacc);
  upload_finish<<<M_SLOTS, blk, 0, stream>>>(qacc, Km, train, memo);

  // pred last (standalone, deterministic)
  pred_kernel<<<N_ROWS/4, blk, 0, stream>>>(Qhi, Qlo, Wd, bd, pred);
}

// Round 14
// 396.385 us; speedup vs baseline: 1.5915x; 1.1968x over previous
//
#include <hip/hip_runtime.h>
#include <math.h>

// Problem constants (fixed by the reference).
#define N_ROWS 16384
#define D_INN  360
#define KP1    384      // D_INN padded to multiple of 64
#define HID    512
#define M_SLOTS 2048

typedef __attribute__((ext_vector_type(8))) short short8v;
typedef __attribute__((ext_vector_type(4))) float f32x4;
typedef __attribute__((address_space(1))) unsigned int as1_uint;
typedef __attribute__((address_space(3))) unsigned int as3_uint;

// ---- bf16 helpers (manual, RNE) ----
__device__ __forceinline__ unsigned short bf16_rne(float f){
  unsigned u = __float_as_uint(f);
  unsigned r = u + 0x7FFFu + ((u >> 16) & 1u);
  return (unsigned short)(r >> 16);
}
__device__ __forceinline__ float bf16_to_f32(unsigned short h){
  return __uint_as_float(((unsigned)h) << 16);
}

// monotone float<->uint mapping for atomicMax on floats (proven r1 pattern)
__device__ __forceinline__ unsigned fmap(float f){
  unsigned u = __float_as_uint(f);
  return (u & 0x80000000u) ? ~u : (u | 0x80000000u);
}
__device__ __forceinline__ float funmap(unsigned u){
  unsigned b = (u & 0x80000000u) ? (u ^ 0x80000000u) : ~u;
  return __uint_as_float(b);
}

__device__ __forceinline__ void glds16(const void* g, void* l){
  __builtin_amdgcn_global_load_lds((const as1_uint*)g, (as3_uint*)l, 16, 0, 0);
}

// reconstruct 4 consecutive f32 from hi/lo bf16 pair arrays
__device__ __forceinline__ float4 ld4bf(const unsigned short* hi, const unsigned short* lo, size_t off){
  uint2 h = *(const uint2*)(hi + off);
  uint2 l = *(const uint2*)(lo + off);
  float4 r;
  r.x = bf16_to_f32((unsigned short)(h.x & 0xffffu)) + bf16_to_f32((unsigned short)(l.x & 0xffffu));
  r.y = bf16_to_f32((unsigned short)(h.x >> 16))     + bf16_to_f32((unsigned short)(l.x >> 16));
  r.z = bf16_to_f32((unsigned short)(h.y & 0xffffu)) + bf16_to_f32((unsigned short)(l.y & 0xffffu));
  r.w = bf16_to_f32((unsigned short)(h.y >> 16))     + bf16_to_f32((unsigned short)(l.y >> 16));
  return r;
}

// ============================ fused init kernel ============================
// Block ranges: [0,6144) cvt x | [6144,6336) cvt W1 | [6336,6464) W2 |
// [6464,6592) W3 | [6592,7104) Km | [7104,7360) kt | [7360,7872) qacc zero |
// [7872,7880) cnt + colmaxU zero.

__device__ __forceinline__ void split_body(const float* __restrict__ src,
                                           unsigned short* __restrict__ hi,
                                           unsigned short* __restrict__ lo, int b){
  int idx = (b*256 + (int)threadIdx.x) * 8;
  float4 a = *(const float4*)&src[idx];
  float4 bb = *(const float4*)&src[idx+4];
  float v[8] = {a.x,a.y,a.z,a.w,bb.x,bb.y,bb.z,bb.w};
  short8v hv, lv;
#pragma unroll
  for (int e=0;e<8;++e){
    unsigned short h = bf16_rne(v[e]);
    hv[e] = (short)h;
    lv[e] = (short)bf16_rne(v[e] - bf16_to_f32(h));
  }
  *(short8v*)&hi[idx] = hv;
  *(short8v*)&lo[idx] = lv;
}

__device__ __forceinline__ void pad_split_body(const float* __restrict__ src,
                                               unsigned short* __restrict__ hi,
                                               unsigned short* __restrict__ lo,
                                               int R, int Ksrc, int Kp, int b){
  long long e0 = ((long long)b*256 + threadIdx.x) * 4;
  if (e0 >= (long long)R*Kp) return;
  int row = (int)(e0 / Kp), c = (int)(e0 % Kp);
  unsigned short h4[4], l4[4];
  if (c < Ksrc){
    float4 v = *(const float4*)&src[(size_t)row*Ksrc + c];
    float vv[4] = {v.x, v.y, v.z, v.w};
#pragma unroll
    for (int e=0;e<4;++e){
      unsigned short h = bf16_rne(vv[e]);
      h4[e] = h;
      l4[e] = bf16_rne(vv[e] - bf16_to_f32(h));
    }
  } else {
#pragma unroll
    for (int e=0;e<4;++e){ h4[e]=0; l4[e]=0; }
  }
  *(uint2*)&hi[(size_t)row*Kp + c] = *(uint2*)h4;
  *(uint2*)&lo[(size_t)row*Kp + c] = *(uint2*)l4;
}

__global__ __launch_bounds__(256) void init_all(
    const float* __restrict__ x,  const float* __restrict__ W1,
    const float* __restrict__ W2, const float* __restrict__ W3,
    const float* __restrict__ Km,
    unsigned short* __restrict__ xph,  unsigned short* __restrict__ xpl,
    unsigned short* __restrict__ W1ph, unsigned short* __restrict__ W1pl,
    unsigned short* __restrict__ W2h,  unsigned short* __restrict__ W2l,
    unsigned short* __restrict__ W3h,  unsigned short* __restrict__ W3l,
    unsigned short* __restrict__ Khi,  unsigned short* __restrict__ Klo,
    unsigned short* __restrict__ Kt,
    float* __restrict__ qacc, int* __restrict__ cnt,
    unsigned* __restrict__ colmaxU)
{
  __shared__ float tile[64][65];  // used by the kt branch only
  int b = blockIdx.x;
  const int t = threadIdx.x;
  if (b < 6144){ pad_split_body(x, xph, xpl, N_ROWS, D_INN, KP1, b); return; }
  b -= 6144;
  if (b < 192){ pad_split_body(W1, W1ph, W1pl, HID, D_INN, KP1, b); return; }
  b -= 192;
  if (b < 128){ split_body(W2, W2h, W2l, b); return; }
  b -= 128;
  if (b < 128){ split_body(W3, W3h, W3l, b); return; }
  b -= 128;
  if (b < 512){ split_body(Km, Khi, Klo, b); return; }
  b -= 512;
  if (b < 256){
    const int sb = (b & 31) * 64;
    const int hb = (b >> 5) * 64;
    {
      int r = t >> 2, cq = t & 3;
#pragma unroll
      for (int q=0;q<4;++q){
        float4 v = *(const float4*)&Km[(size_t)(sb+r)*HID + hb + cq*16 + q*4];
        tile[r][cq*16+q*4+0]=v.x; tile[r][cq*16+q*4+1]=v.y;
        tile[r][cq*16+q*4+2]=v.z; tile[r][cq*16+q*4+3]=v.w;
      }
    }
    __syncthreads();
    {
      int hl = t >> 2, sq = t & 3;
      unsigned short w16[16];
#pragma unroll
      for (int q=0;q<16;++q) w16[q] = bf16_rne(tile[sq*16+q][hl]);
      *(uint4*)&Kt[(size_t)(hb+hl)*M_SLOTS + sb + sq*16]     = *(uint4*)&w16[0];
      *(uint4*)&Kt[(size_t)(hb+hl)*M_SLOTS + sb + sq*16 + 8] = *(uint4*)&w16[8];
    }
    return;
  }
  b -= 256;
  if (b < 512){
    int idx = (b*256 + t)*8;
    float4 z = {0.f,0.f,0.f,0.f};
    *(float4*)&qacc[idx]     = z;
    *(float4*)&qacc[idx + 4] = z;
    return;
  }
  b -= 512;
  { int i = b*256 + t; if (i < M_SLOTS){ cnt[i] = 0; colmaxU[i] = 0u; } }
}

// ============================ MLP GEMM (3-term split bf16, 16x16, BM=128, 512 thr) ============================
// Optional ppart (last layer): per-(row, colblock-half) f32 pred partials (plain stores).
__global__ __launch_bounds__(512) void mlp_gemm(
    const unsigned short* __restrict__ Ah_g, const unsigned short* __restrict__ Al_g,
    const unsigned short* __restrict__ Wh_g, const unsigned short* __restrict__ Wl_g,
    const float* __restrict__ bias,
    unsigned short* __restrict__ Ohi, unsigned short* __restrict__ Olo,
    int Kp, const float* __restrict__ Wd, float* __restrict__ ppart)
{
  __shared__ char smem[65536];
  unsigned short* Ah = (unsigned short*)smem;            // [128][64] hi
  unsigned short* Al = (unsigned short*)(smem + 16384);  // [128][64] lo
  unsigned short* Bh = (unsigned short*)(smem + 32768);  // [128][64] hi
  unsigned short* Bl = (unsigned short*)(smem + 49152);  // [128][64] lo
  const int t = threadIdx.x;
  const int lane = t & 63, w = t >> 6;            // 8 waves
  const int l15 = lane & 15, l4 = lane >> 4;
  const int rowBase = blockIdx.x * 128;
  const int colBase = blockIdx.y * 128;
  const int wr = (w >> 1) * 32;
  const int wc = (w & 1) * 64;

  f32x4 acc[2][4];
#pragma unroll
  for (int i=0;i<2;++i)
#pragma unroll
    for (int j=0;j<4;++j) acc[i][j] = (f32x4){0.f,0.f,0.f,0.f};

  const int nkt = Kp >> 6;
  for (int kt = 0; kt < nkt; ++kt){
    const int k0 = kt * 64;
#pragma unroll
    for (int p = 0; p < 2; ++p){
      int idx = p*512 + t;
      int r = idx >> 3, c = idx & 7;
      int cc = c ^ (r & 7);
      size_t go = (size_t)(rowBase + r) * Kp + (k0 + cc*8);
      glds16(Ah_g + go, (char*)Ah + idx*16);
      glds16(Al_g + go, (char*)Al + idx*16);
    }
#pragma unroll
    for (int p = 0; p < 2; ++p){
      int idx = p*512 + t;
      int r = idx >> 3, c = idx & 7;
      int cc = c ^ (r & 7);
      size_t go = (size_t)(colBase + r) * Kp + (k0 + cc*8);
      glds16(Wh_g + go, (char*)Bh + idx*16);
      glds16(Wl_g + go, (char*)Bl + idx*16);
    }
    __syncthreads();

#pragma unroll
    for (int s = 0; s < 2; ++s){
      short8v a_h[2], a_l[2], b_h[4], b_l[4];
#pragma unroll
      for (int rt = 0; rt < 2; ++rt){
        int r = wr + rt*16 + l15;
        int off = r*128 + ((s*4 + l4) ^ (r & 7))*16;
        a_h[rt] = *(const short8v*)((const char*)Ah + off);
        a_l[rt] = *(const short8v*)((const char*)Al + off);
      }
#pragma unroll
      for (int ct = 0; ct < 4; ++ct){
        int r = wc + ct*16 + l15;
        int off = r*128 + ((s*4 + l4) ^ (r & 7))*16;
        b_h[ct] = *(const short8v*)((const char*)Bh + off);
        b_l[ct] = *(const short8v*)((const char*)Bl + off);
      }
#pragma unroll
      for (int rt = 0; rt < 2; ++rt)
#pragma unroll
        for (int ct = 0; ct < 4; ++ct){
          acc[rt][ct] = __builtin_amdgcn_mfma_f32_16x16x32_bf16(a_h[rt], b_h[ct], acc[rt][ct], 0,0,0);
          acc[rt][ct] = __builtin_amdgcn_mfma_f32_16x16x32_bf16(a_h[rt], b_l[ct], acc[rt][ct], 0,0,0);
          acc[rt][ct] = __builtin_amdgcn_mfma_f32_16x16x32_bf16(a_l[rt], b_h[ct], acc[rt][ct], 0,0,0);
        }
    }
    __syncthreads();
  }

  // epilogue: bias + relu, split hi/lo, stage through LDS for coalesced writes
  float bcol[4];
#pragma unroll
  for (int ct=0; ct<4; ++ct) bcol[ct] = bias[colBase + wc + ct*16 + l15];
  unsigned short* Sout = (unsigned short*)smem;  // [128][136] = 34816 B
#pragma unroll
  for (int rt=0; rt<2; ++rt)
#pragma unroll
    for (int ct=0; ct<4; ++ct)
#pragma unroll
      for (int reg=0; reg<4; ++reg){
        float v = acc[rt][ct][reg] + bcol[ct];
        v = v > 0.f ? v : 0.f;
        acc[rt][ct][reg] = v;
        Sout[(wr + rt*16 + l4*4 + reg)*136 + wc + ct*16 + l15] = bf16_rne(v);
      }

  // pred partials (last layer only): per-row dot over this block's 64-col half.
  if (ppart){
    float wdv[4];
#pragma unroll
    for (int ct=0; ct<4; ++ct) wdv[ct] = Wd[colBase + wc + ct*16 + l15];
#pragma unroll
    for (int rt=0; rt<2; ++rt)
#pragma unroll
      for (int reg=0; reg<4; ++reg){
        float pd = acc[rt][0][reg]*wdv[0] + acc[rt][1][reg]*wdv[1]
                 + acc[rt][2][reg]*wdv[2] + acc[rt][3][reg]*wdv[3];
#pragma unroll
        for (int d=1; d<16; d<<=1) pd += __shfl_xor(pd, d);
        if (l15 == 0){
          int row = rowBase + wr + rt*16 + l4*4 + reg;
          ppart[(size_t)row*8 + (colBase >> 7)*2 + (wc >> 6)] = pd;
        }
      }
  }

  __syncthreads();
#pragma unroll
  for (int p = 0; p < 4; ++p){
    int row = (t >> 4) + p*32;
    int c8 = (t & 15) * 8;
    uint4 v = *(uint4*)&Sout[row*136 + c8];
    *(uint4*)&Ohi[(size_t)(rowBase+row)*HID + colBase + c8] = v;
  }
  __syncthreads();
#pragma unroll
  for (int rt=0; rt<2; ++rt)
#pragma unroll
    for (int ct=0; ct<4; ++ct)
#pragma unroll
      for (int reg=0; reg<4; ++reg){
        float v = acc[rt][ct][reg];
        unsigned short h = bf16_rne(v);
        Sout[(wr + rt*16 + l4*4 + reg)*136 + wc + ct*16 + l15] = bf16_rne(v - bf16_to_f32(h));
      }
  __syncthreads();
#pragma unroll
  for (int p = 0; p < 4; ++p){
    int row = (t >> 4) + p*32;
    int c8 = (t & 15) * 8;
    uint4 v = *(uint4*)&Sout[row*136 + c8];
    *(uint4*)&Olo[(size_t)(rowBase+row)*HID + colBase + c8] = v;
  }
}

// ============================ S GEMM + stats (16x16, BM=128 x BN=128, 512 thr) ============================
// Column maxima go directly to colmaxU via mapped-uint atomicMax (bit-identical to merge).
__global__ __launch_bounds__(512) void sgemm_stats(
    const unsigned short* __restrict__ Qhi, const unsigned short* __restrict__ Qlo,
    const unsigned short* __restrict__ Khi, const unsigned short* __restrict__ Klo,
    unsigned short* __restrict__ Sb,
    float* __restrict__ pmax, int* __restrict__ pcol,
    float* __restrict__ psum, float* __restrict__ pnmax, float* __restrict__ pnsum,
    unsigned* __restrict__ colmaxU)
{
  __shared__ char smem[65536];
  unsigned short* Ah = (unsigned short*)smem;            // [128][64] hi
  unsigned short* Al = (unsigned short*)(smem + 16384);  // [128][64] lo
  unsigned short* Bh = (unsigned short*)(smem + 32768);  // [128][64] hi
  unsigned short* Bl = (unsigned short*)(smem + 49152);  // [128][64] lo
  const int t = threadIdx.x;
  const int lane = t & 63, w = t >> 6;            // 8 waves
  const int l15 = lane & 15, l4 = lane >> 4;
  const int cb = blockIdx.x;      // 0..15  col block
  const int rb = blockIdx.y;      // 0..127 row block
  const int rowBase = rb * 128;
  const int colBase = cb * 128;
  const int wr = (w >> 1) * 32;   // row quarter (0,32,64,96)
  const int wc = (w & 1) * 64;    // col half

  f32x4 acc[2][4];
#pragma unroll
  for (int i=0;i<2;++i)
#pragma unroll
    for (int j=0;j<4;++j) acc[i][j] = (f32x4){0.f,0.f,0.f,0.f};

  for (int kt = 0; kt < 8; ++kt){
    const int k0 = kt * 64;
#pragma unroll
    for (int p = 0; p < 2; ++p){
      int idx = p*512 + t;
      int r = idx >> 3, c = idx & 7;
      int cc = c ^ (r & 7);
      size_t go = (size_t)(rowBase + r) * HID + (k0 + cc*8);
      glds16(Qhi + go, (char*)Ah + idx*16);
      glds16(Qlo + go, (char*)Al + idx*16);
    }
#pragma unroll
    for (int p = 0; p < 2; ++p){
      int idx = p*512 + t;
      int r = idx >> 3, c = idx & 7;
      int cc = c ^ (r & 7);
      size_t go = (size_t)(colBase + r) * HID + (k0 + cc*8);
      glds16(Khi + go, (char*)Bh + idx*16);
      glds16(Klo + go, (char*)Bl + idx*16);
    }
    __syncthreads();

#pragma unroll
    for (int s = 0; s < 2; ++s){
      short8v a_h[2], a_l[2], b_h[4], b_l[4];
#pragma unroll
      for (int rt = 0; rt < 2; ++rt){
        int r = wr + rt*16 + l15;
        int off = r*128 + ((s*4 + l4) ^ (r & 7))*16;
        a_h[rt] = *(const short8v*)((const char*)Ah + off);
        a_l[rt] = *(const short8v*)((const char*)Al + off);
      }
#pragma unroll
      for (int ct = 0; ct < 4; ++ct){
        int r = wc + ct*16 + l15;
        int off = r*128 + ((s*4 + l4) ^ (r & 7))*16;
        b_h[ct] = *(const short8v*)((const char*)Bh + off);
        b_l[ct] = *(const short8v*)((const char*)Bl + off);
      }
#pragma unroll
      for (int rt = 0; rt < 2; ++rt)
#pragma unroll
        for (int ct = 0; ct < 4; ++ct){
          acc[rt][ct] = __builtin_amdgcn_mfma_f32_16x16x32_bf16(a_h[rt], b_h[ct], acc[rt][ct], 0,0,0);
          acc[rt][ct] = __builtin_amdgcn_mfma_f32_16x16x32_bf16(a_h[rt], b_l[ct], acc[rt][ct], 0,0,0);
          acc[rt][ct] = __builtin_amdgcn_mfma_f32_16x16x32_bf16(a_l[rt], b_h[ct], acc[rt][ct], 0,0,0);
        }
    }
    __syncthreads();
  }

  // ---- row stats (per wave over its 64-col half) ----
#pragma unroll
  for (int rt = 0; rt < 2; ++rt){
#pragma unroll
    for (int reg = 0; reg < 4; ++reg){
      float v0 = acc[rt][0][reg], v1 = acc[rt][1][reg];
      float v2 = acc[rt][2][reg], v3 = acc[rt][3][reg];
      float bvv = v0; int bcc = colBase + wc + l15;
      if (v1 > bvv){ bvv = v1; bcc = colBase + wc + 16 + l15; }
      if (v2 > bvv){ bvv = v2; bcc = colBase + wc + 32 + l15; }
      if (v3 > bvv){ bvv = v3; bcc = colBase + wc + 48 + l15; }
      float mnv = fminf(fminf(v0,v1), fminf(v2,v3));
#pragma unroll
      for (int d = 1; d < 16; d <<= 1){
        float ov = __shfl_xor(bvv, d);
        int   oc = __shfl_xor(bcc, d);
        float om = __shfl_xor(mnv, d);
        if (ov > bvv || (ov == bvv && oc < bcc)){ bvv = ov; bcc = oc; }
        mnv = fminf(mnv, om);
      }
      float sp = __expf(v0-bvv)+__expf(v1-bvv)+__expf(v2-bvv)+__expf(v3-bvv);
      float sn = __expf(mnv-v0)+__expf(mnv-v1)+__expf(mnv-v2)+__expf(mnv-v3);
#pragma unroll
      for (int d = 1; d < 16; d <<= 1){ sp += __shfl_xor(sp,d); sn += __shfl_xor(sn,d); }
      if (l15 == 0){
        int row = rowBase + wr + rt*16 + l4*4 + reg;
        size_t pi = (size_t)row*32 + cb*2 + (w & 1);
        pmax[pi] = bvv; pcol[pi] = bcc; psum[pi] = sp;
        pnmax[pi] = -mnv; pnsum[pi] = sn;
      }
    }
  }

  // ---- per-column max -> device-wide atomicMax (mapped uint) ----
#pragma unroll
  for (int ct = 0; ct < 4; ++ct){
    float cm = -1e30f;
#pragma unroll
    for (int rt=0; rt<2; ++rt)
#pragma unroll
      for (int reg=0; reg<4; ++reg) cm = fmaxf(cm, acc[rt][ct][reg]);
    cm = fmaxf(cm, __shfl_xor(cm, 16));
    cm = fmaxf(cm, __shfl_xor(cm, 32));
    if (l4 == 0)
      atomicMax(&colmaxU[colBase + wc + ct*16 + l15], fmap(cm));
  }

  // ---- S bf16 write (staged through LDS for coalescing) ----
  __syncthreads();
  unsigned short* Sout = (unsigned short*)smem;  // [128][136] = 34816 B
#pragma unroll
  for (int rt=0; rt<2; ++rt)
#pragma unroll
    for (int ct=0; ct<4; ++ct)
#pragma unroll
      for (int reg=0; reg<4; ++reg)
        Sout[(wr + rt*16 + l4*4 + reg)*136 + wc + ct*16 + l15] = bf16_rne(acc[rt][ct][reg]);
  __syncthreads();
#pragma unroll
  for (int p = 0; p < 4; ++p){
    int row = (t >> 4) + p*32;
    int c8 = (t & 15) * 8;
    uint4 v = *(uint4*)&Sout[row*136 + c8];
    *(uint4*)&Sb[(size_t)(rowBase+row)*M_SLOTS + colBase + c8] = v;
  }
}

// merge rows (64 blocks): row stats + fused csr count + pred assembly from partials
__global__ __launch_bounds__(256) void merge_all(
    const float* __restrict__ pmax, const int* __restrict__ pcol,
    const float* __restrict__ psum, const float* __restrict__ pnmax,
    const float* __restrict__ pnsum,
    float* __restrict__ rowm, float* __restrict__ rsp,
    float* __restrict__ rmn, float* __restrict__ rsn, int* __restrict__ gidx,
    int* __restrict__ cnt,
    const float* __restrict__ ppart, const float* __restrict__ bd,
    float* __restrict__ pred)
{
  int row = blockIdx.x*256 + threadIdx.x;
  const size_t base = (size_t)row*32;
  float m = -1e30f; int g = 0;
  for (int i=0;i<32;++i){
    float v = pmax[base+i];
    if (v > m){ m = v; g = pcol[base+i]; }
  }
  float s = 0.f;
  for (int i=0;i<32;++i) s += psum[base+i] * __expf(pmax[base+i]-m);
  float mn = -1e30f;
  for (int i=0;i<32;++i) mn = fmaxf(mn, pnmax[base+i]);
  float sn = 0.f;
  for (int i=0;i<32;++i) sn += pnsum[base+i] * __expf(pnmax[base+i]-mn);
  rowm[row]=m; gidx[row]=g; rsp[row]=1.f/s; rmn[row]=mn; rsn[row]=1.f/sn;
  atomicAdd(&cnt[g], 1);
  float pd = bd[0];
#pragma unroll
  for (int i=0;i<8;++i) pd += ppart[(size_t)row*8 + i];
  pred[row] = pd;
}

// ============================ PV (S read once, 16x16, 64 rows, 512 thr) ============================
#define PV_RB 64
#define PV_HB 256
__global__ __launch_bounds__(512) void pv2(
    const unsigned short* __restrict__ Sb, const unsigned short* __restrict__ Kt,
    const float* __restrict__ rowm, const float* __restrict__ rsp,
    const float* __restrict__ rmn, const float* __restrict__ rsn,
    const unsigned short* __restrict__ Qhi, const unsigned short* __restrict__ Qlo,
    float* __restrict__ outP, float* __restrict__ outN)
{
  __shared__ char smem[49152];
  unsigned short* Ktile = (unsigned short*)smem;          // [256 h][64 slots], chunk-swizzled, 32KB
  unsigned short* Wp = (unsigned short*)(smem + 32768);   // [64 rows][8 octets] 16B chunks, 8KB
  unsigned short* Wn = (unsigned short*)(smem + 40960);   // 8KB
  const int t = threadIdx.x, lane = t & 63, w = t >> 6;
  const int l15 = lane & 15, l4 = lane >> 4;
  const int rowBase = blockIdx.y * PV_RB;
  const int hBase = blockIdx.x * PV_HB;
  const int wrq = (w >> 2) * 32;       // wave row half (0 or 32)
  const int hw = (w & 3) * 64;         // wave col group
  const int rS = t >> 3;               // 0..63: row for weight computation
  const int c8 = t & 7;                // slot-octet
  const float mp = rowm[rowBase + rS], mn = rmn[rowBase + rS];

  f32x4 accP[2][4], accN[2][4];
#pragma unroll
  for (int i=0;i<2;++i)
#pragma unroll
    for (int j=0;j<4;++j){ accP[i][j]=(f32x4){0.f,0.f,0.f,0.f}; accN[i][j]=(f32x4){0.f,0.f,0.f,0.f}; }

  for (int kt = 0; kt < 32; ++kt){
    const int k0 = kt*64;
#pragma unroll
    for (int p=0;p<4;++p){
      int idx = p*512 + t;
      int r = idx >> 3, c = idx & 7;
      int cc = c ^ (r & 7);
      glds16(Kt + (size_t)(hBase + r)*M_SLOTS + k0 + cc*8, (char*)Ktile + idx*16);
    }
    short8v sv = *(const short8v*)&Sb[(size_t)(rowBase + rS)*M_SLOTS + k0 + c8*8];
    short8v wp, wn;
#pragma unroll
    for (int e=0;e<8;++e){
      float sval = bf16_to_f32((unsigned short)sv[e]);
      wp[e] = (short)bf16_rne(__expf(sval - mp));
      wn[e] = (short)bf16_rne(__expf(-sval - mn));
    }
    {
      int ch = rS*8 + (c8 ^ (rS & 7));
      *(short8v*)(Wp + ch*8) = wp;
      *(short8v*)(Wn + ch*8) = wn;
    }
    __syncthreads();
#pragma unroll
    for (int s=0; s<2; ++s){
      short8v ap[2], an[2], b[4];
#pragma unroll
      for (int rt=0; rt<2; ++rt){
        int r = wrq + rt*16 + l15;
        int ch = r*8 + ((s*4 + l4) ^ (r & 7));
        ap[rt] = *(const short8v*)(Wp + ch*8);
        an[rt] = *(const short8v*)(Wn + ch*8);
      }
#pragma unroll
      for (int ct=0; ct<4; ++ct){
        int hr = hw + ct*16 + l15;
        b[ct] = *(const short8v*)((const char*)Ktile + hr*128 + ((s*4 + l4) ^ (hr & 7))*16);
      }
#pragma unroll
      for (int rt=0; rt<2; ++rt)
#pragma unroll
        for (int ct=0; ct<4; ++ct){
          accP[rt][ct] = __builtin_amdgcn_mfma_f32_16x16x32_bf16(ap[rt], b[ct], accP[rt][ct], 0,0,0);
          accN[rt][ct] = __builtin_amdgcn_mfma_f32_16x16x32_bf16(an[rt], b[ct], accN[rt][ct], 0,0,0);
        }
    }
    __syncthreads();
  }

  // epilogue: scale, gate by Q (hi+lo), staged 32-row phases through reused LDS
  float isp[2][4], isn[2][4];
#pragma unroll
  for (int rt=0; rt<2; ++rt)
#pragma unroll
    for (int reg=0; reg<4; ++reg){
      int row = rowBase + wrq + rt*16 + l4*4 + reg;
      isp[rt][reg] = rsp[row];
      isn[rt][reg] = rsn[row];
    }
  float* Pout = (float*)smem;   // [32][260] = 33280 B
#pragma unroll
  for (int sign=0; sign<2; ++sign){
#pragma unroll
    for (int rh=0; rh<2; ++rh){
      if ((w >> 2) == rh){
#pragma unroll
        for (int rt=0; rt<2; ++rt)
#pragma unroll
          for (int ct=0; ct<4; ++ct)
#pragma unroll
            for (int reg=0; reg<4; ++reg){
              float v = sign ? accN[rt][ct][reg]*isn[rt][reg]
                             : accP[rt][ct][reg]*isp[rt][reg];
              Pout[(rt*16 + l4*4 + reg)*260 + hw + ct*16 + l15] = v;
            }
      }
      __syncthreads();
      float* outX = sign ? outN : outP;
#pragma unroll
      for (int p=0; p<4; ++p){
        int row = t >> 4;                 // 0..31
        int col = (t & 15)*4 + p*64;      // 0..252
        int grow = rowBase + rh*32 + row;
        float4 pv = *(float4*)&Pout[row*260 + col];
        float4 qv = ld4bf(Qhi, Qlo, (size_t)grow*HID + hBase + col);
        float4 o; o.x=pv.x*qv.x; o.y=pv.y*qv.y; o.z=pv.z*qv.z; o.w=pv.w*qv.w;
        *(float4*)&outX[(size_t)grow*HID + hBase + col] = o;
      }
      __syncthreads();
    }
  }
}

// ============================ CSR upload (skew-independent) ============================

__global__ __launch_bounds__(256) void csr_scan(const int* __restrict__ cnt,
                                                int* __restrict__ off, int* __restrict__ woff){
  __shared__ int partial[256];
  const int t = threadIdx.x;
  const int base = t*8;
  int local[8]; int s = 0;
#pragma unroll
  for (int j=0;j<8;++j){ local[j] = s; s += cnt[base+j]; }
  partial[t] = s;
  __syncthreads();
  for (int d=1; d<256; d<<=1){
    int v = (t>=d) ? partial[t-d] : 0;
    __syncthreads();
    partial[t] += v;
    __syncthreads();
  }
  int pre = (t==0) ? 0 : partial[t-1];
#pragma unroll
  for (int j=0;j<8;++j){ int o = pre + local[j]; off[base+j]=o; woff[base+j]=o; }
  if (t==255) off[2048] = partial[255];
}

__global__ __launch_bounds__(256) void csr_fill(const int* __restrict__ gidx,
                                                const float* __restrict__ rowm,
                                                const unsigned* __restrict__ colmaxU,
                                                int* __restrict__ woff,
                                                int* __restrict__ rows, float* __restrict__ wv,
                                                int* __restrict__ sid){
  int i = blockIdx.x*256 + threadIdx.x;
  int g = gidx[i];
  int p = atomicAdd(&woff[g], 1);
  rows[p] = i;
  wv[p] = __expf(rowm[i] - funmap(colmaxU[g]));
  sid[p] = g;
}

__global__ __launch_bounds__(256) void upload_scatter(
    const unsigned short* __restrict__ Qhi, const unsigned short* __restrict__ Qlo,
    const int* __restrict__ sid, const int* __restrict__ rows, const float* __restrict__ wv,
    const int* __restrict__ train, float* __restrict__ qacc)
{
  if (*train == 0) return;
  const int b = blockIdx.x, t = threadIdx.x;
  __shared__ int   s_sid[64];
  __shared__ int   s_row[64];
  __shared__ float s_w[64];
  if (t < 64){
    int p = b*64 + t;
    s_sid[t] = sid[p];
    s_row[t] = rows[p];
    s_w[t]   = wv[p];
  }
  __syncthreads();
  const int h0 = t*2;
  float a0 = 0.f, a1 = 0.f;
  int prev = s_sid[0];
#pragma unroll 4
  for (int p = 0; p < 64; ++p){
    int s = s_sid[p];
    if (s != prev){
      atomicAdd(&qacc[(size_t)prev*HID + h0],     a0);
      atomicAdd(&qacc[(size_t)prev*HID + h0 + 1], a1);
      a0 = 0.f; a1 = 0.f; prev = s;
    }
    int row = s_row[p];
    float w = s_w[p];
    unsigned h = *(const unsigned*)(Qhi + (size_t)row*HID + h0);
    unsigned l = *(const unsigned*)(Qlo + (size_t)row*HID + h0);
    a0 += w * (bf16_to_f32((unsigned short)(h & 0xffffu)) + bf16_to_f32((unsigned short)(l & 0xffffu)));
    a1 += w * (bf16_to_f32((unsigned short)(h >> 16))     + bf16_to_f32((unsigned short)(l >> 16)));
  }
  atomicAdd(&qacc[(size_t)prev*HID + h0],     a0);
  atomicAdd(&qacc[(size_t)prev*HID + h0 + 1], a1);
}

__global__ __launch_bounds__(256) void upload_finish(const float* __restrict__ qacc,
                                                     const float* __restrict__ Km,
                                                     const int* __restrict__ train,
                                                     float* __restrict__ mem)
{
  const int m = blockIdx.x, t = threadIdx.x;
  const int h0 = t * 2;
  float2 kv = *(const float2*)&Km[(size_t)m*HID + h0];
  if (*train == 0){
    mem[(size_t)m*HID + h0]     = kv.x;
    mem[(size_t)m*HID + h0 + 1] = kv.y;
    return;
  }
  float2 av = *(const float2*)&qacc[(size_t)m*HID + h0];
  float v0 = av.x + kv.x, v1 = av.y + kv.y;
  __shared__ float red[256];
  red[t] = v0*v0 + v1*v1;
  __syncthreads();
  for (int s = 128; s > 0; s >>= 1){
    if (t < s) red[t] += red[t + s];
    __syncthreads();
  }
  float rinv = 1.f / fmaxf(sqrtf(red[0]), 1e-12f);
  mem[(size_t)m*HID + h0]     = v0 * rinv;
  mem[(size_t)m*HID + h0 + 1] = v1 * rinv;
}

// ============================ host ============================

extern "C" void kernel_launch(void* const* d_in, const int* in_sizes, int n_in,
                              void* d_out, int out_size, void* d_ws, size_t ws_size,
                              hipStream_t stream)
{
  const float* x   = (const float*)d_in[0];
  const float* Km  = (const float*)d_in[1];
  const float* W1  = (const float*)d_in[2];
  const float* b1  = (const float*)d_in[3];
  const float* W2  = (const float*)d_in[4];
  const float* b2  = (const float*)d_in[5];
  const float* W3  = (const float*)d_in[6];
  const float* b3  = (const float*)d_in[7];
  const float* Wd  = (const float*)d_in[8];
  const float* bd  = (const float*)d_in[9];
  const int* train = (const int*)d_in[10];

  float* out  = (float*)d_out;
  float* pred = out;
  float* outN = out + 16384;
  float* outP = out + 16384 + 8388608;
  float* memo = out + 16384 + 2*8388608;

  char* ws = (char*)d_ws;
  unsigned short* Qhi   = (unsigned short*)(ws + 0);           // 16,777,216
  unsigned short* Qlo   = (unsigned short*)(ws + 16777216);    // 16,777,216
  unsigned short* xph   = (unsigned short*)(ws + 33554432);    // 12,582,912
  unsigned short* xpl   = (unsigned short*)(ws + 46137344);    // 12,582,912
  unsigned short* h1h   = (unsigned short*)(ws + 58720256);    // 16,777,216
  unsigned short* h1l   = (unsigned short*)(ws + 75497472);    // 16,777,216
  unsigned short* h2h   = (unsigned short*)(ws + 92274688);    // 16,777,216
  unsigned short* h2l   = (unsigned short*)(ws + 109051904);   // 16,777,216 (R0 end 125,829,120)
  unsigned short* Sb    = (unsigned short*)(ws + 33554432);    // 67,108,864 (aliases R0)
  unsigned short* Khi   = (unsigned short*)(ws + 125829120);   //  2,097,152
  unsigned short* Klo   = (unsigned short*)(ws + 127926272);   //  2,097,152
  unsigned short* Kt    = (unsigned short*)(ws + 130023424);   //  2,097,152
  unsigned short* W1ph  = (unsigned short*)(ws + 132120576);   //    393,216
  unsigned short* W1pl  = (unsigned short*)(ws + 132513792);   //    393,216
  unsigned short* W2h   = (unsigned short*)(ws + 132907008);   //    524,288
  unsigned short* W2l   = (unsigned short*)(ws + 133431296);   //    524,288
  unsigned short* W3h   = (unsigned short*)(ws + 133955584);   //    524,288
  unsigned short* W3l   = (unsigned short*)(ws + 134479872);   //    524,288
  float* pmax    = (float*)(ws + 135004160);                   //  2,097,152
  int*   pcol    = (int*)  (ws + 137101312);                   //  2,097,152
  float* psum    = (float*)(ws + 139198464);                   //  2,097,152
  float* pnmax   = (float*)(ws + 141295616);                   //  2,097,152
  float* pnsum   = (float*)(ws + 143392768);                   //  2,097,152
  // (ws + 145489920) 4 MB: unused (was pcolmax)
  float* rowm    = (float*)(ws + 149684224);
  float* rsp     = (float*)(ws + 149749760);
  float* rmn     = (float*)(ws + 149815296);
  float* rsn     = (float*)(ws + 149880832);
  int*   gidx    = (int*)  (ws + 149946368);
  unsigned* colmaxU = (unsigned*)(ws + 150011904);             //      8,192
  int*   cnt     = (int*)  (ws + 150020096);                   //      8,192
  int*   off     = (int*)  (ws + 150028288);                   //      8,448 (2049 ints)
  int*   woff    = (int*)  (ws + 150036736);                   //      8,192
  int*   rows    = (int*)  (ws + 150044928);                   //     65,536
  float* wv      = (float*)(ws + 150110464);                   //     65,536
  int*   sid     = (int*)  (ws + 150176000);                   //     65,536
  float* qacc    = (float*)(ws + 150241536);                   //  4,194,304
  float* ppart   = (float*)(ws + 154435840);                   //    524,288 (16384 x 8)
  const size_t NEED = 154960128ull;
  if (ws_size < NEED) return;  // harness provides >= 155.5 MB (proven round 2)

  dim3 blk(256);

  // fused conversions + Kt transpose + cnt/colmaxU/qacc zeroing (one launch)
  init_all<<<7880, blk, 0, stream>>>(x, W1, W2, W3, Km,
                                     xph, xpl, W1ph, W1pl, W2h, W2l, W3h, W3l,
                                     Khi, Klo, Kt, qacc, cnt, colmaxU);

  // MLP (split-bf16 MFMA, BM=128 16x16); layer 3 writes pred partials (plain stores)
  mlp_gemm<<<dim3(N_ROWS/128, 4), dim3(512), 0, stream>>>(xph, xpl, W1ph, W1pl, b1, h1h, h1l, KP1,
                                                          (const float*)nullptr, (float*)nullptr);
  mlp_gemm<<<dim3(N_ROWS/128, 4), dim3(512), 0, stream>>>(h1h, h1l, W2h, W2l, b2, h2h, h2l, HID,
                                                          (const float*)nullptr, (float*)nullptr);
  mlp_gemm<<<dim3(N_ROWS/128, 4), dim3(512), 0, stream>>>(h2h, h2l, W3h, W3l, b3, Qhi, Qlo, HID,
                                                          Wd, ppart);

  // attention stats + PV
  sgemm_stats<<<dim3(16, 128), dim3(512), 0, stream>>>(Qhi, Qlo, Khi, Klo, Sb,
                                                       pmax, pcol, psum, pnmax, pnsum, colmaxU);
  merge_all<<<64, blk, 0, stream>>>(pmax, pcol, psum, pnmax, pnsum,
                                    rowm, rsp, rmn, rsn, gidx, cnt, ppart, bd, pred);
  pv2<<<dim3(2, 256), dim3(512), 0, stream>>>(Sb, Kt, rowm, rsp, rmn, rsn, Qhi, Qlo, outP, outN);

  // upload via CSR + bounded scatter
  csr_scan<<<1, blk, 0, stream>>>(cnt, off, woff);
  csr_fill<<<N_ROWS/256, blk, 0, stream>>>(gidx, rowm, colmaxU, woff, rows, wv, sid);
  upload_scatter<<<N_ROWS/64, blk, 0, stream>>>(Qhi, Qlo, sid, rows, wv, train, qacc);
  upload_finish<<<M_SLOTS, blk, 0, stream>>>(qacc, Km, train, memo);
}

// Round 15
// 386.377 us; speedup vs baseline: 1.6327x; 1.0259x over previous
//
#include <hip/hip_runtime.h>
#include <math.h>

// Problem constants (fixed by the reference).
#define N_ROWS 16384
#define D_INN  360
#define KP1    384      // D_INN padded to multiple of 64
#define HID    512
#define M_SLOTS 2048

typedef __attribute__((ext_vector_type(8))) short short8v;
typedef __attribute__((ext_vector_type(4))) float f32x4;
typedef __attribute__((address_space(1))) unsigned int as1_uint;
typedef __attribute__((address_space(3))) unsigned int as3_uint;

// ---- bf16 helpers (manual, RNE) ----
__device__ __forceinline__ unsigned short bf16_rne(float f){
  unsigned u = __float_as_uint(f);
  unsigned r = u + 0x7FFFu + ((u >> 16) & 1u);
  return (unsigned short)(r >> 16);
}
__device__ __forceinline__ float bf16_to_f32(unsigned short h){
  return __uint_as_float(((unsigned)h) << 16);
}

// monotone float<->uint mapping for atomicMax on floats (proven r1 pattern)
__device__ __forceinline__ unsigned fmap(float f){
  unsigned u = __float_as_uint(f);
  return (u & 0x80000000u) ? ~u : (u | 0x80000000u);
}
__device__ __forceinline__ float funmap(unsigned u){
  unsigned b = (u & 0x80000000u) ? (u ^ 0x80000000u) : ~u;
  return __uint_as_float(b);
}

__device__ __forceinline__ void glds16(const void* g, void* l){
  __builtin_amdgcn_global_load_lds((const as1_uint*)g, (as3_uint*)l, 16, 0, 0);
}

// reconstruct 4 consecutive f32 from hi/lo bf16 pair arrays
__device__ __forceinline__ float4 ld4bf(const unsigned short* hi, const unsigned short* lo, size_t off){
  uint2 h = *(const uint2*)(hi + off);
  uint2 l = *(const uint2*)(lo + off);
  float4 r;
  r.x = bf16_to_f32((unsigned short)(h.x & 0xffffu)) + bf16_to_f32((unsigned short)(l.x & 0xffffu));
  r.y = bf16_to_f32((unsigned short)(h.x >> 16))     + bf16_to_f32((unsigned short)(l.x >> 16));
  r.z = bf16_to_f32((unsigned short)(h.y & 0xffffu)) + bf16_to_f32((unsigned short)(l.y & 0xffffu));
  r.w = bf16_to_f32((unsigned short)(h.y >> 16))     + bf16_to_f32((unsigned short)(l.y >> 16));
  return r;
}

// ============================ fused init kernel ============================
// Block ranges: [0,6144) cvt x | [6144,6336) cvt W1 | [6336,6464) W2 |
// [6464,6592) W3 | [6592,7104) Km | [7104,7360) kt | [7360,7872) qacc zero |
// [7872,7880) cnt + colmaxU + woff zero.

__device__ __forceinline__ void split_body(const float* __restrict__ src,
                                           unsigned short* __restrict__ hi,
                                           unsigned short* __restrict__ lo, int b){
  int idx = (b*256 + (int)threadIdx.x) * 8;
  float4 a = *(const float4*)&src[idx];
  float4 bb = *(const float4*)&src[idx+4];
  float v[8] = {a.x,a.y,a.z,a.w,bb.x,bb.y,bb.z,bb.w};
  short8v hv, lv;
#pragma unroll
  for (int e=0;e<8;++e){
    unsigned short h = bf16_rne(v[e]);
    hv[e] = (short)h;
    lv[e] = (short)bf16_rne(v[e] - bf16_to_f32(h));
  }
  *(short8v*)&hi[idx] = hv;
  *(short8v*)&lo[idx] = lv;
}

__device__ __forceinline__ void pad_split_body(const float* __restrict__ src,
                                               unsigned short* __restrict__ hi,
                                               unsigned short* __restrict__ lo,
                                               int R, int Ksrc, int Kp, int b){
  long long e0 = ((long long)b*256 + threadIdx.x) * 4;
  if (e0 >= (long long)R*Kp) return;
  int row = (int)(e0 / Kp), c = (int)(e0 % Kp);
  unsigned short h4[4], l4[4];
  if (c < Ksrc){
    float4 v = *(const float4*)&src[(size_t)row*Ksrc + c];
    float vv[4] = {v.x, v.y, v.z, v.w};
#pragma unroll
    for (int e=0;e<4;++e){
      unsigned short h = bf16_rne(vv[e]);
      h4[e] = h;
      l4[e] = bf16_rne(vv[e] - bf16_to_f32(h));
    }
  } else {
#pragma unroll
    for (int e=0;e<4;++e){ h4[e]=0; l4[e]=0; }
  }
  *(uint2*)&hi[(size_t)row*Kp + c] = *(uint2*)h4;
  *(uint2*)&lo[(size_t)row*Kp + c] = *(uint2*)l4;
}

__global__ __launch_bounds__(256) void init_all(
    const float* __restrict__ x,  const float* __restrict__ W1,
    const float* __restrict__ W2, const float* __restrict__ W3,
    const float* __restrict__ Km,
    unsigned short* __restrict__ xph,  unsigned short* __restrict__ xpl,
    unsigned short* __restrict__ W1ph, unsigned short* __restrict__ W1pl,
    unsigned short* __restrict__ W2h,  unsigned short* __restrict__ W2l,
    unsigned short* __restrict__ W3h,  unsigned short* __restrict__ W3l,
    unsigned short* __restrict__ Khi,  unsigned short* __restrict__ Klo,
    unsigned short* __restrict__ Kt,
    float* __restrict__ qacc, int* __restrict__ cnt,
    unsigned* __restrict__ colmaxU, int* __restrict__ woff)
{
  __shared__ float tile[64][65];  // used by the kt branch only
  int b = blockIdx.x;
  const int t = threadIdx.x;
  if (b < 6144){ pad_split_body(x, xph, xpl, N_ROWS, D_INN, KP1, b); return; }
  b -= 6144;
  if (b < 192){ pad_split_body(W1, W1ph, W1pl, HID, D_INN, KP1, b); return; }
  b -= 192;
  if (b < 128){ split_body(W2, W2h, W2l, b); return; }
  b -= 128;
  if (b < 128){ split_body(W3, W3h, W3l, b); return; }
  b -= 128;
  if (b < 512){ split_body(Km, Khi, Klo, b); return; }
  b -= 512;
  if (b < 256){
    const int sb = (b & 31) * 64;
    const int hb = (b >> 5) * 64;
    {
      int r = t >> 2, cq = t & 3;
#pragma unroll
      for (int q=0;q<4;++q){
        float4 v = *(const float4*)&Km[(size_t)(sb+r)*HID + hb + cq*16 + q*4];
        tile[r][cq*16+q*4+0]=v.x; tile[r][cq*16+q*4+1]=v.y;
        tile[r][cq*16+q*4+2]=v.z; tile[r][cq*16+q*4+3]=v.w;
      }
    }
    __syncthreads();
    {
      int hl = t >> 2, sq = t & 3;
      unsigned short w16[16];
#pragma unroll
      for (int q=0;q<16;++q) w16[q] = bf16_rne(tile[sq*16+q][hl]);
      *(uint4*)&Kt[(size_t)(hb+hl)*M_SLOTS + sb + sq*16]     = *(uint4*)&w16[0];
      *(uint4*)&Kt[(size_t)(hb+hl)*M_SLOTS + sb + sq*16 + 8] = *(uint4*)&w16[8];
    }
    return;
  }
  b -= 256;
  if (b < 512){
    int idx = (b*256 + t)*8;
    float4 z = {0.f,0.f,0.f,0.f};
    *(float4*)&qacc[idx]     = z;
    *(float4*)&qacc[idx + 4] = z;
    return;
  }
  b -= 512;
  { int i = b*256 + t; if (i < M_SLOTS){ cnt[i] = 0; colmaxU[i] = 0u; woff[i] = 0; } }
}

// ============================ MLP GEMM (3-term split bf16, 16x16, BM=128, 512 thr) ============================
// Optional ppart (last layer): per-(row, colblock-half) f32 pred partials (plain stores).
__global__ __launch_bounds__(512) void mlp_gemm(
    const unsigned short* __restrict__ Ah_g, const unsigned short* __restrict__ Al_g,
    const unsigned short* __restrict__ Wh_g, const unsigned short* __restrict__ Wl_g,
    const float* __restrict__ bias,
    unsigned short* __restrict__ Ohi, unsigned short* __restrict__ Olo,
    int Kp, const float* __restrict__ Wd, float* __restrict__ ppart)
{
  __shared__ char smem[65536];
  unsigned short* Ah = (unsigned short*)smem;            // [128][64] hi
  unsigned short* Al = (unsigned short*)(smem + 16384);  // [128][64] lo
  unsigned short* Bh = (unsigned short*)(smem + 32768);  // [128][64] hi
  unsigned short* Bl = (unsigned short*)(smem + 49152);  // [128][64] lo
  const int t = threadIdx.x;
  const int lane = t & 63, w = t >> 6;            // 8 waves
  const int l15 = lane & 15, l4 = lane >> 4;
  const int rowBase = blockIdx.x * 128;
  const int colBase = blockIdx.y * 128;
  const int wr = (w >> 1) * 32;
  const int wc = (w & 1) * 64;

  f32x4 acc[2][4];
#pragma unroll
  for (int i=0;i<2;++i)
#pragma unroll
    for (int j=0;j<4;++j) acc[i][j] = (f32x4){0.f,0.f,0.f,0.f};

  const int nkt = Kp >> 6;
  for (int kt = 0; kt < nkt; ++kt){
    const int k0 = kt * 64;
#pragma unroll
    for (int p = 0; p < 2; ++p){
      int idx = p*512 + t;
      int r = idx >> 3, c = idx & 7;
      int cc = c ^ (r & 7);
      size_t go = (size_t)(rowBase + r) * Kp + (k0 + cc*8);
      glds16(Ah_g + go, (char*)Ah + idx*16);
      glds16(Al_g + go, (char*)Al + idx*16);
    }
#pragma unroll
    for (int p = 0; p < 2; ++p){
      int idx = p*512 + t;
      int r = idx >> 3, c = idx & 7;
      int cc = c ^ (r & 7);
      size_t go = (size_t)(colBase + r) * Kp + (k0 + cc*8);
      glds16(Wh_g + go, (char*)Bh + idx*16);
      glds16(Wl_g + go, (char*)Bl + idx*16);
    }
    __syncthreads();

#pragma unroll
    for (int s = 0; s < 2; ++s){
      short8v a_h[2], a_l[2], b_h[4], b_l[4];
#pragma unroll
      for (int rt = 0; rt < 2; ++rt){
        int r = wr + rt*16 + l15;
        int off = r*128 + ((s*4 + l4) ^ (r & 7))*16;
        a_h[rt] = *(const short8v*)((const char*)Ah + off);
        a_l[rt] = *(const short8v*)((const char*)Al + off);
      }
#pragma unroll
      for (int ct = 0; ct < 4; ++ct){
        int r = wc + ct*16 + l15;
        int off = r*128 + ((s*4 + l4) ^ (r & 7))*16;
        b_h[ct] = *(const short8v*)((const char*)Bh + off);
        b_l[ct] = *(const short8v*)((const char*)Bl + off);
      }
#pragma unroll
      for (int rt = 0; rt < 2; ++rt)
#pragma unroll
        for (int ct = 0; ct < 4; ++ct){
          acc[rt][ct] = __builtin_amdgcn_mfma_f32_16x16x32_bf16(a_h[rt], b_h[ct], acc[rt][ct], 0,0,0);
          acc[rt][ct] = __builtin_amdgcn_mfma_f32_16x16x32_bf16(a_h[rt], b_l[ct], acc[rt][ct], 0,0,0);
          acc[rt][ct] = __builtin_amdgcn_mfma_f32_16x16x32_bf16(a_l[rt], b_h[ct], acc[rt][ct], 0,0,0);
        }
    }
    __syncthreads();
  }

  // epilogue: bias + relu, split hi/lo, stage through LDS for coalesced writes
  float bcol[4];
#pragma unroll
  for (int ct=0; ct<4; ++ct) bcol[ct] = bias[colBase + wc + ct*16 + l15];
  unsigned short* Sout = (unsigned short*)smem;  // [128][136] = 34816 B
#pragma unroll
  for (int rt=0; rt<2; ++rt)
#pragma unroll
    for (int ct=0; ct<4; ++ct)
#pragma unroll
      for (int reg=0; reg<4; ++reg){
        float v = acc[rt][ct][reg] + bcol[ct];
        v = v > 0.f ? v : 0.f;
        acc[rt][ct][reg] = v;
        Sout[(wr + rt*16 + l4*4 + reg)*136 + wc + ct*16 + l15] = bf16_rne(v);
      }

  // pred partials (last layer only): per-row dot over this block's 64-col half.
  if (ppart){
    float wdv[4];
#pragma unroll
    for (int ct=0; ct<4; ++ct) wdv[ct] = Wd[colBase + wc + ct*16 + l15];
#pragma unroll
    for (int rt=0; rt<2; ++rt)
#pragma unroll
      for (int reg=0; reg<4; ++reg){
        float pd = acc[rt][0][reg]*wdv[0] + acc[rt][1][reg]*wdv[1]
                 + acc[rt][2][reg]*wdv[2] + acc[rt][3][reg]*wdv[3];
#pragma unroll
        for (int d=1; d<16; d<<=1) pd += __shfl_xor(pd, d);
        if (l15 == 0){
          int row = rowBase + wr + rt*16 + l4*4 + reg;
          ppart[(size_t)row*8 + (colBase >> 7)*2 + (wc >> 6)] = pd;
        }
      }
  }

  __syncthreads();
#pragma unroll
  for (int p = 0; p < 4; ++p){
    int row = (t >> 4) + p*32;
    int c8 = (t & 15) * 8;
    uint4 v = *(uint4*)&Sout[row*136 + c8];
    *(uint4*)&Ohi[(size_t)(rowBase+row)*HID + colBase + c8] = v;
  }
  __syncthreads();
#pragma unroll
  for (int rt=0; rt<2; ++rt)
#pragma unroll
    for (int ct=0; ct<4; ++ct)
#pragma unroll
      for (int reg=0; reg<4; ++reg){
        float v = acc[rt][ct][reg];
        unsigned short h = bf16_rne(v);
        Sout[(wr + rt*16 + l4*4 + reg)*136 + wc + ct*16 + l15] = bf16_rne(v - bf16_to_f32(h));
      }
  __syncthreads();
#pragma unroll
  for (int p = 0; p < 4; ++p){
    int row = (t >> 4) + p*32;
    int c8 = (t & 15) * 8;
    uint4 v = *(uint4*)&Sout[row*136 + c8];
    *(uint4*)&Olo[(size_t)(rowBase+row)*HID + colBase + c8] = v;
  }
}

// ============================ S GEMM + stats (16x16, BM=128 x BN=128, 512 thr) ============================
// XCD-aware block swizzle (bijective: 2048 % 8 == 0): each XCD gets 16 whole
// row-blocks (all 16 col-blocks) -> Q strips L2-resident per XCD.
__global__ __launch_bounds__(512) void sgemm_stats(
    const unsigned short* __restrict__ Qhi, const unsigned short* __restrict__ Qlo,
    const unsigned short* __restrict__ Khi, const unsigned short* __restrict__ Klo,
    unsigned short* __restrict__ Sb,
    float* __restrict__ pmax, int* __restrict__ pcol,
    float* __restrict__ psum, float* __restrict__ pnmax, float* __restrict__ pnsum,
    unsigned* __restrict__ colmaxU)
{
  __shared__ char smem[65536];
  unsigned short* Ah = (unsigned short*)smem;            // [128][64] hi
  unsigned short* Al = (unsigned short*)(smem + 16384);  // [128][64] lo
  unsigned short* Bh = (unsigned short*)(smem + 32768);  // [128][64] hi
  unsigned short* Bl = (unsigned short*)(smem + 49152);  // [128][64] lo
  const int t = threadIdx.x;
  const int lane = t & 63, w = t >> 6;            // 8 waves
  const int l15 = lane & 15, l4 = lane >> 4;
  const int flat = blockIdx.x + 16*blockIdx.y;    // 0..2047
  const int swz  = (flat & 7)*256 + (flat >> 3);  // XCD-chunked bijection
  const int cb = swz & 15;        // 0..15  col block
  const int rb = swz >> 4;        // 0..127 row block
  const int rowBase = rb * 128;
  const int colBase = cb * 128;
  const int wr = (w >> 1) * 32;   // row quarter (0,32,64,96)
  const int wc = (w & 1) * 64;    // col half

  f32x4 acc[2][4];
#pragma unroll
  for (int i=0;i<2;++i)
#pragma unroll
    for (int j=0;j<4;++j) acc[i][j] = (f32x4){0.f,0.f,0.f,0.f};

  for (int kt = 0; kt < 8; ++kt){
    const int k0 = kt * 64;
#pragma unroll
    for (int p = 0; p < 2; ++p){
      int idx = p*512 + t;
      int r = idx >> 3, c = idx & 7;
      int cc = c ^ (r & 7);
      size_t go = (size_t)(rowBase + r) * HID + (k0 + cc*8);
      glds16(Qhi + go, (char*)Ah + idx*16);
      glds16(Qlo + go, (char*)Al + idx*16);
    }
#pragma unroll
    for (int p = 0; p < 2; ++p){
      int idx = p*512 + t;
      int r = idx >> 3, c = idx & 7;
      int cc = c ^ (r & 7);
      size_t go = (size_t)(colBase + r) * HID + (k0 + cc*8);
      glds16(Khi + go, (char*)Bh + idx*16);
      glds16(Klo + go, (char*)Bl + idx*16);
    }
    __syncthreads();

#pragma unroll
    for (int s = 0; s < 2; ++s){
      short8v a_h[2], a_l[2], b_h[4], b_l[4];
#pragma unroll
      for (int rt = 0; rt < 2; ++rt){
        int r = wr + rt*16 + l15;
        int off = r*128 + ((s*4 + l4) ^ (r & 7))*16;
        a_h[rt] = *(const short8v*)((const char*)Ah + off);
        a_l[rt] = *(const short8v*)((const char*)Al + off);
      }
#pragma unroll
      for (int ct = 0; ct < 4; ++ct){
        int r = wc + ct*16 + l15;
        int off = r*128 + ((s*4 + l4) ^ (r & 7))*16;
        b_h[ct] = *(const short8v*)((const char*)Bh + off);
        b_l[ct] = *(const short8v*)((const char*)Bl + off);
      }
#pragma unroll
      for (int rt = 0; rt < 2; ++rt)
#pragma unroll
        for (int ct = 0; ct < 4; ++ct){
          acc[rt][ct] = __builtin_amdgcn_mfma_f32_16x16x32_bf16(a_h[rt], b_h[ct], acc[rt][ct], 0,0,0);
          acc[rt][ct] = __builtin_amdgcn_mfma_f32_16x16x32_bf16(a_h[rt], b_l[ct], acc[rt][ct], 0,0,0);
          acc[rt][ct] = __builtin_amdgcn_mfma_f32_16x16x32_bf16(a_l[rt], b_h[ct], acc[rt][ct], 0,0,0);
        }
    }
    __syncthreads();
  }

  // ---- row stats (per wave over its 64-col half) ----
#pragma unroll
  for (int rt = 0; rt < 2; ++rt){
#pragma unroll
    for (int reg = 0; reg < 4; ++reg){
      float v0 = acc[rt][0][reg], v1 = acc[rt][1][reg];
      float v2 = acc[rt][2][reg], v3 = acc[rt][3][reg];
      float bvv = v0; int bcc = colBase + wc + l15;
      if (v1 > bvv){ bvv = v1; bcc = colBase + wc + 16 + l15; }
      if (v2 > bvv){ bvv = v2; bcc = colBase + wc + 32 + l15; }
      if (v3 > bvv){ bvv = v3; bcc = colBase + wc + 48 + l15; }
      float mnv = fminf(fminf(v0,v1), fminf(v2,v3));
#pragma unroll
      for (int d = 1; d < 16; d <<= 1){
        float ov = __shfl_xor(bvv, d);
        int   oc = __shfl_xor(bcc, d);
        float om = __shfl_xor(mnv, d);
        if (ov > bvv || (ov == bvv && oc < bcc)){ bvv = ov; bcc = oc; }
        mnv = fminf(mnv, om);
      }
      float sp = __expf(v0-bvv)+__expf(v1-bvv)+__expf(v2-bvv)+__expf(v3-bvv);
      float sn = __expf(mnv-v0)+__expf(mnv-v1)+__expf(mnv-v2)+__expf(mnv-v3);
#pragma unroll
      for (int d = 1; d < 16; d <<= 1){ sp += __shfl_xor(sp,d); sn += __shfl_xor(sn,d); }
      if (l15 == 0){
        int row = rowBase + wr + rt*16 + l4*4 + reg;
        size_t pi = (size_t)row*32 + cb*2 + (w & 1);
        pmax[pi] = bvv; pcol[pi] = bcc; psum[pi] = sp;
        pnmax[pi] = -mnv; pnsum[pi] = sn;
      }
    }
  }

  // ---- per-column max -> device-wide atomicMax (mapped uint) ----
#pragma unroll
  for (int ct = 0; ct < 4; ++ct){
    float cm = -1e30f;
#pragma unroll
    for (int rt=0; rt<2; ++rt)
#pragma unroll
      for (int reg=0; reg<4; ++reg) cm = fmaxf(cm, acc[rt][ct][reg]);
    cm = fmaxf(cm, __shfl_xor(cm, 16));
    cm = fmaxf(cm, __shfl_xor(cm, 32));
    if (l4 == 0)
      atomicMax(&colmaxU[colBase + wc + ct*16 + l15], fmap(cm));
  }

  // ---- S bf16 write (staged through LDS for coalescing) ----
  __syncthreads();
  unsigned short* Sout = (unsigned short*)smem;  // [128][136] = 34816 B
#pragma unroll
  for (int rt=0; rt<2; ++rt)
#pragma unroll
    for (int ct=0; ct<4; ++ct)
#pragma unroll
      for (int reg=0; reg<4; ++reg)
        Sout[(wr + rt*16 + l4*4 + reg)*136 + wc + ct*16 + l15] = bf16_rne(acc[rt][ct][reg]);
  __syncthreads();
#pragma unroll
  for (int p = 0; p < 4; ++p){
    int row = (t >> 4) + p*32;
    int c8 = (t & 15) * 8;
    uint4 v = *(uint4*)&Sout[row*136 + c8];
    *(uint4*)&Sb[(size_t)(rowBase+row)*M_SLOTS + colBase + c8] = v;
  }
}

// merge rows (64 blocks): row stats + fused csr count + pred assembly from partials
__global__ __launch_bounds__(256) void merge_all(
    const float* __restrict__ pmax, const int* __restrict__ pcol,
    const float* __restrict__ psum, const float* __restrict__ pnmax,
    const float* __restrict__ pnsum,
    float* __restrict__ rowm, float* __restrict__ rsp,
    float* __restrict__ rmn, float* __restrict__ rsn, int* __restrict__ gidx,
    int* __restrict__ cnt,
    const float* __restrict__ ppart, const float* __restrict__ bd,
    float* __restrict__ pred)
{
  int row = blockIdx.x*256 + threadIdx.x;
  const size_t base = (size_t)row*32;
  float m = -1e30f; int g = 0;
  for (int i=0;i<32;++i){
    float v = pmax[base+i];
    if (v > m){ m = v; g = pcol[base+i]; }
  }
  float s = 0.f;
  for (int i=0;i<32;++i) s += psum[base+i] * __expf(pmax[base+i]-m);
  float mn = -1e30f;
  for (int i=0;i<32;++i) mn = fmaxf(mn, pnmax[base+i]);
  float sn = 0.f;
  for (int i=0;i<32;++i) sn += pnsum[base+i] * __expf(pnmax[base+i]-mn);
  rowm[row]=m; gidx[row]=g; rsp[row]=1.f/s; rmn[row]=mn; rsn[row]=1.f/sn;
  atomicAdd(&cnt[g], 1);
  float pd = bd[0];
#pragma unroll
  for (int i=0;i<8;++i) pd += ppart[(size_t)row*8 + i];
  pred[row] = pd;
}

// ============================ PV (S read once, 16x16, 64 rows, 512 thr) ============================
// XCD-aware swizzle (512 % 8 == 0): both h-halves of a row-block land on the
// same XCD -> Sb strip fetched once per XCD.
#define PV_RB 64
#define PV_HB 256
__global__ __launch_bounds__(512) void pv2(
    const unsigned short* __restrict__ Sb, const unsigned short* __restrict__ Kt,
    const float* __restrict__ rowm, const float* __restrict__ rsp,
    const float* __restrict__ rmn, const float* __restrict__ rsn,
    const unsigned short* __restrict__ Qhi, const unsigned short* __restrict__ Qlo,
    float* __restrict__ outP, float* __restrict__ outN)
{
  __shared__ char smem[49152];
  unsigned short* Ktile = (unsigned short*)smem;          // [256 h][64 slots], chunk-swizzled, 32KB
  unsigned short* Wp = (unsigned short*)(smem + 32768);   // [64 rows][8 octets] 16B chunks, 8KB
  unsigned short* Wn = (unsigned short*)(smem + 40960);   // 8KB
  const int t = threadIdx.x, lane = t & 63, w = t >> 6;
  const int l15 = lane & 15, l4 = lane >> 4;
  const int flat = blockIdx.x + 2*blockIdx.y;     // 0..511
  const int swz  = (flat & 7)*64 + (flat >> 3);   // XCD-chunked bijection
  const int rowBase = (swz >> 1) * PV_RB;
  const int hBase = (swz & 1) * PV_HB;
  const int wrq = (w >> 2) * 32;       // wave row half (0 or 32)
  const int hw = (w & 3) * 64;         // wave col group
  const int rS = t >> 3;               // 0..63: row for weight computation
  const int c8 = t & 7;                // slot-octet
  const float mp = rowm[rowBase + rS], mn = rmn[rowBase + rS];

  f32x4 accP[2][4], accN[2][4];
#pragma unroll
  for (int i=0;i<2;++i)
#pragma unroll
    for (int j=0;j<4;++j){ accP[i][j]=(f32x4){0.f,0.f,0.f,0.f}; accN[i][j]=(f32x4){0.f,0.f,0.f,0.f}; }

  for (int kt = 0; kt < 32; ++kt){
    const int k0 = kt*64;
#pragma unroll
    for (int p=0;p<4;++p){
      int idx = p*512 + t;
      int r = idx >> 3, c = idx & 7;
      int cc = c ^ (r & 7);
      glds16(Kt + (size_t)(hBase + r)*M_SLOTS + k0 + cc*8, (char*)Ktile + idx*16);
    }
    short8v sv = *(const short8v*)&Sb[(size_t)(rowBase + rS)*M_SLOTS + k0 + c8*8];
    short8v wp, wn;
#pragma unroll
    for (int e=0;e<8;++e){
      float sval = bf16_to_f32((unsigned short)sv[e]);
      wp[e] = (short)bf16_rne(__expf(sval - mp));
      wn[e] = (short)bf16_rne(__expf(-sval - mn));
    }
    {
      int ch = rS*8 + (c8 ^ (rS & 7));
      *(short8v*)(Wp + ch*8) = wp;
      *(short8v*)(Wn + ch*8) = wn;
    }
    __syncthreads();
#pragma unroll
    for (int s=0; s<2; ++s){
      short8v ap[2], an[2], b[4];
#pragma unroll
      for (int rt=0; rt<2; ++rt){
        int r = wrq + rt*16 + l15;
        int ch = r*8 + ((s*4 + l4) ^ (r & 7));
        ap[rt] = *(const short8v*)(Wp + ch*8);
        an[rt] = *(const short8v*)(Wn + ch*8);
      }
#pragma unroll
      for (int ct=0; ct<4; ++ct){
        int hr = hw + ct*16 + l15;
        b[ct] = *(const short8v*)((const char*)Ktile + hr*128 + ((s*4 + l4) ^ (hr & 7))*16);
      }
#pragma unroll
      for (int rt=0; rt<2; ++rt)
#pragma unroll
        for (int ct=0; ct<4; ++ct){
          accP[rt][ct] = __builtin_amdgcn_mfma_f32_16x16x32_bf16(ap[rt], b[ct], accP[rt][ct], 0,0,0);
          accN[rt][ct] = __builtin_amdgcn_mfma_f32_16x16x32_bf16(an[rt], b[ct], accN[rt][ct], 0,0,0);
        }
    }
    __syncthreads();
  }

  // epilogue: scale, gate by Q (hi+lo), staged 32-row phases through reused LDS
  float isp[2][4], isn[2][4];
#pragma unroll
  for (int rt=0; rt<2; ++rt)
#pragma unroll
    for (int reg=0; reg<4; ++reg){
      int row = rowBase + wrq + rt*16 + l4*4 + reg;
      isp[rt][reg] = rsp[row];
      isn[rt][reg] = rsn[row];
    }
  float* Pout = (float*)smem;   // [32][260] = 33280 B
#pragma unroll
  for (int sign=0; sign<2; ++sign){
#pragma unroll
    for (int rh=0; rh<2; ++rh){
      if ((w >> 2) == rh){
#pragma unroll
        for (int rt=0; rt<2; ++rt)
#pragma unroll
          for (int ct=0; ct<4; ++ct)
#pragma unroll
            for (int reg=0; reg<4; ++reg){
              float v = sign ? accN[rt][ct][reg]*isn[rt][reg]
                             : accP[rt][ct][reg]*isp[rt][reg];
              Pout[(rt*16 + l4*4 + reg)*260 + hw + ct*16 + l15] = v;
            }
      }
      __syncthreads();
      float* outX = sign ? outN : outP;
#pragma unroll
      for (int p=0; p<4; ++p){
        int row = t >> 4;                 // 0..31
        int col = (t & 15)*4 + p*64;      // 0..252
        int grow = rowBase + rh*32 + row;
        float4 pv = *(float4*)&Pout[row*260 + col];
        float4 qv = ld4bf(Qhi, Qlo, (size_t)grow*HID + hBase + col);
        float4 o; o.x=pv.x*qv.x; o.y=pv.y*qv.y; o.z=pv.z*qv.z; o.w=pv.w*qv.w;
        *(float4*)&outX[(size_t)grow*HID + hBase + col] = o;
      }
      __syncthreads();
    }
  }
}

// ============================ CSR upload (skew-independent) ============================
// csr_fill with fused in-block scan: each of 64 blocks redundantly scans cnt
// in LDS (deterministic, identical result) and uses global atomic cursors.
__global__ __launch_bounds__(256) void csr_fill(const int* __restrict__ cnt,
                                                const int* __restrict__ gidx,
                                                const float* __restrict__ rowm,
                                                const unsigned* __restrict__ colmaxU,
                                                int* __restrict__ woff,
                                                int* __restrict__ rows, float* __restrict__ wv,
                                                int* __restrict__ sid){
  __shared__ int s_off[M_SLOTS];
  __shared__ int partial[256];
  const int t = threadIdx.x;
  const int base = t*8;
  int local[8]; int s = 0;
#pragma unroll
  for (int j=0;j<8;++j){ local[j] = s; s += cnt[base+j]; }
  partial[t] = s;
  __syncthreads();
  for (int d=1; d<256; d<<=1){
    int v = (t>=d) ? partial[t-d] : 0;
    __syncthreads();
    partial[t] += v;
    __syncthreads();
  }
  int pre = (t==0) ? 0 : partial[t-1];
#pragma unroll
  for (int j=0;j<8;++j) s_off[base+j] = pre + local[j];
  __syncthreads();
  int i = blockIdx.x*256 + t;
  int g = gidx[i];
  int p = s_off[g] + atomicAdd(&woff[g], 1);
  rows[p] = i;
  wv[p] = __expf(rowm[i] - funmap(colmaxU[g]));
  sid[p] = g;
}

__global__ __launch_bounds__(256) void upload_scatter(
    const unsigned short* __restrict__ Qhi, const unsigned short* __restrict__ Qlo,
    const int* __restrict__ sid, const int* __restrict__ rows, const float* __restrict__ wv,
    const int* __restrict__ train, float* __restrict__ qacc)
{
  if (*train == 0) return;
  const int b = blockIdx.x, t = threadIdx.x;
  __shared__ int   s_sid[64];
  __shared__ int   s_row[64];
  __shared__ float s_w[64];
  if (t < 64){
    int p = b*64 + t;
    s_sid[t] = sid[p];
    s_row[t] = rows[p];
    s_w[t]   = wv[p];
  }
  __syncthreads();
  const int h0 = t*2;
  float a0 = 0.f, a1 = 0.f;
  int prev = s_sid[0];
#pragma unroll 4
  for (int p = 0; p < 64; ++p){
    int s = s_sid[p];
    if (s != prev){
      atomicAdd(&qacc[(size_t)prev*HID + h0],     a0);
      atomicAdd(&qacc[(size_t)prev*HID + h0 + 1], a1);
      a0 = 0.f; a1 = 0.f; prev = s;
    }
    int row = s_row[p];
    float w = s_w[p];
    unsigned h = *(const unsigned*)(Qhi + (size_t)row*HID + h0);
    unsigned l = *(const unsigned*)(Qlo + (size_t)row*HID + h0);
    a0 += w * (bf16_to_f32((unsigned short)(h & 0xffffu)) + bf16_to_f32((unsigned short)(l & 0xffffu)));
    a1 += w * (bf16_to_f32((unsigned short)(h >> 16))     + bf16_to_f32((unsigned short)(l >> 16)));
  }
  atomicAdd(&qacc[(size_t)prev*HID + h0],     a0);
  atomicAdd(&qacc[(size_t)prev*HID + h0 + 1], a1);
}

__global__ __launch_bounds__(256) void upload_finish(const float* __restrict__ qacc,
                                                     const float* __restrict__ Km,
                                                     const int* __restrict__ train,
                                                     float* __restrict__ mem)
{
  const int m = blockIdx.x, t = threadIdx.x;
  const int h0 = t * 2;
  float2 kv = *(const float2*)&Km[(size_t)m*HID + h0];
  if (*train == 0){
    mem[(size_t)m*HID + h0]     = kv.x;
    mem[(size_t)m*HID + h0 + 1] = kv.y;
    return;
  }
  float2 av = *(const float2*)&qacc[(size_t)m*HID + h0];
  float v0 = av.x + kv.x, v1 = av.y + kv.y;
  __shared__ float red[256];
  red[t] = v0*v0 + v1*v1;
  __syncthreads();
  for (int s = 128; s > 0; s >>= 1){
    if (t < s) red[t] += red[t + s];
    __syncthreads();
  }
  float rinv = 1.f / fmaxf(sqrtf(red[0]), 1e-12f);
  mem[(size_t)m*HID + h0]     = v0 * rinv;
  mem[(size_t)m*HID + h0 + 1] = v1 * rinv;
}

// ============================ host ============================

extern "C" void kernel_launch(void* const* d_in, const int* in_sizes, int n_in,
                              void* d_out, int out_size, void* d_ws, size_t ws_size,
                              hipStream_t stream)
{
  const float* x   = (const float*)d_in[0];
  const float* Km  = (const float*)d_in[1];
  const float* W1  = (const float*)d_in[2];
  const float* b1  = (const float*)d_in[3];
  const float* W2  = (const float*)d_in[4];
  const float* b2  = (const float*)d_in[5];
  const float* W3  = (const float*)d_in[6];
  const float* b3  = (const float*)d_in[7];
  const float* Wd  = (const float*)d_in[8];
  const float* bd  = (const float*)d_in[9];
  const int* train = (const int*)d_in[10];

  float* out  = (float*)d_out;
  float* pred = out;
  float* outN = out + 16384;
  float* outP = out + 16384 + 8388608;
  float* memo = out + 16384 + 2*8388608;

  char* ws = (char*)d_ws;
  unsigned short* Qhi   = (unsigned short*)(ws + 0);           // 16,777,216
  unsigned short* Qlo   = (unsigned short*)(ws + 16777216);    // 16,777,216
  unsigned short* xph   = (unsigned short*)(ws + 33554432);    // 12,582,912
  unsigned short* xpl   = (unsigned short*)(ws + 46137344);    // 12,582,912
  unsigned short* h1h   = (unsigned short*)(ws + 58720256);    // 16,777,216
  unsigned short* h1l   = (unsigned short*)(ws + 75497472);    // 16,777,216
  unsigned short* h2h   = (unsigned short*)(ws + 92274688);    // 16,777,216
  unsigned short* h2l   = (unsigned short*)(ws + 109051904);   // 16,777,216 (R0 end 125,829,120)
  unsigned short* Sb    = (unsigned short*)(ws + 33554432);    // 67,108,864 (aliases R0)
  unsigned short* Khi   = (unsigned short*)(ws + 125829120);   //  2,097,152
  unsigned short* Klo   = (unsigned short*)(ws + 127926272);   //  2,097,152
  unsigned short* Kt    = (unsigned short*)(ws + 130023424);   //  2,097,152
  unsigned short* W1ph  = (unsigned short*)(ws + 132120576);   //    393,216
  unsigned short* W1pl  = (unsigned short*)(ws + 132513792);   //    393,216
  unsigned short* W2h   = (unsigned short*)(ws + 132907008);   //    524,288
  unsigned short* W2l   = (unsigned short*)(ws + 133431296);   //    524,288
  unsigned short* W3h   = (unsigned short*)(ws + 133955584);   //    524,288
  unsigned short* W3l   = (unsigned short*)(ws + 134479872);   //    524,288
  float* pmax    = (float*)(ws + 135004160);                   //  2,097,152
  int*   pcol    = (int*)  (ws + 137101312);                   //  2,097,152
  float* psum    = (float*)(ws + 139198464);                   //  2,097,152
  float* pnmax   = (float*)(ws + 141295616);                   //  2,097,152
  float* pnsum   = (float*)(ws + 143392768);                   //  2,097,152
  // (ws + 145489920) 4 MB: unused
  float* rowm    = (float*)(ws + 149684224);
  float* rsp     = (float*)(ws + 149749760);
  float* rmn     = (float*)(ws + 149815296);
  float* rsn     = (float*)(ws + 149880832);
  int*   gidx    = (int*)  (ws + 149946368);
  unsigned* colmaxU = (unsigned*)(ws + 150011904);             //      8,192
  int*   cnt     = (int*)  (ws + 150020096);                   //      8,192
  // (ws + 150028288) 8,448 bytes: unused (was off)
  int*   woff    = (int*)  (ws + 150036736);                   //      8,192
  int*   rows    = (int*)  (ws + 150044928);                   //     65,536
  float* wv      = (float*)(ws + 150110464);                   //     65,536
  int*   sid     = (int*)  (ws + 150176000);                   //     65,536
  float* qacc    = (float*)(ws + 150241536);                   //  4,194,304
  float* ppart   = (float*)(ws + 154435840);                   //    524,288 (16384 x 8)
  const size_t NEED = 154960128ull;
  if (ws_size < NEED) return;  // harness provides >= 155.5 MB (proven round 2)

  dim3 blk(256);

  // fused conversions + Kt transpose + cnt/colmaxU/woff/qacc zeroing (one launch)
  init_all<<<7880, blk, 0, stream>>>(x, W1, W2, W3, Km,
                                     xph, xpl, W1ph, W1pl, W2h, W2l, W3h, W3l,
                                     Khi, Klo, Kt, qacc, cnt, colmaxU, woff);

  // MLP (split-bf16 MFMA, BM=128 16x16); layer 3 writes pred partials (plain stores)
  mlp_gemm<<<dim3(N_ROWS/128, 4), dim3(512), 0, stream>>>(xph, xpl, W1ph, W1pl, b1, h1h, h1l, KP1,
                                                          (const float*)nullptr, (float*)nullptr);
  mlp_gemm<<<dim3(N_ROWS/128, 4), dim3(512), 0, stream>>>(h1h, h1l, W2h, W2l, b2, h2h, h2l, HID,
                                                          (const float*)nullptr, (float*)nullptr);
  mlp_gemm<<<dim3(N_ROWS/128, 4), dim3(512), 0, stream>>>(h2h, h2l, W3h, W3l, b3, Qhi, Qlo, HID,
                                                          Wd, ppart);

  // attention stats + PV (both XCD-swizzled)
  sgemm_stats<<<dim3(16, 128), dim3(512), 0, stream>>>(Qhi, Qlo, Khi, Klo, Sb,
                                                       pmax, pcol, psum, pnmax, pnsum, colmaxU);
  merge_all<<<64, blk, 0, stream>>>(pmax, pcol, psum, pnmax, pnsum,
                                    rowm, rsp, rmn, rsn, gidx, cnt, ppart, bd, pred);
  pv2<<<dim3(2, 256), dim3(512), 0, stream>>>(Sb, Kt, rowm, rsp, rmn, rsn, Qhi, Qlo, outP, outN);

  // upload via CSR (scan fused into fill) + bounded scatter
  csr_fill<<<N_ROWS/256, blk, 0, stream>>>(cnt, gidx, rowm, colmaxU, woff, rows, wv, sid);
  upload_scatter<<<N_ROWS/64, blk, 0, stream>>>(Qhi, Qlo, sid, rows, wv, train, qacc);
  upload_finish<<<M_SLOTS, blk, 0, stream>>>(qacc, Km, train, memo);
}